// Round 1
// baseline (892.616 us; speedup 1.0000x reference)
//
#include <hip/hip_runtime.h>

// GCN-EEGNet forward, MI355X. Dtype-adaptive (fp32/bf16 detected in K0 via
// adjacency sentinel). Weights in ws, wave-uniform -> SGPR. Intermediates
// f16. Round-14: fuse K2 (sparse graph einsum) + K3 (gconv+bn+elu) into K23.
// K2's 131 MB HBM write + K3's re-read of the same tensor was a pure round
// trip (graph sum is ~32 fma/output vs 2048 dot2 in gconv). K23 stages the
// 8-channel Ah window in 33 KB LDS per (b,c) block (graph sum on the fly,
// neighbor rows served from L2), one barrier, then the verified r10 dot2
// body reads windows from LDS. Buffers ping-pong A->B->A->B; K4 reads bufB.
// LESSON (r12): never launch empty blocks in a pattern resonant with id%8
// XCD round-robin. K23 keeps k3's exact grid (2, B*C).
// Pipeline: K0 -> K1 conv1+bn -> 3x K23 -> K4 dw+bn+elu+pool4 -> K5 sep ->
// K6 pool8+fc.

#define B_   32
#define C_   64
#define T_   4000
#define F1_  8
#define TP_  1000
#define W2_  1001
#define MAXDEG 16
#define NCH  258      // uint4 chunks per i-row staged in LDS (2064 halfs)
#define LDW  1032     // dwords per i-row (NCH*4)

typedef _Float16 h16x2 __attribute__((ext_vector_type(2)));

static __device__ __forceinline__ float bf2f(unsigned short h) {
  union { unsigned int u; float f; } v; v.u = ((unsigned int)h) << 16; return v.f;
}
static __device__ __forceinline__ unsigned short f2bf(float f) {
  union { float f; unsigned int u; } v; v.f = f;
  unsigned int r = v.u + 0x7FFFu + ((v.u >> 16) & 1u);
  return (unsigned short)(r >> 16);
}
static __device__ __forceinline__ float lo_h(unsigned int u) {
  union { unsigned int u; _Float16 h[2]; } v; v.u = u; return (float)v.h[0];
}
static __device__ __forceinline__ float hi_h(unsigned int u) {
  union { unsigned int u; _Float16 h[2]; } v; v.u = u; return (float)v.h[1];
}
static __device__ __forceinline__ unsigned int pack2h(float a, float b) {
  union { _Float16 h[2]; unsigned int u; } v;
  v.h[0] = (_Float16)a; v.h[1] = (_Float16)b; return v.u;
}
static __device__ __forceinline__ h16x2 as_h2(unsigned int u) {
  union { unsigned int u; h16x2 h; } v; v.u = u; return v.h;
}
#if defined(__has_builtin) && __has_builtin(__builtin_amdgcn_fdot2)
#define DOT2(a, b, c) __builtin_amdgcn_fdot2((a), (b), (c), false)
#else
static __device__ __forceinline__ float dot2_fb(h16x2 a, h16x2 b, float c) {
  return fmaf((float)a[0], (float)b[0], fmaf((float)a[1], (float)b[1], c));
}
#define DOT2(a, b, c) dot2_fb((a), (b), (c))
#endif
static __device__ __forceinline__ float eluf(float z) {
  return z > 0.0f ? z : __expf(z) - 1.0f;
}
static __device__ __forceinline__ float ldin(const void* p, int i, int isf32) {
  return isf32 ? ((const float*)p)[i] : bf2f(((const unsigned short*)p)[i]);
}

// ---------------- K0: dtype detect + canonicalize + CSR + bn fold ----------
__global__ __launch_bounds__(256) void k0_setup(
    const void* __restrict__ adj, const void* __restrict__ imp,
    const void* __restrict__ dww, const void* __restrict__ w1,
    const void* __restrict__ bnF, const void* __restrict__ gw,
    const void* __restrict__ bnsp, const void* __restrict__ sdw,
    const void* __restrict__ pw, const void* __restrict__ bnsep,
    const void* __restrict__ fcw, const void* __restrict__ fcb,
    int* __restrict__ flag, int* __restrict__ deg, int* __restrict__ col,
    float* __restrict__ avals, float* __restrict__ w1c,
    unsigned int* __restrict__ gwh, float* __restrict__ dwn,
    float* __restrict__ sdwc, float* __restrict__ pwc,
    float* __restrict__ fcwc, float* __restrict__ fcbc,
    float* __restrict__ bnFs, float* __restrict__ bnsps,
    float* __restrict__ bnseps)
{
  __shared__ float dwr[1024];
  __shared__ float dsc[16];
  int tid = threadIdx.x;
  int isf32 = (((const float*)adj)[0] == 1.0f) ? 1 : 0;
  if (tid == 0) *flag = isf32;

  for (int i = tid; i < 512;  i += 256) w1c[i]  = ldin(w1, i, isf32);
  // gconv weights packed as f16 pairs: gwh[((l*8+o)*8+i)*4+kp] = (W[2kp],W[2kp+1])
  for (int idx = tid; idx < 768; idx += 256) {
    int kp = idx & 3, i = (idx >> 2) & 7, o = (idx >> 5) & 7, l = idx >> 8;
    int bi = l*512 + (o*8 + i)*8 + 2*kp;
    gwh[idx] = pack2h(ldin(gw, bi, isf32), ldin(gw, bi + 1, isf32));
  }
  for (int i = tid; i < 256;  i += 256) sdwc[i] = ldin(sdw, i, isf32);
  for (int i = tid; i < 256;  i += 256) pwc[i]  = ldin(pw, i, isf32);
  for (int i = tid; i < 8000; i += 256) fcwc[i] = ldin(fcw, i, isf32);
  if (tid < 4) fcbc[tid] = ldin(fcb, tid, isf32);
  for (int i = tid; i < 1024; i += 256) dwr[i] = ldin(dww, i, isf32);

  if (tid < 64) {            // CSR of adjacency (data-driven), self-padded
    int c = tid, n = 0;
    for (int e = 0; e < MAXDEG; ++e) col[c*MAXDEG + e] = c;
    for (int d = 0; d < 64; ++d) {
      if (ldin(adj, c*64 + d, isf32) != 0.0f) {
        if (n < MAXDEG) col[c*MAXDEG + n] = d;
        ++n;
      }
    }
    deg[c] = n < MAXDEG ? n : MAXDEG;
  }
  __syncthreads();
  if (tid < 16) {            // dw norm clamp scale
    float s2 = 0.0f;
    for (int c2 = 0; c2 < 64; ++c2) { float wv = dwr[tid*64 + c2]; s2 += wv*wv; }
    dsc[tid] = fminf(1.0f, 1.0f / fmaxf(sqrtf(s2), 1e-7f));
  }
  if (tid >= 64 && tid < 96) {   // bnF folded scale/shift: 4 stages x 8 ch
    int i = tid - 64, s = i >> 3, f = i & 7;
    float g = ldin(bnF, s*32 + f,      isf32);
    float b = ldin(bnF, s*32 + 8 + f,  isf32);
    float m = ldin(bnF, s*32 + 16 + f, isf32);
    float v = ldin(bnF, s*32 + 24 + f, isf32);
    float sc = g * rsqrtf(v + 1e-3f);
    bnFs[s*16 + f] = sc; bnFs[s*16 + 8 + f] = b - m*sc;
  }
  if (tid >= 96 && tid < 112) {  // bn_sp
    int ch = tid - 96;
    float g = ldin(bnsp, ch, isf32), b = ldin(bnsp, 16 + ch, isf32);
    float m = ldin(bnsp, 32 + ch, isf32), v = ldin(bnsp, 48 + ch, isf32);
    float sc = g * rsqrtf(v + 1e-3f);
    bnsps[ch] = sc; bnsps[16 + ch] = b - m*sc;
  }
  if (tid >= 112 && tid < 128) { // bn_sep
    int ch = tid - 112;
    float g = ldin(bnsep, ch, isf32), b = ldin(bnsep, 16 + ch, isf32);
    float m = ldin(bnsep, 32 + ch, isf32), v = ldin(bnsep, 48 + ch, isf32);
    float sc = g * rsqrtf(v + 1e-3f);
    bnseps[ch] = sc; bnseps[16 + ch] = b - m*sc;
  }
  for (int combo = tid; combo < 3*8*64; combo += 256) {
    int l = combo >> 9, f = (combo >> 6) & 7, c = combo & 63;
    int dg = deg[c];
    for (int e = 0; e < MAXDEG; ++e) {
      float v = 0.0f;
      if (e < dg) {
        int d = col[c*MAXDEG + e];
        v = ldin(adj, c*64 + d, isf32) * ldin(imp, ((l*8 + f)*64 + c)*64 + d, isf32);
      }
      avals[((l*8 + f)*64 + c)*MAXDEG + e] = v;
    }
  }
  __syncthreads();
  for (int i = tid; i < 1024; i += 256) dwn[i] = dwr[i] * dsc[i >> 6];
}

// ---------------- K1: conv1 (64-tap) + bn0. 4 t/thread, SGPR weights -------
// grid (4 t-tiles of 1024, B*C). Stage xs[s] = x[tb-36+s], s in [0,1096):
// base tb-36 makes fp32 float4 (16B) and bf16 uint2 (8B) loads aligned.
__global__ __launch_bounds__(256, 4) void k1_conv1_bn(
    const void* __restrict__ x,               // B,C,T raw dtype
    const float* __restrict__ w1c,            // 8x64 fp32 (uniform -> s_load)
    const float* __restrict__ bnFs,
    const int* __restrict__ flag,
    unsigned short* __restrict__ outp)        // B,F1,C,T f16
{
  __shared__ __align__(16) float xs[1096];
  int tid = threadIdx.x;
  int bc = blockIdx.y;                 // b*64+c
  int b = bc >> 6, c = bc & 63;
  int tb = blockIdx.x * 1024;
  int isf32 = *flag;
  int row = bc * T_;
  if (isf32) {
    const float* xr = (const float*)x + row;
    for (int m = tid; m < 274; m += 256) {
      int tg = tb - 36 + 4*m;
      if (tg >= 0 && tg + 3 < T_) {
        *(float4*)(xs + 4*m) = *(const float4*)(xr + tg);   // 16B aligned
      } else {
        #pragma unroll
        for (int q = 0; q < 4; ++q) {
          int t = tg + q;
          xs[4*m + q] = (t >= 0 && t < T_) ? xr[t] : 0.0f;
        }
      }
    }
  } else {
    const unsigned short* xr = (const unsigned short*)x + row;
    for (int m = tid; m < 274; m += 256) {
      int tg = tb - 36 + 4*m;
      if (tg >= 0 && tg + 3 < T_) {
        uint2 v = *(const uint2*)(xr + tg);                 // 8B aligned
        xs[4*m]     = bf2f((unsigned short)(v.x & 0xFFFFu));
        xs[4*m + 1] = bf2f((unsigned short)(v.x >> 16));
        xs[4*m + 2] = bf2f((unsigned short)(v.y & 0xFFFFu));
        xs[4*m + 3] = bf2f((unsigned short)(v.y >> 16));
      } else {
        #pragma unroll
        for (int q = 0; q < 4; ++q) {
          int t = tg + q;
          xs[4*m + q] = (t >= 0 && t < T_) ? bf2f(xr[t]) : 0.0f;
        }
      }
    }
  }
  __syncthreads();
  int t0 = tb + 4*tid;
  if (t0 >= T_) return;
  float acc[8][4];
  #pragma unroll
  for (int f = 0; f < 8; ++f)
    #pragma unroll
    for (int j = 0; j < 4; ++j) acc[f][j] = 0.0f;
  float4 A4 = *(const float4*)(xs + 4*tid + 4);
  float4 B4 = *(const float4*)(xs + 4*tid + 8);
  for (int cc = 0; cc < 16; ++cc) {
    float ev[7] = {A4.y, A4.z, A4.w, B4.x, B4.y, B4.z, B4.w};
    #pragma unroll
    for (int kk = 0; kk < 4; ++kk) {
      #pragma unroll
      for (int f = 0; f < 8; ++f) {
        float wv = w1c[f*64 + 4*cc + kk];    // uniform -> SGPR
        #pragma unroll
        for (int j = 0; j < 4; ++j) acc[f][j] = fmaf(wv, ev[kk + j], acc[f][j]);
      }
    }
    A4 = B4;
    if (cc < 15) B4 = *(const float4*)(xs + 4*tid + 12 + 4*cc);
  }
  #pragma unroll
  for (int f = 0; f < 8; ++f) {
    float sc = bnFs[f], sh = bnFs[8 + f];
    uint2 st;
    st.x = pack2h(acc[f][0]*sc + sh, acc[f][1]*sc + sh);
    st.y = pack2h(acc[f][2]*sc + sh, acc[f][3]*sc + sh);
    *(uint2*)(outp + ((b*8 + f)*64 + c)*T_ + t0) = st;
  }
}

// ---------------- K23: fused graph einsum + gconv + bn + elu ---------------
// grid (2, B*C), 256 thr. Phase 1: stage Ah[i, t] for i=0..7 over the
// block's t-window [tb-8, tb+2056) into 33 KB LDS (graph sum over deg(c)
// neighbor rows; deg/col/avals wave-uniform -> SGPR; neighbor rows L2-hot
// since a full b-slice is 4 MB). One barrier. Phase 2: r10's verified dot2
// gconv body, windows read from LDS (uint2 = ds_read_b64, 8B aligned).
// Window map: thread tile t0 = tb+8*tid needs halfs t0-4..t0+11 ->
// LDS half idx p = 8*tid+4 .. 8*tid+19 (p = t - (tb-8)); max p 2059 < 2064.
// No thread returns before the barrier (r12 lesson: grid exactly (2, B*C)).
__global__ __launch_bounds__(256) void k23_gcn_gconv(
    const unsigned short* __restrict__ in,    // B,F1,C,T f16
    unsigned short* __restrict__ outp,        // B,F1,C,T f16
    const int* __restrict__ deg, const int* __restrict__ col,
    const float* __restrict__ avals,          // 3*8*64*MAXDEG
    const unsigned int* __restrict__ gwh,     // 3*8*8*4 packed f16 pairs
    const float* __restrict__ bnFs, int l)
{
  __shared__ __align__(16) uint4 ash[8 * NCH];   // 33,024 B
  int tid = threadIdx.x;
  int bc = blockIdx.y;                 // b*64+c
  int b = bc >> 6, c = bc & 63;
  int tb = blockIdx.x * 2048;
  int wb = tb - 8;                     // staged range [wb, wb+2064)
  int dg = deg[c];                     // uniform -> s_load
  const int* cp = col + c*MAXDEG;

  // ---- phase 1: stage Ah into LDS ----
  for (int i = 0; i < 8; ++i) {
    const float* av = avals + ((l*8 + i)*64 + c) * MAXDEG;   // uniform
    const unsigned short* rbp = in + (size_t)((b*8 + i) * 64) * T_;
    for (int m = tid; m < NCH; m += 256) {
      int t = wb + 8*m;
      float a[8] = {0,0,0,0,0,0,0,0};
      if (t >= 0 && t + 7 < T_) {
        for (int e = 0; e < dg; ++e) {
          int d = cp[e];               // uniform
          float wv = av[e];            // uniform
          uint4 v = *(const uint4*)(rbp + d*T_ + t);         // 16B aligned
          a[0] = fmaf(wv, lo_h(v.x), a[0]); a[1] = fmaf(wv, hi_h(v.x), a[1]);
          a[2] = fmaf(wv, lo_h(v.y), a[2]); a[3] = fmaf(wv, hi_h(v.y), a[3]);
          a[4] = fmaf(wv, lo_h(v.z), a[4]); a[5] = fmaf(wv, hi_h(v.z), a[5]);
          a[6] = fmaf(wv, lo_h(v.w), a[6]); a[7] = fmaf(wv, hi_h(v.w), a[7]);
        }
      } else if (t + 7 >= 0 && t < T_) {
        for (int e = 0; e < dg; ++e) {
          int d = cp[e];
          float wv = av[e];
          const unsigned short* rp = rbp + d*T_;
          #pragma unroll
          for (int q = 0; q < 8; ++q) {
            int tq = t + q;
            if (tq >= 0 && tq < T_)
              a[q] = fmaf(wv, lo_h((unsigned int)rp[tq]), a[q]);
          }
        }
      }
      uint4 o;
      o.x = pack2h(a[0], a[1]); o.y = pack2h(a[2], a[3]);
      o.z = pack2h(a[4], a[5]); o.w = pack2h(a[6], a[7]);
      ash[i*NCH + m] = o;
    }
  }
  __syncthreads();

  // ---- phase 2: gconv via dot2 + bn + elu (r10 body, LDS windows) ----
  int tile = blockIdx.x * 256 + tid;
  if (tile >= 500) return;
  int t0 = tile * 8;
  float acc[8][8];
  #pragma unroll
  for (int o = 0; o < 8; ++o)
    #pragma unroll
    for (int j = 0; j < 8; ++j) acc[o][j] = 0.0f;
  const unsigned int* gh = gwh + l*256;
  const unsigned int* ab = (const unsigned int*)ash;
  for (int i = 0; i < 8; ++i) {
    const unsigned int* ap = ab + i*LDW + 4*tid + 2;  // byte 16*tid+8: 8B aligned
    unsigned int u[8];
    uint2 q0 = *(const uint2*)(ap);     u[0] = q0.x; u[1] = q0.y;
    uint2 q1 = *(const uint2*)(ap + 2); u[2] = q1.x; u[3] = q1.y;
    uint2 q2 = *(const uint2*)(ap + 4); u[4] = q2.x; u[5] = q2.y;
    uint2 q3 = *(const uint2*)(ap + 6); u[6] = q3.x; u[7] = q3.y;
    unsigned int od[7];
    #pragma unroll
    for (int m = 0; m < 7; ++m) od[m] = (u[m] >> 16) | (u[m+1] << 16);
    #pragma unroll
    for (int o = 0; o < 8; ++o) {
      #pragma unroll
      for (int kp = 0; kp < 4; ++kp) {
        h16x2 wp = as_h2(gh[(o*8 + i)*4 + kp]);      // uniform -> SGPR
        #pragma unroll
        for (int j = 0; j < 8; ++j) {
          unsigned int pr = (j & 1) ? u[((j + 1) >> 1) + kp]
                                    : od[(j >> 1) + kp];
          acc[o][j] = DOT2(wp, as_h2(pr), acc[o][j]);
        }
      }
    }
  }
  #pragma unroll
  for (int o = 0; o < 8; ++o) {
    float sc = bnFs[(l+1)*16 + o], sh = bnFs[(l+1)*16 + 8 + o];
    uint4 v;
    v.x = pack2h(eluf(acc[o][0]*sc + sh), eluf(acc[o][1]*sc + sh));
    v.y = pack2h(eluf(acc[o][2]*sc + sh), eluf(acc[o][3]*sc + sh));
    v.z = pack2h(eluf(acc[o][4]*sc + sh), eluf(acc[o][5]*sc + sh));
    v.w = pack2h(eluf(acc[o][6]*sc + sh), eluf(acc[o][7]*sc + sh));
    *(uint4*)(outp + ((b*8 + o)*64 + c)*T_ + t0) = v;
  }
}

// ---------------- K4: depthwise-over-C + bn + elu + avgpool4. 8 t/thread ---
__global__ __launch_bounds__(256) void k4_dw(
    const unsigned short* __restrict__ in,    // B,F1,C,T f16
    const float* __restrict__ dwn,            // 16x64 (uniform)
    const float* __restrict__ bnsps,
    float* __restrict__ p1)                   // B,16,1000 fp32
{
  int tid = threadIdx.x;
  int bg = blockIdx.y;                 // b*8+g
  int b = bg >> 3, g = bg & 7;
  int tile = blockIdx.x * 256 + tid;
  if (tile >= 500) return;
  int t0 = tile * 8;
  int base = bg * (64 * T_);
  float a0[8] = {0,0,0,0,0,0,0,0}, a1[8] = {0,0,0,0,0,0,0,0};
  for (int cc = 0; cc < 64; ++cc) {
    float w0 = dwn[(2*g)*64 + cc];     // uniform
    float w1 = dwn[(2*g+1)*64 + cc];   // uniform
    uint4 v = *(const uint4*)(in + base + cc*T_ + t0);
    float h[8];
    h[0] = lo_h(v.x); h[1] = hi_h(v.x); h[2] = lo_h(v.y); h[3] = hi_h(v.y);
    h[4] = lo_h(v.z); h[5] = hi_h(v.z); h[6] = lo_h(v.w); h[7] = hi_h(v.w);
    #pragma unroll
    for (int j = 0; j < 8; ++j) {
      a0[j] = fmaf(w0, h[j], a0[j]);
      a1[j] = fmaf(w1, h[j], a1[j]);
    }
  }
  float sc0 = bnsps[2*g],     sh0 = bnsps[16 + 2*g];
  float sc1 = bnsps[2*g + 1], sh1 = bnsps[16 + 2*g + 1];
  int oi = t0 >> 2;
  float2 r0, r1;
  r0.x = 0.25f * (eluf(a0[0]*sc0+sh0) + eluf(a0[1]*sc0+sh0)
                + eluf(a0[2]*sc0+sh0) + eluf(a0[3]*sc0+sh0));
  r0.y = 0.25f * (eluf(a0[4]*sc0+sh0) + eluf(a0[5]*sc0+sh0)
                + eluf(a0[6]*sc0+sh0) + eluf(a0[7]*sc0+sh0));
  r1.x = 0.25f * (eluf(a1[0]*sc1+sh1) + eluf(a1[1]*sc1+sh1)
                + eluf(a1[2]*sc1+sh1) + eluf(a1[3]*sc1+sh1));
  r1.y = 0.25f * (eluf(a1[4]*sc1+sh1) + eluf(a1[5]*sc1+sh1)
                + eluf(a1[6]*sc1+sh1) + eluf(a1[7]*sc1+sh1));
  *(float2*)(p1 + (b*16 + 2*g)*TP_ + oi)     = r0;
  *(float2*)(p1 + (b*16 + 2*g + 1)*TP_ + oi) = r1;
}

// ---------------- K5: sep depthwise(16) + pointwise(16x16) + bn + elu ------
__global__ __launch_bounds__(256) void k5_sep(
    const float* __restrict__ p1,             // B,16,1000
    const float* __restrict__ sdwc,           // 16x16 (uniform)
    const float* __restrict__ pwc,            // 16x16 (uniform)
    const float* __restrict__ bnseps,
    float* __restrict__ p2)                   // B,16,1001
{
  __shared__ float ps[16*272];
  int tid = threadIdx.x;
  int wq = blockIdx.x, b = blockIdx.y;
  int wb = wq * 256;
  for (int ch = 0; ch < 16; ++ch) {
    for (int s = tid; s < 272; s += 256) {
      int t = wb - 8 + s;
      ps[ch*272 + s] = (t >= 0 && t < TP_) ? p1[(b*16 + ch)*TP_ + t] : 0.0f;
    }
  }
  __syncthreads();
  int w0 = wb + tid;
  if (w0 >= W2_) return;
  float dws[16];
  for (int ch = 0; ch < 16; ++ch) {
    float a = 0.0f;
    #pragma unroll
    for (int k = 0; k < 16; ++k)
      a = fmaf(sdwc[ch*16 + k], ps[ch*272 + tid + k], a);
    dws[ch] = a;
  }
  for (int f = 0; f < 16; ++f) {
    float a = 0.0f;
    #pragma unroll
    for (int ch = 0; ch < 16; ++ch) a = fmaf(pwc[f*16 + ch], dws[ch], a);
    float sc = bnseps[f], sh = bnseps[16 + f];
    p2[(b*16 + f)*W2_ + w0] = eluf(a*sc + sh);
  }
}

// ---------------- K6: avgpool8 (first 1000) + fc ---------------------------
__global__ __launch_bounds__(256) void k6_fc(
    const float* __restrict__ p2,             // B,16,1001
    const float* __restrict__ fcwc,           // 4x2000
    const float* __restrict__ fcbc,           // 4
    const int* __restrict__ flag,
    void* __restrict__ outp)                  // B,4
{
  __shared__ float red[4*256];
  int tid = threadIdx.x;
  int b = blockIdx.x;
  float part[4] = {0.0f, 0.0f, 0.0f, 0.0f};
  for (int idx = tid; idx < 2000; idx += 256) {
    int f = idx / 125, q = idx - f*125;
    const float* src = p2 + (b*16 + f)*W2_ + q*8;
    float s = src[0]+src[1]+src[2]+src[3]+src[4]+src[5]+src[6]+src[7];
    float mval = 0.125f * s;
    #pragma unroll
    for (int n = 0; n < 4; ++n) part[n] = fmaf(fcwc[n*2000 + idx], mval, part[n]);
  }
  #pragma unroll
  for (int n = 0; n < 4; ++n) red[n*256 + tid] = part[n];
  __syncthreads();
  for (int s = 128; s > 0; s >>= 1) {
    if (tid < s) {
      #pragma unroll
      for (int n = 0; n < 4; ++n) red[n*256 + tid] += red[n*256 + tid + s];
    }
    __syncthreads();
  }
  if (tid < 4) {
    float val = red[tid*256] + fcbc[tid];
    if (*flag) ((float*)outp)[b*4 + tid] = val;
    else       ((unsigned short*)outp)[b*4 + tid] = f2bf(val);
  }
}

// ---------------------------------------------------------------------------
extern "C" void kernel_launch(void* const* d_in, const int* in_sizes, int n_in,
                              void* d_out, int out_size, void* d_ws, size_t ws_size,
                              hipStream_t stream) {
  const void* x     = d_in[0];
  const void* adj   = d_in[1];
  const void* w1    = d_in[2];
  const void* bnF   = d_in[3];
  const void* imp   = d_in[4];
  const void* gw    = d_in[5];
  const void* dww   = d_in[6];
  const void* bnsp  = d_in[7];
  const void* sdw   = d_in[8];
  const void* pw    = d_in[9];
  const void* bnsep = d_in[10];
  const void* fcw   = d_in[11];
  const void* fcb   = d_in[12];

  char* w = (char*)d_ws;
  const size_t OFF = 262144000;  // after two 131,072,000-byte f16 buffers
  unsigned short* bufA = (unsigned short*)(w);
  unsigned short* bufB = (unsigned short*)(w + 131072000);
  int*   flag   = (int*)  (w + OFF + 0);
  int*   deg    = (int*)  (w + OFF + 256);
  int*   col    = (int*)  (w + OFF + 512);
  float* avals  = (float*)(w + OFF + 4608);
  float* w1c    = (float*)(w + OFF + 102912);
  unsigned int* gwh = (unsigned int*)(w + OFF + 104960);  // 768 uints
  float* dwn    = (float*)(w + OFF + 108032);
  float* sdwc   = (float*)(w + OFF + 112128);
  float* pwc    = (float*)(w + OFF + 113152);
  float* fcwc   = (float*)(w + OFF + 114176);
  float* fcbc   = (float*)(w + OFF + 146176);
  float* bnFs   = (float*)(w + OFF + 146432);
  float* bnsps  = (float*)(w + OFF + 146688);
  float* bnseps = (float*)(w + OFF + 146944);
  float* p1     = (float*)(w + OFF + 147200);
  float* p2     = (float*)(w + OFF + 2195200);

  k0_setup<<<1, 256, 0, stream>>>(adj, imp, dww, w1, bnF, gw, bnsp, sdw, pw,
                                  bnsep, fcw, fcb, flag, deg, col, avals,
                                  w1c, gwh, dwn, sdwc, pwc, fcwc, fcbc,
                                  bnFs, bnsps, bnseps);
  k1_conv1_bn<<<dim3(4, B_*C_), 256, 0, stream>>>(x, w1c, bnFs, flag, bufA);
  for (int l = 0; l < 3; ++l) {
    const unsigned short* src = (l & 1) ? bufB : bufA;
    unsigned short*       dst = (l & 1) ? bufA : bufB;
    k23_gcn_gconv<<<dim3(2, B_*C_), 256, 0, stream>>>(src, dst, deg, col,
                                                      avals, gwh, bnFs, l);
  }
  k4_dw<<<dim3(2, B_*F1_), 256, 0, stream>>>(bufB, dwn, bnsps, p1);
  k5_sep<<<dim3(4, B_), 256, 0, stream>>>(p1, sdwc, pwc, bnseps, p2);
  k6_fc<<<32, 256, 0, stream>>>(p2, fcwc, fcbc, flag, d_out);
}

// Round 2
// 621.095 us; speedup vs baseline: 1.4372x; 1.4372x over previous
//
#include <hip/hip_runtime.h>

// GCN-EEGNet forward, MI355X. Dtype-adaptive (fp32/bf16 detected in K0 via
// adjacency sentinel). Weights in ws, wave-uniform -> SGPR. Intermediates
// f16. Round-15: keep K23 fusion (r14 killed K2's 128 MB HBM round trip)
// but fix its two measured regressions: (a) 8-way LDS bank conflict in
// phase 2 (16B lane stride, 6.16M conflict cycles) -> tile=4 halfs/thread
// gives 8B stride = conflict-free b64; (b) occupancy 30% (33 KB LDS, 4
// blk/CU) -> 16.6 KB LDS + VGPR<=64 via __launch_bounds__(256,8) -> 8
// blk/CU. Staging now uses 32 threads/row, all 8 rows in parallel.
// Bijective XCD swizzle (c fastest, then t-tile, then b): each XCD streams
// one b's 4.1 MB working set ~= its 4 MB L2.
// LESSON (r12): never launch empty blocks in a pattern resonant with id%8
// XCD round-robin. Grid (4, B*C): tail blocks keep 232/256 active threads.
// Pipeline: K0 -> K1 conv1+bn -> 3x K23 -> K4 dw+bn+elu+pool4 -> K5 sep ->
// K6 pool8+fc.

#define B_   32
#define C_   64
#define T_   4000
#define F1_  8
#define TP_  1000
#define W2_  1001
#define MAXDEG 16
#define NC4  130      // uint4 chunks per i-row staged in LDS (1040 halfs)
#define RDW  520      // dwords per i-row (NC4*4)

typedef _Float16 h16x2 __attribute__((ext_vector_type(2)));

static __device__ __forceinline__ float bf2f(unsigned short h) {
  union { unsigned int u; float f; } v; v.u = ((unsigned int)h) << 16; return v.f;
}
static __device__ __forceinline__ unsigned short f2bf(float f) {
  union { float f; unsigned int u; } v; v.f = f;
  unsigned int r = v.u + 0x7FFFu + ((v.u >> 16) & 1u);
  return (unsigned short)(r >> 16);
}
static __device__ __forceinline__ float lo_h(unsigned int u) {
  union { unsigned int u; _Float16 h[2]; } v; v.u = u; return (float)v.h[0];
}
static __device__ __forceinline__ float hi_h(unsigned int u) {
  union { unsigned int u; _Float16 h[2]; } v; v.u = u; return (float)v.h[1];
}
static __device__ __forceinline__ unsigned int pack2h(float a, float b) {
  union { _Float16 h[2]; unsigned int u; } v;
  v.h[0] = (_Float16)a; v.h[1] = (_Float16)b; return v.u;
}
static __device__ __forceinline__ h16x2 as_h2(unsigned int u) {
  union { unsigned int u; h16x2 h; } v; v.u = u; return v.h;
}
#if defined(__has_builtin) && __has_builtin(__builtin_amdgcn_fdot2)
#define DOT2(a, b, c) __builtin_amdgcn_fdot2((a), (b), (c), false)
#else
static __device__ __forceinline__ float dot2_fb(h16x2 a, h16x2 b, float c) {
  return fmaf((float)a[0], (float)b[0], fmaf((float)a[1], (float)b[1], c));
}
#define DOT2(a, b, c) dot2_fb((a), (b), (c))
#endif
static __device__ __forceinline__ float eluf(float z) {
  return z > 0.0f ? z : __expf(z) - 1.0f;
}
static __device__ __forceinline__ float ldin(const void* p, int i, int isf32) {
  return isf32 ? ((const float*)p)[i] : bf2f(((const unsigned short*)p)[i]);
}

// ---------------- K0: dtype detect + canonicalize + CSR + bn fold ----------
__global__ __launch_bounds__(256) void k0_setup(
    const void* __restrict__ adj, const void* __restrict__ imp,
    const void* __restrict__ dww, const void* __restrict__ w1,
    const void* __restrict__ bnF, const void* __restrict__ gw,
    const void* __restrict__ bnsp, const void* __restrict__ sdw,
    const void* __restrict__ pw, const void* __restrict__ bnsep,
    const void* __restrict__ fcw, const void* __restrict__ fcb,
    int* __restrict__ flag, int* __restrict__ deg, int* __restrict__ col,
    float* __restrict__ avals, float* __restrict__ w1c,
    unsigned int* __restrict__ gwh, float* __restrict__ dwn,
    float* __restrict__ sdwc, float* __restrict__ pwc,
    float* __restrict__ fcwc, float* __restrict__ fcbc,
    float* __restrict__ bnFs, float* __restrict__ bnsps,
    float* __restrict__ bnseps)
{
  __shared__ float dwr[1024];
  __shared__ float dsc[16];
  int tid = threadIdx.x;
  int isf32 = (((const float*)adj)[0] == 1.0f) ? 1 : 0;
  if (tid == 0) *flag = isf32;

  for (int i = tid; i < 512;  i += 256) w1c[i]  = ldin(w1, i, isf32);
  // gconv weights packed as f16 pairs: gwh[((l*8+o)*8+i)*4+kp] = (W[2kp],W[2kp+1])
  for (int idx = tid; idx < 768; idx += 256) {
    int kp = idx & 3, i = (idx >> 2) & 7, o = (idx >> 5) & 7, l = idx >> 8;
    int bi = l*512 + (o*8 + i)*8 + 2*kp;
    gwh[idx] = pack2h(ldin(gw, bi, isf32), ldin(gw, bi + 1, isf32));
  }
  for (int i = tid; i < 256;  i += 256) sdwc[i] = ldin(sdw, i, isf32);
  for (int i = tid; i < 256;  i += 256) pwc[i]  = ldin(pw, i, isf32);
  for (int i = tid; i < 8000; i += 256) fcwc[i] = ldin(fcw, i, isf32);
  if (tid < 4) fcbc[tid] = ldin(fcb, tid, isf32);
  for (int i = tid; i < 1024; i += 256) dwr[i] = ldin(dww, i, isf32);

  if (tid < 64) {            // CSR of adjacency (data-driven), self-padded
    int c = tid, n = 0;
    for (int e = 0; e < MAXDEG; ++e) col[c*MAXDEG + e] = c;
    for (int d = 0; d < 64; ++d) {
      if (ldin(adj, c*64 + d, isf32) != 0.0f) {
        if (n < MAXDEG) col[c*MAXDEG + n] = d;
        ++n;
      }
    }
    deg[c] = n < MAXDEG ? n : MAXDEG;
  }
  __syncthreads();
  if (tid < 16) {            // dw norm clamp scale
    float s2 = 0.0f;
    for (int c2 = 0; c2 < 64; ++c2) { float wv = dwr[tid*64 + c2]; s2 += wv*wv; }
    dsc[tid] = fminf(1.0f, 1.0f / fmaxf(sqrtf(s2), 1e-7f));
  }
  if (tid >= 64 && tid < 96) {   // bnF folded scale/shift: 4 stages x 8 ch
    int i = tid - 64, s = i >> 3, f = i & 7;
    float g = ldin(bnF, s*32 + f,      isf32);
    float b = ldin(bnF, s*32 + 8 + f,  isf32);
    float m = ldin(bnF, s*32 + 16 + f, isf32);
    float v = ldin(bnF, s*32 + 24 + f, isf32);
    float sc = g * rsqrtf(v + 1e-3f);
    bnFs[s*16 + f] = sc; bnFs[s*16 + 8 + f] = b - m*sc;
  }
  if (tid >= 96 && tid < 112) {  // bn_sp
    int ch = tid - 96;
    float g = ldin(bnsp, ch, isf32), b = ldin(bnsp, 16 + ch, isf32);
    float m = ldin(bnsp, 32 + ch, isf32), v = ldin(bnsp, 48 + ch, isf32);
    float sc = g * rsqrtf(v + 1e-3f);
    bnsps[ch] = sc; bnsps[16 + ch] = b - m*sc;
  }
  if (tid >= 112 && tid < 128) { // bn_sep
    int ch = tid - 112;
    float g = ldin(bnsep, ch, isf32), b = ldin(bnsep, 16 + ch, isf32);
    float m = ldin(bnsep, 32 + ch, isf32), v = ldin(bnsep, 48 + ch, isf32);
    float sc = g * rsqrtf(v + 1e-3f);
    bnseps[ch] = sc; bnseps[16 + ch] = b - m*sc;
  }
  for (int combo = tid; combo < 3*8*64; combo += 256) {
    int l = combo >> 9, f = (combo >> 6) & 7, c = combo & 63;
    int dg = deg[c];
    for (int e = 0; e < MAXDEG; ++e) {
      float v = 0.0f;
      if (e < dg) {
        int d = col[c*MAXDEG + e];
        v = ldin(adj, c*64 + d, isf32) * ldin(imp, ((l*8 + f)*64 + c)*64 + d, isf32);
      }
      avals[((l*8 + f)*64 + c)*MAXDEG + e] = v;
    }
  }
  __syncthreads();
  for (int i = tid; i < 1024; i += 256) dwn[i] = dwr[i] * dsc[i >> 6];
}

// ---------------- K1: conv1 (64-tap) + bn0. 4 t/thread, SGPR weights -------
// grid (4 t-tiles of 1024, B*C). Stage xs[s] = x[tb-36+s], s in [0,1096):
// base tb-36 makes fp32 float4 (16B) and bf16 uint2 (8B) loads aligned.
__global__ __launch_bounds__(256, 4) void k1_conv1_bn(
    const void* __restrict__ x,               // B,C,T raw dtype
    const float* __restrict__ w1c,            // 8x64 fp32 (uniform -> s_load)
    const float* __restrict__ bnFs,
    const int* __restrict__ flag,
    unsigned short* __restrict__ outp)        // B,F1,C,T f16
{
  __shared__ __align__(16) float xs[1096];
  int tid = threadIdx.x;
  int bc = blockIdx.y;                 // b*64+c
  int b = bc >> 6, c = bc & 63;
  int tb = blockIdx.x * 1024;
  int isf32 = *flag;
  int row = bc * T_;
  if (isf32) {
    const float* xr = (const float*)x + row;
    for (int m = tid; m < 274; m += 256) {
      int tg = tb - 36 + 4*m;
      if (tg >= 0 && tg + 3 < T_) {
        *(float4*)(xs + 4*m) = *(const float4*)(xr + tg);   // 16B aligned
      } else {
        #pragma unroll
        for (int q = 0; q < 4; ++q) {
          int t = tg + q;
          xs[4*m + q] = (t >= 0 && t < T_) ? xr[t] : 0.0f;
        }
      }
    }
  } else {
    const unsigned short* xr = (const unsigned short*)x + row;
    for (int m = tid; m < 274; m += 256) {
      int tg = tb - 36 + 4*m;
      if (tg >= 0 && tg + 3 < T_) {
        uint2 v = *(const uint2*)(xr + tg);                 // 8B aligned
        xs[4*m]     = bf2f((unsigned short)(v.x & 0xFFFFu));
        xs[4*m + 1] = bf2f((unsigned short)(v.x >> 16));
        xs[4*m + 2] = bf2f((unsigned short)(v.y & 0xFFFFu));
        xs[4*m + 3] = bf2f((unsigned short)(v.y >> 16));
      } else {
        #pragma unroll
        for (int q = 0; q < 4; ++q) {
          int t = tg + q;
          xs[4*m + q] = (t >= 0 && t < T_) ? bf2f(xr[t]) : 0.0f;
        }
      }
    }
  }
  __syncthreads();
  int t0 = tb + 4*tid;
  if (t0 >= T_) return;
  float acc[8][4];
  #pragma unroll
  for (int f = 0; f < 8; ++f)
    #pragma unroll
    for (int j = 0; j < 4; ++j) acc[f][j] = 0.0f;
  float4 A4 = *(const float4*)(xs + 4*tid + 4);
  float4 B4 = *(const float4*)(xs + 4*tid + 8);
  for (int cc = 0; cc < 16; ++cc) {
    float ev[7] = {A4.y, A4.z, A4.w, B4.x, B4.y, B4.z, B4.w};
    #pragma unroll
    for (int kk = 0; kk < 4; ++kk) {
      #pragma unroll
      for (int f = 0; f < 8; ++f) {
        float wv = w1c[f*64 + 4*cc + kk];    // uniform -> SGPR
        #pragma unroll
        for (int j = 0; j < 4; ++j) acc[f][j] = fmaf(wv, ev[kk + j], acc[f][j]);
      }
    }
    A4 = B4;
    if (cc < 15) B4 = *(const float4*)(xs + 4*tid + 12 + 4*cc);
  }
  #pragma unroll
  for (int f = 0; f < 8; ++f) {
    float sc = bnFs[f], sh = bnFs[8 + f];
    uint2 st;
    st.x = pack2h(acc[f][0]*sc + sh, acc[f][1]*sc + sh);
    st.y = pack2h(acc[f][2]*sc + sh, acc[f][3]*sc + sh);
    *(uint2*)(outp + ((b*8 + f)*64 + c)*T_ + t0) = st;
  }
}

// ---------------- K23: fused graph einsum + gconv + bn + elu ---------------
// grid (4, B*C), 256 thr, 4 halfs/thread. XCD swizzle: work = (c fastest,
// then t-tile x, then b); XCD k runs b in [4k,4k+4) one at a time ->
// neighbor-row working set 8i x 64c x 1040h x 2B ~= 4.1 MB ~= one L2.
// Phase 1: 32 threads per i-row (all 8 rows parallel, coalesced 512B
// segments), graph sum over deg(c) neighbors into 16.6 KB LDS.
// Phase 2: dot2 gconv; LDS reads at 8B lane stride (conflict-free).
// Window map: t0 = tb+4*tid needs halfs [t0-4, t0+8) -> dwords 2*tid+2
// .. 2*tid+7 (8B aligned); max half idx 4*255+15 = 1035 < 1040.
// No thread returns before the barrier.
__global__ __launch_bounds__(256, 8) void k23_gcn_gconv(
    const unsigned short* __restrict__ in,    // B,F1,C,T f16
    unsigned short* __restrict__ outp,        // B,F1,C,T f16
    const int* __restrict__ deg, const int* __restrict__ col,
    const float* __restrict__ avals,          // 3*8*64*MAXDEG
    const unsigned int* __restrict__ gwh,     // 3*8*8*4 packed f16 pairs
    const float* __restrict__ bnFs, int l)
{
  __shared__ __align__(16) uint4 ash[8 * NC4];   // 16,640 B
  int tid = threadIdx.x;
  // bijective XCD swizzle (8192 blocks, 8 XCDs)
  int wgid = blockIdx.y * 4 + blockIdx.x;
  int swz  = (wgid & 7) * 1024 + (wgid >> 3);
  int c = swz & 63;
  int x = (swz >> 6) & 3;
  int b = swz >> 8;
  int tb = x * 1024;
  int wb = tb - 8;                     // staged range [wb, wb+1040)
  int dg = deg[c];                     // uniform -> s_load
  const int* cp = col + c*MAXDEG;

  // ---- phase 1: stage Ah into LDS, 32 threads per i-row ----
  {
    int i = tid >> 5;                  // 0..7
    int mlane = tid & 31;
    const float* av = avals + ((l*8 + i)*64 + c) * MAXDEG;
    const unsigned short* rbp = in + (size_t)((b*8 + i) * 64) * T_;
    for (int m = mlane; m < NC4; m += 32) {
      int t = wb + 8*m;
      float a[8] = {0,0,0,0,0,0,0,0};
      if (t >= 0 && t + 7 < T_) {
        for (int e = 0; e < dg; ++e) {
          int d = cp[e];               // uniform -> s_load
          float wv = av[e];
          uint4 v = *(const uint4*)(rbp + d*T_ + t);        // 16B aligned
          a[0] = fmaf(wv, lo_h(v.x), a[0]); a[1] = fmaf(wv, hi_h(v.x), a[1]);
          a[2] = fmaf(wv, lo_h(v.y), a[2]); a[3] = fmaf(wv, hi_h(v.y), a[3]);
          a[4] = fmaf(wv, lo_h(v.z), a[4]); a[5] = fmaf(wv, hi_h(v.z), a[5]);
          a[6] = fmaf(wv, lo_h(v.w), a[6]); a[7] = fmaf(wv, hi_h(v.w), a[7]);
        }
      } else if (t + 7 >= 0 && t < T_) {
        for (int e = 0; e < dg; ++e) {
          int d = cp[e];
          float wv = av[e];
          const unsigned short* rp = rbp + d*T_;
          #pragma unroll
          for (int q = 0; q < 8; ++q) {
            int tq = t + q;
            if (tq >= 0 && tq < T_)
              a[q] = fmaf(wv, lo_h((unsigned int)rp[tq]), a[q]);
          }
        }
      }
      uint4 o;
      o.x = pack2h(a[0], a[1]); o.y = pack2h(a[2], a[3]);
      o.z = pack2h(a[4], a[5]); o.w = pack2h(a[6], a[7]);
      ash[i*NC4 + m] = o;
    }
  }
  __syncthreads();

  // ---- phase 2: gconv via dot2 + bn + elu (4 outputs/thread) ----
  int t0 = tb + 4*tid;
  if (t0 >= T_) return;
  float acc[8][4];
  #pragma unroll
  for (int o = 0; o < 8; ++o)
    #pragma unroll
    for (int j = 0; j < 4; ++j) acc[o][j] = 0.0f;
  const unsigned int* gh = gwh + l*256;
  const unsigned int* ab = (const unsigned int*)ash;
  for (int i = 0; i < 8; ++i) {
    const unsigned int* ap = ab + i*RDW + 2*tid + 2;  // 8B aligned, 8B stride
    unsigned int u[6];
    uint2 q0 = *(const uint2*)(ap);     u[0] = q0.x; u[1] = q0.y;
    uint2 q1 = *(const uint2*)(ap + 2); u[2] = q1.x; u[3] = q1.y;
    uint2 q2 = *(const uint2*)(ap + 4); u[4] = q2.x; u[5] = q2.y;
    unsigned int od[5];
    #pragma unroll
    for (int m = 0; m < 5; ++m) od[m] = (u[m] >> 16) | (u[m+1] << 16);
    #pragma unroll
    for (int o = 0; o < 8; ++o) {
      #pragma unroll
      for (int kp = 0; kp < 4; ++kp) {
        h16x2 wp = as_h2(gh[(o*8 + i)*4 + kp]);      // uniform -> SGPR
        #pragma unroll
        for (int j = 0; j < 4; ++j) {
          unsigned int pr = (j & 1) ? u[((j + 1) >> 1) + kp]
                                    : od[(j >> 1) + kp];
          acc[o][j] = DOT2(wp, as_h2(pr), acc[o][j]);
        }
      }
    }
  }
  #pragma unroll
  for (int o = 0; o < 8; ++o) {
    float sc = bnFs[(l+1)*16 + o], sh = bnFs[(l+1)*16 + 8 + o];
    uint2 v;
    v.x = pack2h(eluf(acc[o][0]*sc + sh), eluf(acc[o][1]*sc + sh));
    v.y = pack2h(eluf(acc[o][2]*sc + sh), eluf(acc[o][3]*sc + sh));
    *(uint2*)(outp + ((b*8 + o)*64 + c)*T_ + t0) = v;
  }
}

// ---------------- K4: depthwise-over-C + bn + elu + avgpool4. 8 t/thread ---
__global__ __launch_bounds__(256) void k4_dw(
    const unsigned short* __restrict__ in,    // B,F1,C,T f16
    const float* __restrict__ dwn,            // 16x64 (uniform)
    const float* __restrict__ bnsps,
    float* __restrict__ p1)                   // B,16,1000 fp32
{
  int tid = threadIdx.x;
  int bg = blockIdx.y;                 // b*8+g
  int b = bg >> 3, g = bg & 7;
  int tile = blockIdx.x * 256 + tid;
  if (tile >= 500) return;
  int t0 = tile * 8;
  int base = bg * (64 * T_);
  float a0[8] = {0,0,0,0,0,0,0,0}, a1[8] = {0,0,0,0,0,0,0,0};
  for (int cc = 0; cc < 64; ++cc) {
    float w0 = dwn[(2*g)*64 + cc];     // uniform
    float w1 = dwn[(2*g+1)*64 + cc];   // uniform
    uint4 v = *(const uint4*)(in + base + cc*T_ + t0);
    float h[8];
    h[0] = lo_h(v.x); h[1] = hi_h(v.x); h[2] = lo_h(v.y); h[3] = hi_h(v.y);
    h[4] = lo_h(v.z); h[5] = hi_h(v.z); h[6] = lo_h(v.w); h[7] = hi_h(v.w);
    #pragma unroll
    for (int j = 0; j < 8; ++j) {
      a0[j] = fmaf(w0, h[j], a0[j]);
      a1[j] = fmaf(w1, h[j], a1[j]);
    }
  }
  float sc0 = bnsps[2*g],     sh0 = bnsps[16 + 2*g];
  float sc1 = bnsps[2*g + 1], sh1 = bnsps[16 + 2*g + 1];
  int oi = t0 >> 2;
  float2 r0, r1;
  r0.x = 0.25f * (eluf(a0[0]*sc0+sh0) + eluf(a0[1]*sc0+sh0)
                + eluf(a0[2]*sc0+sh0) + eluf(a0[3]*sc0+sh0));
  r0.y = 0.25f * (eluf(a0[4]*sc0+sh0) + eluf(a0[5]*sc0+sh0)
                + eluf(a0[6]*sc0+sh0) + eluf(a0[7]*sc0+sh0));
  r1.x = 0.25f * (eluf(a1[0]*sc1+sh1) + eluf(a1[1]*sc1+sh1)
                + eluf(a1[2]*sc1+sh1) + eluf(a1[3]*sc1+sh1));
  r1.y = 0.25f * (eluf(a1[4]*sc1+sh1) + eluf(a1[5]*sc1+sh1)
                + eluf(a1[6]*sc1+sh1) + eluf(a1[7]*sc1+sh1));
  *(float2*)(p1 + (b*16 + 2*g)*TP_ + oi)     = r0;
  *(float2*)(p1 + (b*16 + 2*g + 1)*TP_ + oi) = r1;
}

// ---------------- K5: sep depthwise(16) + pointwise(16x16) + bn + elu ------
__global__ __launch_bounds__(256) void k5_sep(
    const float* __restrict__ p1,             // B,16,1000
    const float* __restrict__ sdwc,           // 16x16 (uniform)
    const float* __restrict__ pwc,            // 16x16 (uniform)
    const float* __restrict__ bnseps,
    float* __restrict__ p2)                   // B,16,1001
{
  __shared__ float ps[16*272];
  int tid = threadIdx.x;
  int wq = blockIdx.x, b = blockIdx.y;
  int wb = wq * 256;
  for (int ch = 0; ch < 16; ++ch) {
    for (int s = tid; s < 272; s += 256) {
      int t = wb - 8 + s;
      ps[ch*272 + s] = (t >= 0 && t < TP_) ? p1[(b*16 + ch)*TP_ + t] : 0.0f;
    }
  }
  __syncthreads();
  int w0 = wb + tid;
  if (w0 >= W2_) return;
  float dws[16];
  for (int ch = 0; ch < 16; ++ch) {
    float a = 0.0f;
    #pragma unroll
    for (int k = 0; k < 16; ++k)
      a = fmaf(sdwc[ch*16 + k], ps[ch*272 + tid + k], a);
    dws[ch] = a;
  }
  for (int f = 0; f < 16; ++f) {
    float a = 0.0f;
    #pragma unroll
    for (int ch = 0; ch < 16; ++ch) a = fmaf(pwc[f*16 + ch], dws[ch], a);
    float sc = bnseps[f], sh = bnseps[16 + f];
    p2[(b*16 + f)*W2_ + w0] = eluf(a*sc + sh);
  }
}

// ---------------- K6: avgpool8 (first 1000) + fc ---------------------------
__global__ __launch_bounds__(256) void k6_fc(
    const float* __restrict__ p2,             // B,16,1001
    const float* __restrict__ fcwc,           // 4x2000
    const float* __restrict__ fcbc,           // 4
    const int* __restrict__ flag,
    void* __restrict__ outp)                  // B,4
{
  __shared__ float red[4*256];
  int tid = threadIdx.x;
  int b = blockIdx.x;
  float part[4] = {0.0f, 0.0f, 0.0f, 0.0f};
  for (int idx = tid; idx < 2000; idx += 256) {
    int f = idx / 125, q = idx - f*125;
    const float* src = p2 + (b*16 + f)*W2_ + q*8;
    float s = src[0]+src[1]+src[2]+src[3]+src[4]+src[5]+src[6]+src[7];
    float mval = 0.125f * s;
    #pragma unroll
    for (int n = 0; n < 4; ++n) part[n] = fmaf(fcwc[n*2000 + idx], mval, part[n]);
  }
  #pragma unroll
  for (int n = 0; n < 4; ++n) red[n*256 + tid] = part[n];
  __syncthreads();
  for (int s = 128; s > 0; s >>= 1) {
    if (tid < s) {
      #pragma unroll
      for (int n = 0; n < 4; ++n) red[n*256 + tid] += red[n*256 + tid + s];
    }
    __syncthreads();
  }
  if (tid < 4) {
    float val = red[tid*256] + fcbc[tid];
    if (*flag) ((float*)outp)[b*4 + tid] = val;
    else       ((unsigned short*)outp)[b*4 + tid] = f2bf(val);
  }
}

// ---------------------------------------------------------------------------
extern "C" void kernel_launch(void* const* d_in, const int* in_sizes, int n_in,
                              void* d_out, int out_size, void* d_ws, size_t ws_size,
                              hipStream_t stream) {
  const void* x     = d_in[0];
  const void* adj   = d_in[1];
  const void* w1    = d_in[2];
  const void* bnF   = d_in[3];
  const void* imp   = d_in[4];
  const void* gw    = d_in[5];
  const void* dww   = d_in[6];
  const void* bnsp  = d_in[7];
  const void* sdw   = d_in[8];
  const void* pw    = d_in[9];
  const void* bnsep = d_in[10];
  const void* fcw   = d_in[11];
  const void* fcb   = d_in[12];

  char* w = (char*)d_ws;
  const size_t OFF = 262144000;  // after two 131,072,000-byte f16 buffers
  unsigned short* bufA = (unsigned short*)(w);
  unsigned short* bufB = (unsigned short*)(w + 131072000);
  int*   flag   = (int*)  (w + OFF + 0);
  int*   deg    = (int*)  (w + OFF + 256);
  int*   col    = (int*)  (w + OFF + 512);
  float* avals  = (float*)(w + OFF + 4608);
  float* w1c    = (float*)(w + OFF + 102912);
  unsigned int* gwh = (unsigned int*)(w + OFF + 104960);  // 768 uints
  float* dwn    = (float*)(w + OFF + 108032);
  float* sdwc   = (float*)(w + OFF + 112128);
  float* pwc    = (float*)(w + OFF + 113152);
  float* fcwc   = (float*)(w + OFF + 114176);
  float* fcbc   = (float*)(w + OFF + 146176);
  float* bnFs   = (float*)(w + OFF + 146432);
  float* bnsps  = (float*)(w + OFF + 146688);
  float* bnseps = (float*)(w + OFF + 146944);
  float* p1     = (float*)(w + OFF + 147200);
  float* p2     = (float*)(w + OFF + 2195200);

  k0_setup<<<1, 256, 0, stream>>>(adj, imp, dww, w1, bnF, gw, bnsp, sdw, pw,
                                  bnsep, fcw, fcb, flag, deg, col, avals,
                                  w1c, gwh, dwn, sdwc, pwc, fcwc, fcbc,
                                  bnFs, bnsps, bnseps);
  k1_conv1_bn<<<dim3(4, B_*C_), 256, 0, stream>>>(x, w1c, bnFs, flag, bufA);
  for (int l = 0; l < 3; ++l) {
    const unsigned short* src = (l & 1) ? bufB : bufA;
    unsigned short*       dst = (l & 1) ? bufA : bufB;
    k23_gcn_gconv<<<dim3(4, B_*C_), 256, 0, stream>>>(src, dst, deg, col,
                                                      avals, gwh, bnFs, l);
  }
  k4_dw<<<dim3(2, B_*F1_), 256, 0, stream>>>(bufB, dwn, bnsps, p1);
  k5_sep<<<dim3(4, B_), 256, 0, stream>>>(p1, sdwc, pwc, bnseps, p2);
  k6_fc<<<32, 256, 0, stream>>>(p2, fcwc, fcbc, flag, d_out);
}

// Round 3
// 569.791 us; speedup vs baseline: 1.5666x; 1.0900x over previous
//
#include <hip/hip_runtime.h>

// GCN-EEGNet forward, MI355X. Dtype-adaptive (fp32/bf16 detected in K0 via
// adjacency sentinel). Weights in ws, wave-uniform -> SGPR. Intermediates
// f16. Round-16: k23 phase 2 moved from dot2 (VALU) to MFMA. r15 counters:
// VALUBusy 77%, MfmaUtil 0.0, HBM 18% -> the matrix pipe idles while VALU
// does 2.1e9 dot2/layer. gconv is a GEMM per (b,c): Out[t,o] = sum_k
// X[t,k64] W[k64,o], k64 = (i,k). mfma_f32_16x16x32_f16, 2 per 16-t tile:
//   A (16x32): lane l -> row t'=l&15, k = 8*(l>>4)+r  => 8 consecutive LDS
//     halfs from row i=(l>>4) (+4 for MFMA1) at S = t_base + (l&15) + 5;
//     gathered via 3x ds_read_b64 + 5 cndmask + 4 alignbit (lane-const sel).
//   B (32x16): lane l -> col o=l&15, k = 8*(l>>4)+r => weights, precomputed
//     per-lane in K0 (wmf), loaded once into 8 VGPRs (zero for o>=8).
//   C/D (m89-verified, dtype-indep): col=lane&15=o, row=4*(l>>4)+reg=t' =>
//     each lane stores 4 consecutive t as one 8B store (masked m<8, t<T).
// Phase 1 (graph einsum staging) unchanged. LDS row stride 130 uint4.
// LESSON (r12): no empty blocks resonant with id%8 XCD rr. Grid (4, B*C).
// LESSON (r15): XCD swizzle (c fastest, then t, then b) -> FETCH 66 MB.
// Pipeline: K0 -> K1 conv1+bn -> 3x K23 -> K4 dw+bn+elu+pool4 -> K5 sep ->
// K6 pool8+fc.

#define B_   32
#define C_   64
#define T_   4000
#define F1_  8
#define TP_  1000
#define W2_  1001
#define MAXDEG 16
#define ROW4 130      // uint4 chunks per i-row staged in LDS (1040 halfs)
#define ROWB 2080     // bytes per i-row

typedef _Float16 h16x2 __attribute__((ext_vector_type(2)));
typedef _Float16 f16x8 __attribute__((ext_vector_type(8)));
typedef float    f32x4 __attribute__((ext_vector_type(4)));

static __device__ __forceinline__ float bf2f(unsigned short h) {
  union { unsigned int u; float f; } v; v.u = ((unsigned int)h) << 16; return v.f;
}
static __device__ __forceinline__ unsigned short f2bf(float f) {
  union { float f; unsigned int u; } v; v.f = f;
  unsigned int r = v.u + 0x7FFFu + ((v.u >> 16) & 1u);
  return (unsigned short)(r >> 16);
}
static __device__ __forceinline__ float lo_h(unsigned int u) {
  union { unsigned int u; _Float16 h[2]; } v; v.u = u; return (float)v.h[0];
}
static __device__ __forceinline__ float hi_h(unsigned int u) {
  union { unsigned int u; _Float16 h[2]; } v; v.u = u; return (float)v.h[1];
}
static __device__ __forceinline__ unsigned int pack2h(float a, float b) {
  union { _Float16 h[2]; unsigned int u; } v;
  v.h[0] = (_Float16)a; v.h[1] = (_Float16)b; return v.u;
}
static __device__ __forceinline__ unsigned int alignb(unsigned int hi,
                                                      unsigned int lo,
                                                      unsigned int s) {
  // s in {0,16}; folds to v_alignbit_b32
  return (unsigned int)(((((unsigned long long)hi) << 32) | lo) >> s);
}
static __device__ __forceinline__ float eluf(float z) {
  return z > 0.0f ? z : __expf(z) - 1.0f;
}
static __device__ __forceinline__ float ldin(const void* p, int i, int isf32) {
  return isf32 ? ((const float*)p)[i] : bf2f(((const unsigned short*)p)[i]);
}

// ---------------- K0: dtype detect + canonicalize + CSR + bn fold ----------
__global__ __launch_bounds__(256) void k0_setup(
    const void* __restrict__ adj, const void* __restrict__ imp,
    const void* __restrict__ dww, const void* __restrict__ w1,
    const void* __restrict__ bnF, const void* __restrict__ gw,
    const void* __restrict__ bnsp, const void* __restrict__ sdw,
    const void* __restrict__ pw, const void* __restrict__ bnsep,
    const void* __restrict__ fcw, const void* __restrict__ fcb,
    int* __restrict__ flag, int* __restrict__ deg, int* __restrict__ col,
    float* __restrict__ avals, float* __restrict__ w1c,
    uint4* __restrict__ wmf, float* __restrict__ dwn,
    float* __restrict__ sdwc, float* __restrict__ pwc,
    float* __restrict__ fcwc, float* __restrict__ fcbc,
    float* __restrict__ bnFs, float* __restrict__ bnsps,
    float* __restrict__ bnseps)
{
  __shared__ float dwr[1024];
  __shared__ float dsc[16];
  int tid = threadIdx.x;
  int isf32 = (((const float*)adj)[0] == 1.0f) ? 1 : 0;
  if (tid == 0) *flag = isf32;

  for (int i = tid; i < 512;  i += 256) w1c[i]  = ldin(w1, i, isf32);
  // MFMA B-fragments: wmf[(layer*2+frag)*64 + lane] = uint4 of 8 f16:
  // W[o=lane&15][i=(lane>>4)+4*frag][k=0..7], zero for o>=8.
  for (int idx = tid; idx < 384; idx += 256) {
    int lf = idx >> 6;            // layer*2+frag
    int layer = lf >> 1, frag = lf & 1;
    int lane2 = idx & 63;
    int o = lane2 & 15, ii = (lane2 >> 4) + 4*frag;
    uint4 v; v.x = 0u; v.y = 0u; v.z = 0u; v.w = 0u;
    if (o < 8) {
      int bi = layer*512 + (o*8 + ii)*8;
      v.x = pack2h(ldin(gw, bi+0, isf32), ldin(gw, bi+1, isf32));
      v.y = pack2h(ldin(gw, bi+2, isf32), ldin(gw, bi+3, isf32));
      v.z = pack2h(ldin(gw, bi+4, isf32), ldin(gw, bi+5, isf32));
      v.w = pack2h(ldin(gw, bi+6, isf32), ldin(gw, bi+7, isf32));
    }
    wmf[idx] = v;
  }
  for (int i = tid; i < 256;  i += 256) sdwc[i] = ldin(sdw, i, isf32);
  for (int i = tid; i < 256;  i += 256) pwc[i]  = ldin(pw, i, isf32);
  for (int i = tid; i < 8000; i += 256) fcwc[i] = ldin(fcw, i, isf32);
  if (tid < 4) fcbc[tid] = ldin(fcb, tid, isf32);
  for (int i = tid; i < 1024; i += 256) dwr[i] = ldin(dww, i, isf32);

  if (tid < 64) {            // CSR of adjacency (data-driven), self-padded
    int c = tid, n = 0;
    for (int e = 0; e < MAXDEG; ++e) col[c*MAXDEG + e] = c;
    for (int d = 0; d < 64; ++d) {
      if (ldin(adj, c*64 + d, isf32) != 0.0f) {
        if (n < MAXDEG) col[c*MAXDEG + n] = d;
        ++n;
      }
    }
    deg[c] = n < MAXDEG ? n : MAXDEG;
  }
  __syncthreads();
  if (tid < 16) {            // dw norm clamp scale
    float s2 = 0.0f;
    for (int c2 = 0; c2 < 64; ++c2) { float wv = dwr[tid*64 + c2]; s2 += wv*wv; }
    dsc[tid] = fminf(1.0f, 1.0f / fmaxf(sqrtf(s2), 1e-7f));
  }
  if (tid >= 64 && tid < 96) {   // bnF folded scale/shift: 4 stages x 8 ch
    int i = tid - 64, s = i >> 3, f = i & 7;
    float g = ldin(bnF, s*32 + f,      isf32);
    float b = ldin(bnF, s*32 + 8 + f,  isf32);
    float m = ldin(bnF, s*32 + 16 + f, isf32);
    float v = ldin(bnF, s*32 + 24 + f, isf32);
    float sc = g * rsqrtf(v + 1e-3f);
    bnFs[s*16 + f] = sc; bnFs[s*16 + 8 + f] = b - m*sc;
  }
  if (tid >= 96 && tid < 112) {  // bn_sp
    int ch = tid - 96;
    float g = ldin(bnsp, ch, isf32), b = ldin(bnsp, 16 + ch, isf32);
    float m = ldin(bnsp, 32 + ch, isf32), v = ldin(bnsp, 48 + ch, isf32);
    float sc = g * rsqrtf(v + 1e-3f);
    bnsps[ch] = sc; bnsps[16 + ch] = b - m*sc;
  }
  if (tid >= 112 && tid < 128) { // bn_sep
    int ch = tid - 112;
    float g = ldin(bnsep, ch, isf32), b = ldin(bnsep, 16 + ch, isf32);
    float m = ldin(bnsep, 32 + ch, isf32), v = ldin(bnsep, 48 + ch, isf32);
    float sc = g * rsqrtf(v + 1e-3f);
    bnseps[ch] = sc; bnseps[16 + ch] = b - m*sc;
  }
  for (int combo = tid; combo < 3*8*64; combo += 256) {
    int l = combo >> 9, f = (combo >> 6) & 7, c = combo & 63;
    int dg = deg[c];
    for (int e = 0; e < MAXDEG; ++e) {
      float v = 0.0f;
      if (e < dg) {
        int d = col[c*MAXDEG + e];
        v = ldin(adj, c*64 + d, isf32) * ldin(imp, ((l*8 + f)*64 + c)*64 + d, isf32);
      }
      avals[((l*8 + f)*64 + c)*MAXDEG + e] = v;
    }
  }
  __syncthreads();
  for (int i = tid; i < 1024; i += 256) dwn[i] = dwr[i] * dsc[i >> 6];
}

// ---------------- K1: conv1 (64-tap) + bn0. 4 t/thread, SGPR weights -------
// grid (4 t-tiles of 1024, B*C). Stage xs[s] = x[tb-36+s], s in [0,1096):
// base tb-36 makes fp32 float4 (16B) and bf16 uint2 (8B) loads aligned.
__global__ __launch_bounds__(256, 4) void k1_conv1_bn(
    const void* __restrict__ x,               // B,C,T raw dtype
    const float* __restrict__ w1c,            // 8x64 fp32 (uniform -> s_load)
    const float* __restrict__ bnFs,
    const int* __restrict__ flag,
    unsigned short* __restrict__ outp)        // B,F1,C,T f16
{
  __shared__ __align__(16) float xs[1096];
  int tid = threadIdx.x;
  int bc = blockIdx.y;                 // b*64+c
  int b = bc >> 6, c = bc & 63;
  int tb = blockIdx.x * 1024;
  int isf32 = *flag;
  int row = bc * T_;
  if (isf32) {
    const float* xr = (const float*)x + row;
    for (int m = tid; m < 274; m += 256) {
      int tg = tb - 36 + 4*m;
      if (tg >= 0 && tg + 3 < T_) {
        *(float4*)(xs + 4*m) = *(const float4*)(xr + tg);   // 16B aligned
      } else {
        #pragma unroll
        for (int q = 0; q < 4; ++q) {
          int t = tg + q;
          xs[4*m + q] = (t >= 0 && t < T_) ? xr[t] : 0.0f;
        }
      }
    }
  } else {
    const unsigned short* xr = (const unsigned short*)x + row;
    for (int m = tid; m < 274; m += 256) {
      int tg = tb - 36 + 4*m;
      if (tg >= 0 && tg + 3 < T_) {
        uint2 v = *(const uint2*)(xr + tg);                 // 8B aligned
        xs[4*m]     = bf2f((unsigned short)(v.x & 0xFFFFu));
        xs[4*m + 1] = bf2f((unsigned short)(v.x >> 16));
        xs[4*m + 2] = bf2f((unsigned short)(v.y & 0xFFFFu));
        xs[4*m + 3] = bf2f((unsigned short)(v.y >> 16));
      } else {
        #pragma unroll
        for (int q = 0; q < 4; ++q) {
          int t = tg + q;
          xs[4*m + q] = (t >= 0 && t < T_) ? bf2f(xr[t]) : 0.0f;
        }
      }
    }
  }
  __syncthreads();
  int t0 = tb + 4*tid;
  if (t0 >= T_) return;
  float acc[8][4];
  #pragma unroll
  for (int f = 0; f < 8; ++f)
    #pragma unroll
    for (int j = 0; j < 4; ++j) acc[f][j] = 0.0f;
  float4 A4 = *(const float4*)(xs + 4*tid + 4);
  float4 B4 = *(const float4*)(xs + 4*tid + 8);
  for (int cc = 0; cc < 16; ++cc) {
    float ev[7] = {A4.y, A4.z, A4.w, B4.x, B4.y, B4.z, B4.w};
    #pragma unroll
    for (int kk = 0; kk < 4; ++kk) {
      #pragma unroll
      for (int f = 0; f < 8; ++f) {
        float wv = w1c[f*64 + 4*cc + kk];    // uniform -> SGPR
        #pragma unroll
        for (int j = 0; j < 4; ++j) acc[f][j] = fmaf(wv, ev[kk + j], acc[f][j]);
      }
    }
    A4 = B4;
    if (cc < 15) B4 = *(const float4*)(xs + 4*tid + 12 + 4*cc);
  }
  #pragma unroll
  for (int f = 0; f < 8; ++f) {
    float sc = bnFs[f], sh = bnFs[8 + f];
    uint2 st;
    st.x = pack2h(acc[f][0]*sc + sh, acc[f][1]*sc + sh);
    st.y = pack2h(acc[f][2]*sc + sh, acc[f][3]*sc + sh);
    *(uint2*)(outp + ((b*8 + f)*64 + c)*T_ + t0) = st;
  }
}

// ---------------- K23: fused graph einsum + MFMA gconv + bn + elu ----------
// grid (4, B*C), 256 thr. XCD swizzle: work = (c fastest, t-tile, b).
// Phase 1: 32 threads per i-row stage Ah (graph sum) into 16.6 KB LDS,
//   p = t - tb + 8, p in [0,1040), zero outside [0,T).
// Phase 2: per wave (4 waves x 256 t): 16 tiles of 16 t. Per tile lane l:
//   A-frag rows t'=l&15, k=8q+r (q=l>>4): 8 halfs from LDS row i=q (i=q+4
//   for MFMA1) starting at S = t_base + (l&15) + 5; b=S&3 lane-const ->
//   3x b64 + 5 cndmask + 4 alignbit. acc = mfma(A1,B1, mfma(A0,B0, 0)).
//   D: col=o=l&15 (<8 valid), rows t'=4q+reg -> 8B store per lane.
__global__ __launch_bounds__(256, 6) void k23_gcn_gconv(
    const unsigned short* __restrict__ in,    // B,F1,C,T f16
    unsigned short* __restrict__ outp,        // B,F1,C,T f16
    const int* __restrict__ deg, const int* __restrict__ col,
    const float* __restrict__ avals,          // 3*8*64*MAXDEG
    const uint4* __restrict__ wmf,            // 6*64 B-fragments
    const float* __restrict__ bnFs, int l)
{
  __shared__ __align__(16) uint4 ash[8 * ROW4];   // 16,640 B
  int tid = threadIdx.x;
  // bijective XCD swizzle (8192 blocks, 8 XCDs)
  int wgid = blockIdx.y * 4 + blockIdx.x;
  int swz  = (wgid & 7) * 1024 + (wgid >> 3);
  int c = swz & 63;
  int xt = (swz >> 6) & 3;
  int b = swz >> 8;
  int tb = xt * 1024;
  int wb = tb - 8;                     // staged range [wb, wb+1040)
  int dg = deg[c];                     // uniform -> s_load
  const int* cp = col + c*MAXDEG;

  // ---- phase 1: stage Ah into LDS, 32 threads per i-row ----
  {
    int i = tid >> 5;                  // 0..7
    int mlane = tid & 31;
    const float* av = avals + ((l*8 + i)*64 + c) * MAXDEG;
    const unsigned short* rbp = in + (size_t)((b*8 + i) * 64) * T_;
    for (int m = mlane; m < ROW4; m += 32) {
      int t = wb + 8*m;
      float a[8] = {0,0,0,0,0,0,0,0};
      if (t >= 0 && t + 7 < T_) {
        for (int e = 0; e < dg; ++e) {
          int d = cp[e];               // uniform -> s_load
          float wv = av[e];
          uint4 v = *(const uint4*)(rbp + d*T_ + t);        // 16B aligned
          a[0] = fmaf(wv, lo_h(v.x), a[0]); a[1] = fmaf(wv, hi_h(v.x), a[1]);
          a[2] = fmaf(wv, lo_h(v.y), a[2]); a[3] = fmaf(wv, hi_h(v.y), a[3]);
          a[4] = fmaf(wv, lo_h(v.z), a[4]); a[5] = fmaf(wv, hi_h(v.z), a[5]);
          a[6] = fmaf(wv, lo_h(v.w), a[6]); a[7] = fmaf(wv, hi_h(v.w), a[7]);
        }
      } else if (t + 7 >= 0 && t < T_) {
        for (int e = 0; e < dg; ++e) {
          int d = cp[e];
          float wv = av[e];
          const unsigned short* rp = rbp + d*T_;
          #pragma unroll
          for (int q = 0; q < 8; ++q) {
            int tq = t + q;
            if (tq >= 0 && tq < T_)
              a[q] = fmaf(wv, lo_h((unsigned int)rp[tq]), a[q]);
          }
        }
      }
      uint4 o;
      o.x = pack2h(a[0], a[1]); o.y = pack2h(a[2], a[3]);
      o.z = pack2h(a[4], a[5]); o.w = pack2h(a[6], a[7]);
      ash[i*ROW4 + m] = o;
    }
  }
  __syncthreads();

  // ---- phase 2: MFMA gconv ----
  int lane = tid & 63;
  int wv4 = tid >> 6;                  // wave 0..3
  int m = lane & 15, q = lane >> 4;
  union { uint4 u; f16x8 h; } w0u, w1u;
  w0u.u = wmf[(l*2 + 0)*64 + lane];
  w1u.u = wmf[(l*2 + 1)*64 + lane];
  int o8 = (m < 8) ? m : 0;
  float sc  = bnFs[(l+1)*16 + o8];
  float shb = bnFs[(l+1)*16 + 8 + o8];
  int Sm = m + 5;                      // S = t_base + Sm (t_base % 16 == 0)
  unsigned shv = ((unsigned)Sm & 1u) * 16u;
  int bhi = (Sm >> 1) & 1;             // (S&3)>=2
  int a0b = q*ROWB + ((2*Sm) & ~7);
  const char* ashc = (const char*)ash;
  unsigned short* orow = outp + (size_t)((b*8 + o8)*64 + c) * T_;
  #pragma unroll 2
  for (int tile = 0; tile < 16; ++tile) {
    int t_base = wv4*256 + tile*16;
    int off = a0b + 2*t_base;
    const uint2* pa0 = (const uint2*)(ashc + off);
    uint2 x0 = pa0[0], x1 = pa0[1], x2 = pa0[2];
    const uint2* pa1 = (const uint2*)(ashc + off + 4*ROWB);
    uint2 y0 = pa1[0], y1 = pa1[1], y2 = pa1[2];
    unsigned ua[6] = {x0.x, x0.y, x1.x, x1.y, x2.x, x2.y};
    unsigned ub[6] = {y0.x, y0.y, y1.x, y1.y, y2.x, y2.y};
    union { unsigned d[4]; f16x8 h; } A0, A1;
    #pragma unroll
    for (int j = 0; j < 4; ++j) {
      unsigned vlo = bhi ? ua[j+1] : ua[j];
      unsigned vhi = bhi ? ua[j+2] : ua[j+1];
      A0.d[j] = alignb(vhi, vlo, shv);
      unsigned wlo = bhi ? ub[j+1] : ub[j];
      unsigned whi = bhi ? ub[j+2] : ub[j+1];
      A1.d[j] = alignb(whi, wlo, shv);
    }
    f32x4 acc = {0.0f, 0.0f, 0.0f, 0.0f};
    acc = __builtin_amdgcn_mfma_f32_16x16x32_f16(A0.h, w0u.h, acc, 0, 0, 0);
    acc = __builtin_amdgcn_mfma_f32_16x16x32_f16(A1.h, w1u.h, acc, 0, 0, 0);
    int t0g = tb + t_base + 4*q;
    if (m < 8 && t0g < T_) {
      float e0 = eluf(acc[0]*sc + shb);
      float e1 = eluf(acc[1]*sc + shb);
      float e2 = eluf(acc[2]*sc + shb);
      float e3 = eluf(acc[3]*sc + shb);
      uint2 st; st.x = pack2h(e0, e1); st.y = pack2h(e2, e3);
      *(uint2*)(orow + t0g) = st;
    }
  }
}

// ---------------- K4: depthwise-over-C + bn + elu + avgpool4. 8 t/thread ---
__global__ __launch_bounds__(256) void k4_dw(
    const unsigned short* __restrict__ in,    // B,F1,C,T f16
    const float* __restrict__ dwn,            // 16x64 (uniform)
    const float* __restrict__ bnsps,
    float* __restrict__ p1)                   // B,16,1000 fp32
{
  int tid = threadIdx.x;
  int bg = blockIdx.y;                 // b*8+g
  int b = bg >> 3, g = bg & 7;
  int tile = blockIdx.x * 256 + tid;
  if (tile >= 500) return;
  int t0 = tile * 8;
  int base = bg * (64 * T_);
  float a0[8] = {0,0,0,0,0,0,0,0}, a1[8] = {0,0,0,0,0,0,0,0};
  for (int cc = 0; cc < 64; ++cc) {
    float w0 = dwn[(2*g)*64 + cc];     // uniform
    float w1 = dwn[(2*g+1)*64 + cc];   // uniform
    uint4 v = *(const uint4*)(in + base + cc*T_ + t0);
    float h[8];
    h[0] = lo_h(v.x); h[1] = hi_h(v.x); h[2] = lo_h(v.y); h[3] = hi_h(v.y);
    h[4] = lo_h(v.z); h[5] = hi_h(v.z); h[6] = lo_h(v.w); h[7] = hi_h(v.w);
    #pragma unroll
    for (int j = 0; j < 8; ++j) {
      a0[j] = fmaf(w0, h[j], a0[j]);
      a1[j] = fmaf(w1, h[j], a1[j]);
    }
  }
  float sc0 = bnsps[2*g],     sh0 = bnsps[16 + 2*g];
  float sc1 = bnsps[2*g + 1], sh1 = bnsps[16 + 2*g + 1];
  int oi = t0 >> 2;
  float2 r0, r1;
  r0.x = 0.25f * (eluf(a0[0]*sc0+sh0) + eluf(a0[1]*sc0+sh0)
                + eluf(a0[2]*sc0+sh0) + eluf(a0[3]*sc0+sh0));
  r0.y = 0.25f * (eluf(a0[4]*sc0+sh0) + eluf(a0[5]*sc0+sh0)
                + eluf(a0[6]*sc0+sh0) + eluf(a0[7]*sc0+sh0));
  r1.x = 0.25f * (eluf(a1[0]*sc1+sh1) + eluf(a1[1]*sc1+sh1)
                + eluf(a1[2]*sc1+sh1) + eluf(a1[3]*sc1+sh1));
  r1.y = 0.25f * (eluf(a1[4]*sc1+sh1) + eluf(a1[5]*sc1+sh1)
                + eluf(a1[6]*sc1+sh1) + eluf(a1[7]*sc1+sh1));
  *(float2*)(p1 + (b*16 + 2*g)*TP_ + oi)     = r0;
  *(float2*)(p1 + (b*16 + 2*g + 1)*TP_ + oi) = r1;
}

// ---------------- K5: sep depthwise(16) + pointwise(16x16) + bn + elu ------
__global__ __launch_bounds__(256) void k5_sep(
    const float* __restrict__ p1,             // B,16,1000
    const float* __restrict__ sdwc,           // 16x16 (uniform)
    const float* __restrict__ pwc,            // 16x16 (uniform)
    const float* __restrict__ bnseps,
    float* __restrict__ p2)                   // B,16,1001
{
  __shared__ float ps[16*272];
  int tid = threadIdx.x;
  int wq = blockIdx.x, b = blockIdx.y;
  int wb = wq * 256;
  for (int ch = 0; ch < 16; ++ch) {
    for (int s = tid; s < 272; s += 256) {
      int t = wb - 8 + s;
      ps[ch*272 + s] = (t >= 0 && t < TP_) ? p1[(b*16 + ch)*TP_ + t] : 0.0f;
    }
  }
  __syncthreads();
  int w0 = wb + tid;
  if (w0 >= W2_) return;
  float dws[16];
  for (int ch = 0; ch < 16; ++ch) {
    float a = 0.0f;
    #pragma unroll
    for (int k = 0; k < 16; ++k)
      a = fmaf(sdwc[ch*16 + k], ps[ch*272 + tid + k], a);
    dws[ch] = a;
  }
  for (int f = 0; f < 16; ++f) {
    float a = 0.0f;
    #pragma unroll
    for (int ch = 0; ch < 16; ++ch) a = fmaf(pwc[f*16 + ch], dws[ch], a);
    float sc = bnseps[f], sh = bnseps[16 + f];
    p2[(b*16 + f)*W2_ + w0] = eluf(a*sc + sh);
  }
}

// ---------------- K6: avgpool8 (first 1000) + fc ---------------------------
__global__ __launch_bounds__(256) void k6_fc(
    const float* __restrict__ p2,             // B,16,1001
    const float* __restrict__ fcwc,           // 4x2000
    const float* __restrict__ fcbc,           // 4
    const int* __restrict__ flag,
    void* __restrict__ outp)                  // B,4
{
  __shared__ float red[4*256];
  int tid = threadIdx.x;
  int b = blockIdx.x;
  float part[4] = {0.0f, 0.0f, 0.0f, 0.0f};
  for (int idx = tid; idx < 2000; idx += 256) {
    int f = idx / 125, q = idx - f*125;
    const float* src = p2 + (b*16 + f)*W2_ + q*8;
    float s = src[0]+src[1]+src[2]+src[3]+src[4]+src[5]+src[6]+src[7];
    float mval = 0.125f * s;
    #pragma unroll
    for (int n = 0; n < 4; ++n) part[n] = fmaf(fcwc[n*2000 + idx], mval, part[n]);
  }
  #pragma unroll
  for (int n = 0; n < 4; ++n) red[n*256 + tid] = part[n];
  __syncthreads();
  for (int s = 128; s > 0; s >>= 1) {
    if (tid < s) {
      #pragma unroll
      for (int n = 0; n < 4; ++n) red[n*256 + tid] += red[n*256 + tid + s];
    }
    __syncthreads();
  }
  if (tid < 4) {
    float val = red[tid*256] + fcbc[tid];
    if (*flag) ((float*)outp)[b*4 + tid] = val;
    else       ((unsigned short*)outp)[b*4 + tid] = f2bf(val);
  }
}

// ---------------------------------------------------------------------------
extern "C" void kernel_launch(void* const* d_in, const int* in_sizes, int n_in,
                              void* d_out, int out_size, void* d_ws, size_t ws_size,
                              hipStream_t stream) {
  const void* x     = d_in[0];
  const void* adj   = d_in[1];
  const void* w1    = d_in[2];
  const void* bnF   = d_in[3];
  const void* imp   = d_in[4];
  const void* gw    = d_in[5];
  const void* dww   = d_in[6];
  const void* bnsp  = d_in[7];
  const void* sdw   = d_in[8];
  const void* pw    = d_in[9];
  const void* bnsep = d_in[10];
  const void* fcw   = d_in[11];
  const void* fcb   = d_in[12];

  char* w = (char*)d_ws;
  const size_t OFF = 262144000;  // after two 131,072,000-byte f16 buffers
  unsigned short* bufA = (unsigned short*)(w);
  unsigned short* bufB = (unsigned short*)(w + 131072000);
  int*   flag   = (int*)  (w + OFF + 0);
  int*   deg    = (int*)  (w + OFF + 256);
  int*   col    = (int*)  (w + OFF + 512);
  float* avals  = (float*)(w + OFF + 4608);
  float* w1c    = (float*)(w + OFF + 102912);
  float* dwn    = (float*)(w + OFF + 108032);
  float* sdwc   = (float*)(w + OFF + 112128);
  float* pwc    = (float*)(w + OFF + 113152);
  float* fcwc   = (float*)(w + OFF + 114176);
  float* fcbc   = (float*)(w + OFF + 146176);
  float* bnFs   = (float*)(w + OFF + 146432);
  float* bnsps  = (float*)(w + OFF + 146688);
  float* bnseps = (float*)(w + OFF + 146944);
  float* p1     = (float*)(w + OFF + 147200);
  float* p2     = (float*)(w + OFF + 2195200);
  uint4* wmf    = (uint4*)(w + OFF + 4245248);  // 384 uint4 MFMA B-frags

  k0_setup<<<1, 256, 0, stream>>>(adj, imp, dww, w1, bnF, gw, bnsp, sdw, pw,
                                  bnsep, fcw, fcb, flag, deg, col, avals,
                                  w1c, wmf, dwn, sdwc, pwc, fcwc, fcbc,
                                  bnFs, bnsps, bnseps);
  k1_conv1_bn<<<dim3(4, B_*C_), 256, 0, stream>>>(x, w1c, bnFs, flag, bufA);
  for (int l = 0; l < 3; ++l) {
    const unsigned short* src = (l & 1) ? bufB : bufA;
    unsigned short*       dst = (l & 1) ? bufA : bufB;
    k23_gcn_gconv<<<dim3(4, B_*C_), 256, 0, stream>>>(src, dst, deg, col,
                                                      avals, wmf, bnFs, l);
  }
  k4_dw<<<dim3(2, B_*F1_), 256, 0, stream>>>(bufB, dwn, bnsps, p1);
  k5_sep<<<dim3(4, B_), 256, 0, stream>>>(p1, sdwc, pwc, bnseps, p2);
  k6_fc<<<32, 256, 0, stream>>>(p2, fcwc, fcbc, flag, d_out);
}

// Round 4
// 565.963 us; speedup vs baseline: 1.5772x; 1.0068x over previous
//
#include <hip/hip_runtime.h>

// GCN-EEGNet forward, MI355X. Dtype-adaptive (fp32/bf16 detected in K0 via
// adjacency sentinel). Weights in ws, wave-uniform -> SGPR. Intermediates
// f16. Round-17: r16 left k23 VALU-bound (VALUBusy 77%, MfmaUtil 6.3%,
// HBM 22%). Biggest remaining VALU sinks: phase-1 graph sum (8 cvt + 8
// f32 fma per edge-chunk = 0.5 MAC/instr) and k4's identical pattern.
// Fix: edge-PAIR dot2 — v_perm_b32 builds (h_e0[t], h_e1[t]) f16 pairs
// from two row loads (1 instr), v_dot2_f32_f16 contracts vs packed f16
// weight pair (avph, precomputed in K0; pairs padded w=0/self row -> no
// tail). f32 accumulation kept; only edge weights round to f16 (same
// error class as the f16 MFMA gconv weights). Same for k4 over cc pairs
// (dwph weight pairs from SGPR). ~2x MAC density on both.
// LESSON (r12): no empty blocks resonant with id%8 XCD rr.
// LESSON (r15): XCD swizzle (c fastest, then t, then b) -> FETCH 66 MB.
// Pipeline: K0 -> K1 conv1+bn -> 3x K23 -> K4 dw+bn+elu+pool4 -> K5 sep ->
// K6 pool8+fc.

#define B_   32
#define C_   64
#define T_   4000
#define F1_  8
#define TP_  1000
#define W2_  1001
#define MAXDEG 16
#define ROW4 130      // uint4 chunks per i-row staged in LDS (1040 halfs)
#define ROWB 2080     // bytes per i-row

typedef _Float16 h16x2 __attribute__((ext_vector_type(2)));
typedef _Float16 f16x8 __attribute__((ext_vector_type(8)));
typedef float    f32x4 __attribute__((ext_vector_type(4)));

static __device__ __forceinline__ float bf2f(unsigned short h) {
  union { unsigned int u; float f; } v; v.u = ((unsigned int)h) << 16; return v.f;
}
static __device__ __forceinline__ unsigned short f2bf(float f) {
  union { float f; unsigned int u; } v; v.f = f;
  unsigned int r = v.u + 0x7FFFu + ((v.u >> 16) & 1u);
  return (unsigned short)(r >> 16);
}
static __device__ __forceinline__ float lo_h(unsigned int u) {
  union { unsigned int u; _Float16 h[2]; } v; v.u = u; return (float)v.h[0];
}
static __device__ __forceinline__ float hi_h(unsigned int u) {
  union { unsigned int u; _Float16 h[2]; } v; v.u = u; return (float)v.h[1];
}
static __device__ __forceinline__ unsigned int pack2h(float a, float b) {
  union { _Float16 h[2]; unsigned int u; } v;
  v.h[0] = (_Float16)a; v.h[1] = (_Float16)b; return v.u;
}
static __device__ __forceinline__ h16x2 as_h2(unsigned int u) {
  union { unsigned int u; h16x2 h; } v; v.u = u; return v.h;
}
static __device__ __forceinline__ unsigned int alignb(unsigned int hi,
                                                      unsigned int lo,
                                                      unsigned int s) {
  // s in {0,16}; folds to v_alignbit_b32
  return (unsigned int)(((((unsigned long long)hi) << 32) | lo) >> s);
}
// (x.lo16, y.lo16) -> dword:  b0=x.b0 b1=x.b1 b2=y.b0 b3=y.b1
#define PERM_LO(y, x) __builtin_amdgcn_perm((y), (x), 0x05040100u)
// (x.hi16, y.hi16) -> dword
#define PERM_HI(y, x) __builtin_amdgcn_perm((y), (x), 0x07060302u)
#if defined(__has_builtin) && __has_builtin(__builtin_amdgcn_fdot2)
#define DOT2(a, b, c) __builtin_amdgcn_fdot2((a), (b), (c), false)
#else
static __device__ __forceinline__ float dot2_fb(h16x2 a, h16x2 b, float c) {
  return fmaf((float)a[0], (float)b[0], fmaf((float)a[1], (float)b[1], c));
}
#define DOT2(a, b, c) dot2_fb((a), (b), (c))
#endif
static __device__ __forceinline__ float eluf(float z) {
  return z > 0.0f ? z : __expf(z) - 1.0f;
}
static __device__ __forceinline__ float ldin(const void* p, int i, int isf32) {
  return isf32 ? ((const float*)p)[i] : bf2f(((const unsigned short*)p)[i]);
}

// ---------------- K0: dtype detect + canonicalize + CSR + bn fold ----------
__global__ __launch_bounds__(256) void k0_setup(
    const void* __restrict__ adj, const void* __restrict__ imp,
    const void* __restrict__ dww, const void* __restrict__ w1,
    const void* __restrict__ bnF, const void* __restrict__ gw,
    const void* __restrict__ bnsp, const void* __restrict__ sdw,
    const void* __restrict__ pw, const void* __restrict__ bnsep,
    const void* __restrict__ fcw, const void* __restrict__ fcb,
    int* __restrict__ flag, int* __restrict__ deg, int* __restrict__ col,
    float* __restrict__ avals, float* __restrict__ w1c,
    uint4* __restrict__ wmf, float* __restrict__ dwn,
    float* __restrict__ sdwc, float* __restrict__ pwc,
    float* __restrict__ fcwc, float* __restrict__ fcbc,
    float* __restrict__ bnFs, float* __restrict__ bnsps,
    float* __restrict__ bnseps,
    unsigned int* __restrict__ avph,   // 3*8*64*8 packed f16 weight pairs
    unsigned int* __restrict__ dwph)   // 16*32 packed f16 weight pairs
{
  __shared__ float dwr[1024];
  __shared__ float dsc[16];
  int tid = threadIdx.x;
  int isf32 = (((const float*)adj)[0] == 1.0f) ? 1 : 0;
  if (tid == 0) *flag = isf32;

  for (int i = tid; i < 512;  i += 256) w1c[i]  = ldin(w1, i, isf32);
  // MFMA B-fragments: wmf[(layer*2+frag)*64 + lane] = uint4 of 8 f16:
  // W[o=lane&15][i=(lane>>4)+4*frag][k=0..7], zero for o>=8.
  for (int idx = tid; idx < 384; idx += 256) {
    int lf = idx >> 6;            // layer*2+frag
    int layer = lf >> 1, frag = lf & 1;
    int lane2 = idx & 63;
    int o = lane2 & 15, ii = (lane2 >> 4) + 4*frag;
    uint4 v; v.x = 0u; v.y = 0u; v.z = 0u; v.w = 0u;
    if (o < 8) {
      int bi = layer*512 + (o*8 + ii)*8;
      v.x = pack2h(ldin(gw, bi+0, isf32), ldin(gw, bi+1, isf32));
      v.y = pack2h(ldin(gw, bi+2, isf32), ldin(gw, bi+3, isf32));
      v.z = pack2h(ldin(gw, bi+4, isf32), ldin(gw, bi+5, isf32));
      v.w = pack2h(ldin(gw, bi+6, isf32), ldin(gw, bi+7, isf32));
    }
    wmf[idx] = v;
  }
  for (int i = tid; i < 256;  i += 256) sdwc[i] = ldin(sdw, i, isf32);
  for (int i = tid; i < 256;  i += 256) pwc[i]  = ldin(pw, i, isf32);
  for (int i = tid; i < 8000; i += 256) fcwc[i] = ldin(fcw, i, isf32);
  if (tid < 4) fcbc[tid] = ldin(fcb, tid, isf32);
  for (int i = tid; i < 1024; i += 256) dwr[i] = ldin(dww, i, isf32);

  if (tid < 64) {            // CSR of adjacency (data-driven), self-padded
    int c = tid, n = 0;
    for (int e = 0; e < MAXDEG; ++e) col[c*MAXDEG + e] = c;
    for (int d = 0; d < 64; ++d) {
      if (ldin(adj, c*64 + d, isf32) != 0.0f) {
        if (n < MAXDEG) col[c*MAXDEG + n] = d;
        ++n;
      }
    }
    deg[c] = n < MAXDEG ? n : MAXDEG;
  }
  __syncthreads();
  if (tid < 16) {            // dw norm clamp scale
    float s2 = 0.0f;
    for (int c2 = 0; c2 < 64; ++c2) { float wv = dwr[tid*64 + c2]; s2 += wv*wv; }
    dsc[tid] = fminf(1.0f, 1.0f / fmaxf(sqrtf(s2), 1e-7f));
  }
  if (tid >= 64 && tid < 96) {   // bnF folded scale/shift: 4 stages x 8 ch
    int i = tid - 64, s = i >> 3, f = i & 7;
    float g = ldin(bnF, s*32 + f,      isf32);
    float b = ldin(bnF, s*32 + 8 + f,  isf32);
    float m = ldin(bnF, s*32 + 16 + f, isf32);
    float v = ldin(bnF, s*32 + 24 + f, isf32);
    float sc = g * rsqrtf(v + 1e-3f);
    bnFs[s*16 + f] = sc; bnFs[s*16 + 8 + f] = b - m*sc;
  }
  if (tid >= 96 && tid < 112) {  // bn_sp
    int ch = tid - 96;
    float g = ldin(bnsp, ch, isf32), b = ldin(bnsp, 16 + ch, isf32);
    float m = ldin(bnsp, 32 + ch, isf32), v = ldin(bnsp, 48 + ch, isf32);
    float sc = g * rsqrtf(v + 1e-3f);
    bnsps[ch] = sc; bnsps[16 + ch] = b - m*sc;
  }
  if (tid >= 112 && tid < 128) { // bn_sep
    int ch = tid - 112;
    float g = ldin(bnsep, ch, isf32), b = ldin(bnsep, 16 + ch, isf32);
    float m = ldin(bnsep, 32 + ch, isf32), v = ldin(bnsep, 48 + ch, isf32);
    float sc = g * rsqrtf(v + 1e-3f);
    bnseps[ch] = sc; bnseps[16 + ch] = b - m*sc;
  }
  for (int combo = tid; combo < 3*8*64; combo += 256) {
    int l = combo >> 9, f = (combo >> 6) & 7, c = combo & 63;
    int dg = deg[c];
    for (int e = 0; e < MAXDEG; ++e) {
      float v = 0.0f;
      if (e < dg) {
        int d = col[c*MAXDEG + e];
        v = ldin(adj, c*64 + d, isf32) * ldin(imp, ((l*8 + f)*64 + c)*64 + d, isf32);
      }
      avals[((l*8 + f)*64 + c)*MAXDEG + e] = v;
    }
  }
  __syncthreads();
  for (int i = tid; i < 1024; i += 256) dwn[i] = dwr[i] * dsc[i >> 6];
  // packed f16 edge-weight pairs from avals (global, visible after sync)
  for (int idx = tid; idx < 3*8*64*8; idx += 256) {
    int base16 = (idx >> 3) * MAXDEG, p = idx & 7;
    avph[idx] = pack2h(avals[base16 + 2*p], avals[base16 + 2*p + 1]);
  }
  __syncthreads();
  // packed f16 dw-weight pairs from dwn (global, visible after sync)
  for (int idx = tid; idx < 512; idx += 256) {
    int ch = idx >> 5, p = idx & 31;
    dwph[idx] = pack2h(dwn[ch*64 + 2*p], dwn[ch*64 + 2*p + 1]);
  }
}

// ---------------- K1: conv1 (64-tap) + bn0. 4 t/thread, SGPR weights -------
// grid (4 t-tiles of 1024, B*C). Stage xs[s] = x[tb-36+s], s in [0,1096):
// base tb-36 makes fp32 float4 (16B) and bf16 uint2 (8B) loads aligned.
__global__ __launch_bounds__(256, 4) void k1_conv1_bn(
    const void* __restrict__ x,               // B,C,T raw dtype
    const float* __restrict__ w1c,            // 8x64 fp32 (uniform -> s_load)
    const float* __restrict__ bnFs,
    const int* __restrict__ flag,
    unsigned short* __restrict__ outp)        // B,F1,C,T f16
{
  __shared__ __align__(16) float xs[1096];
  int tid = threadIdx.x;
  int bc = blockIdx.y;                 // b*64+c
  int b = bc >> 6, c = bc & 63;
  int tb = blockIdx.x * 1024;
  int isf32 = *flag;
  int row = bc * T_;
  if (isf32) {
    const float* xr = (const float*)x + row;
    for (int m = tid; m < 274; m += 256) {
      int tg = tb - 36 + 4*m;
      if (tg >= 0 && tg + 3 < T_) {
        *(float4*)(xs + 4*m) = *(const float4*)(xr + tg);   // 16B aligned
      } else {
        #pragma unroll
        for (int q = 0; q < 4; ++q) {
          int t = tg + q;
          xs[4*m + q] = (t >= 0 && t < T_) ? xr[t] : 0.0f;
        }
      }
    }
  } else {
    const unsigned short* xr = (const unsigned short*)x + row;
    for (int m = tid; m < 274; m += 256) {
      int tg = tb - 36 + 4*m;
      if (tg >= 0 && tg + 3 < T_) {
        uint2 v = *(const uint2*)(xr + tg);                 // 8B aligned
        xs[4*m]     = bf2f((unsigned short)(v.x & 0xFFFFu));
        xs[4*m + 1] = bf2f((unsigned short)(v.x >> 16));
        xs[4*m + 2] = bf2f((unsigned short)(v.y & 0xFFFFu));
        xs[4*m + 3] = bf2f((unsigned short)(v.y >> 16));
      } else {
        #pragma unroll
        for (int q = 0; q < 4; ++q) {
          int t = tg + q;
          xs[4*m + q] = (t >= 0 && t < T_) ? bf2f(xr[t]) : 0.0f;
        }
      }
    }
  }
  __syncthreads();
  int t0 = tb + 4*tid;
  if (t0 >= T_) return;
  float acc[8][4];
  #pragma unroll
  for (int f = 0; f < 8; ++f)
    #pragma unroll
    for (int j = 0; j < 4; ++j) acc[f][j] = 0.0f;
  float4 A4 = *(const float4*)(xs + 4*tid + 4);
  float4 B4 = *(const float4*)(xs + 4*tid + 8);
  for (int cc = 0; cc < 16; ++cc) {
    float ev[7] = {A4.y, A4.z, A4.w, B4.x, B4.y, B4.z, B4.w};
    #pragma unroll
    for (int kk = 0; kk < 4; ++kk) {
      #pragma unroll
      for (int f = 0; f < 8; ++f) {
        float wv = w1c[f*64 + 4*cc + kk];    // uniform -> SGPR
        #pragma unroll
        for (int j = 0; j < 4; ++j) acc[f][j] = fmaf(wv, ev[kk + j], acc[f][j]);
      }
    }
    A4 = B4;
    if (cc < 15) B4 = *(const float4*)(xs + 4*tid + 12 + 4*cc);
  }
  #pragma unroll
  for (int f = 0; f < 8; ++f) {
    float sc = bnFs[f], sh = bnFs[8 + f];
    uint2 st;
    st.x = pack2h(acc[f][0]*sc + sh, acc[f][1]*sc + sh);
    st.y = pack2h(acc[f][2]*sc + sh, acc[f][3]*sc + sh);
    *(uint2*)(outp + ((b*8 + f)*64 + c)*T_ + t0) = st;
  }
}

// ---------------- K23: fused graph einsum + MFMA gconv + bn + elu ----------
// grid (4, B*C), 256 thr. XCD swizzle: work = (c fastest, t-tile, b).
// Phase 1: 32 threads per i-row stage Ah (graph sum) into 16.6 KB LDS.
//   Edge-pair dot2: (h_e0[t],h_e1[t]) built by v_perm from two row loads,
//   contracted vs packed f16 weight pair (avph, uniform->SGPR). Pairs are
//   padded (w=0, self row) so dgp = ceil(dg/2) needs no tail. f32 accum.
// Phase 2: per wave: 16 tiles of 16 t, mfma_f32_16x16x32_f16 x2, window
//   gather via 3x ds_read_b64 + cndmask + alignbit (lane-const select).
//   D: col=o=lane&15 (<8 valid), rows t'=4q+reg -> 8B store per lane.
__global__ __launch_bounds__(256, 6) void k23_gcn_gconv(
    const unsigned short* __restrict__ in,    // B,F1,C,T f16
    unsigned short* __restrict__ outp,        // B,F1,C,T f16
    const int* __restrict__ deg, const int* __restrict__ col,
    const float* __restrict__ avals,          // 3*8*64*MAXDEG (boundary path)
    const unsigned int* __restrict__ avph,    // 3*8*64*8 packed pairs
    const uint4* __restrict__ wmf,            // 6*64 B-fragments
    const float* __restrict__ bnFs, int l)
{
  __shared__ __align__(16) uint4 ash[8 * ROW4];   // 16,640 B
  int tid = threadIdx.x;
  // bijective XCD swizzle (8192 blocks, 8 XCDs)
  int wgid = blockIdx.y * 4 + blockIdx.x;
  int swz  = (wgid & 7) * 1024 + (wgid >> 3);
  int c = swz & 63;
  int xt = (swz >> 6) & 3;
  int b = swz >> 8;
  int tb = xt * 1024;
  int wb = tb - 8;                     // staged range [wb, wb+1040)
  int dg = deg[c];                     // uniform -> s_load
  const int* cp = col + c*MAXDEG;

  // ---- phase 1: stage Ah into LDS, 32 threads per i-row ----
  {
    int i = tid >> 5;                  // 0..7
    int mlane = tid & 31;
    int dgp = (dg + 1) >> 1;
    const unsigned int* wpp = avph + ((l*8 + i)*64 + c) * 8;   // uniform
    const float* av = avals + ((l*8 + i)*64 + c) * MAXDEG;     // uniform
    const unsigned short* rbp = in + (size_t)((b*8 + i) * 64) * T_;
    for (int m = mlane; m < ROW4; m += 32) {
      int t = wb + 8*m;
      float a[8] = {0,0,0,0,0,0,0,0};
      if (t >= 0 && t + 7 < T_) {
        for (int p = 0; p < dgp; ++p) {
          int d0 = cp[2*p];            // uniform -> s_load
          int d1 = cp[2*p + 1];
          h16x2 w2 = as_h2(wpp[p]);    // uniform
          uint4 v0 = *(const uint4*)(rbp + d0*T_ + t);   // 16B aligned
          uint4 v1 = *(const uint4*)(rbp + d1*T_ + t);
          a[0] = DOT2(as_h2(PERM_LO(v1.x, v0.x)), w2, a[0]);
          a[1] = DOT2(as_h2(PERM_HI(v1.x, v0.x)), w2, a[1]);
          a[2] = DOT2(as_h2(PERM_LO(v1.y, v0.y)), w2, a[2]);
          a[3] = DOT2(as_h2(PERM_HI(v1.y, v0.y)), w2, a[3]);
          a[4] = DOT2(as_h2(PERM_LO(v1.z, v0.z)), w2, a[4]);
          a[5] = DOT2(as_h2(PERM_HI(v1.z, v0.z)), w2, a[5]);
          a[6] = DOT2(as_h2(PERM_LO(v1.w, v0.w)), w2, a[6]);
          a[7] = DOT2(as_h2(PERM_HI(v1.w, v0.w)), w2, a[7]);
        }
      } else if (t + 7 >= 0 && t < T_) {
        for (int e = 0; e < dg; ++e) {
          int d = cp[e];
          float wv = av[e];
          const unsigned short* rp = rbp + d*T_;
          #pragma unroll
          for (int q = 0; q < 8; ++q) {
            int tq = t + q;
            if (tq >= 0 && tq < T_)
              a[q] = fmaf(wv, lo_h((unsigned int)rp[tq]), a[q]);
          }
        }
      }
      uint4 o;
      o.x = pack2h(a[0], a[1]); o.y = pack2h(a[2], a[3]);
      o.z = pack2h(a[4], a[5]); o.w = pack2h(a[6], a[7]);
      ash[i*ROW4 + m] = o;
    }
  }
  __syncthreads();

  // ---- phase 2: MFMA gconv ----
  int lane = tid & 63;
  int wv4 = tid >> 6;                  // wave 0..3
  int m = lane & 15, q = lane >> 4;
  union { uint4 u; f16x8 h; } w0u, w1u;
  w0u.u = wmf[(l*2 + 0)*64 + lane];
  w1u.u = wmf[(l*2 + 1)*64 + lane];
  int o8 = (m < 8) ? m : 0;
  float sc  = bnFs[(l+1)*16 + o8];
  float shb = bnFs[(l+1)*16 + 8 + o8];
  int Sm = m + 5;                      // S = t_base + Sm (t_base % 16 == 0)
  unsigned shv = ((unsigned)Sm & 1u) * 16u;
  int bhi = (Sm >> 1) & 1;             // (S&3)>=2
  int a0b = q*ROWB + ((2*Sm) & ~7);
  const char* ashc = (const char*)ash;
  unsigned short* orow = outp + (size_t)((b*8 + o8)*64 + c) * T_;
  #pragma unroll 2
  for (int tile = 0; tile < 16; ++tile) {
    int t_base = wv4*256 + tile*16;
    int off = a0b + 2*t_base;
    const uint2* pa0 = (const uint2*)(ashc + off);
    uint2 x0 = pa0[0], x1 = pa0[1], x2 = pa0[2];
    const uint2* pa1 = (const uint2*)(ashc + off + 4*ROWB);
    uint2 y0 = pa1[0], y1 = pa1[1], y2 = pa1[2];
    unsigned ua[6] = {x0.x, x0.y, x1.x, x1.y, x2.x, x2.y};
    unsigned ub[6] = {y0.x, y0.y, y1.x, y1.y, y2.x, y2.y};
    union { unsigned d[4]; f16x8 h; } A0, A1;
    #pragma unroll
    for (int j = 0; j < 4; ++j) {
      unsigned vlo = bhi ? ua[j+1] : ua[j];
      unsigned vhi = bhi ? ua[j+2] : ua[j+1];
      A0.d[j] = alignb(vhi, vlo, shv);
      unsigned wlo = bhi ? ub[j+1] : ub[j];
      unsigned whi = bhi ? ub[j+2] : ub[j+1];
      A1.d[j] = alignb(whi, wlo, shv);
    }
    f32x4 acc = {0.0f, 0.0f, 0.0f, 0.0f};
    acc = __builtin_amdgcn_mfma_f32_16x16x32_f16(A0.h, w0u.h, acc, 0, 0, 0);
    acc = __builtin_amdgcn_mfma_f32_16x16x32_f16(A1.h, w1u.h, acc, 0, 0, 0);
    int t0g = tb + t_base + 4*q;
    if (m < 8 && t0g < T_) {
      float e0 = eluf(acc[0]*sc + shb);
      float e1 = eluf(acc[1]*sc + shb);
      float e2 = eluf(acc[2]*sc + shb);
      float e3 = eluf(acc[3]*sc + shb);
      uint2 st; st.x = pack2h(e0, e1); st.y = pack2h(e2, e3);
      *(uint2*)(orow + t0g) = st;
    }
  }
}

// ---------------- K4: depthwise-over-C + bn + elu + avgpool4. 8 t/thread ---
// cc-pair dot2: (h_cc0[t],h_cc1[t]) via v_perm, weight pairs dwph (SGPR).
__global__ __launch_bounds__(256) void k4_dw(
    const unsigned short* __restrict__ in,    // B,F1,C,T f16
    const unsigned int* __restrict__ dwph,    // 16x32 packed f16 pairs
    const float* __restrict__ bnsps,
    float* __restrict__ p1)                   // B,16,1000 fp32
{
  int tid = threadIdx.x;
  int bg = blockIdx.y;                 // b*8+g
  int b = bg >> 3, g = bg & 7;
  int tile = blockIdx.x * 256 + tid;
  if (tile >= 500) return;
  int t0 = tile * 8;
  int base = bg * (64 * T_);
  const unsigned int* w0pp = dwph + (2*g)*32;      // uniform -> s_load
  const unsigned int* w1pp = dwph + (2*g + 1)*32;
  float a0[8] = {0,0,0,0,0,0,0,0}, a1[8] = {0,0,0,0,0,0,0,0};
  for (int p = 0; p < 32; ++p) {
    h16x2 w02 = as_h2(w0pp[p]);        // uniform
    h16x2 w12 = as_h2(w1pp[p]);        // uniform
    uint4 v0 = *(const uint4*)(in + base + (2*p)*T_ + t0);
    uint4 v1 = *(const uint4*)(in + base + (2*p + 1)*T_ + t0);
    unsigned pr;
    pr = PERM_LO(v1.x, v0.x);
    a0[0] = DOT2(as_h2(pr), w02, a0[0]); a1[0] = DOT2(as_h2(pr), w12, a1[0]);
    pr = PERM_HI(v1.x, v0.x);
    a0[1] = DOT2(as_h2(pr), w02, a0[1]); a1[1] = DOT2(as_h2(pr), w12, a1[1]);
    pr = PERM_LO(v1.y, v0.y);
    a0[2] = DOT2(as_h2(pr), w02, a0[2]); a1[2] = DOT2(as_h2(pr), w12, a1[2]);
    pr = PERM_HI(v1.y, v0.y);
    a0[3] = DOT2(as_h2(pr), w02, a0[3]); a1[3] = DOT2(as_h2(pr), w12, a1[3]);
    pr = PERM_LO(v1.z, v0.z);
    a0[4] = DOT2(as_h2(pr), w02, a0[4]); a1[4] = DOT2(as_h2(pr), w12, a1[4]);
    pr = PERM_HI(v1.z, v0.z);
    a0[5] = DOT2(as_h2(pr), w02, a0[5]); a1[5] = DOT2(as_h2(pr), w12, a1[5]);
    pr = PERM_LO(v1.w, v0.w);
    a0[6] = DOT2(as_h2(pr), w02, a0[6]); a1[6] = DOT2(as_h2(pr), w12, a1[6]);
    pr = PERM_HI(v1.w, v0.w);
    a0[7] = DOT2(as_h2(pr), w02, a0[7]); a1[7] = DOT2(as_h2(pr), w12, a1[7]);
  }
  float sc0 = bnsps[2*g],     sh0 = bnsps[16 + 2*g];
  float sc1 = bnsps[2*g + 1], sh1 = bnsps[16 + 2*g + 1];
  int oi = t0 >> 2;
  float2 r0, r1;
  r0.x = 0.25f * (eluf(a0[0]*sc0+sh0) + eluf(a0[1]*sc0+sh0)
                + eluf(a0[2]*sc0+sh0) + eluf(a0[3]*sc0+sh0));
  r0.y = 0.25f * (eluf(a0[4]*sc0+sh0) + eluf(a0[5]*sc0+sh0)
                + eluf(a0[6]*sc0+sh0) + eluf(a0[7]*sc0+sh0));
  r1.x = 0.25f * (eluf(a1[0]*sc1+sh1) + eluf(a1[1]*sc1+sh1)
                + eluf(a1[2]*sc1+sh1) + eluf(a1[3]*sc1+sh1));
  r1.y = 0.25f * (eluf(a1[4]*sc1+sh1) + eluf(a1[5]*sc1+sh1)
                + eluf(a1[6]*sc1+sh1) + eluf(a1[7]*sc1+sh1));
  *(float2*)(p1 + (b*16 + 2*g)*TP_ + oi)     = r0;
  *(float2*)(p1 + (b*16 + 2*g + 1)*TP_ + oi) = r1;
}

// ---------------- K5: sep depthwise(16) + pointwise(16x16) + bn + elu ------
__global__ __launch_bounds__(256) void k5_sep(
    const float* __restrict__ p1,             // B,16,1000
    const float* __restrict__ sdwc,           // 16x16 (uniform)
    const float* __restrict__ pwc,            // 16x16 (uniform)
    const float* __restrict__ bnseps,
    float* __restrict__ p2)                   // B,16,1001
{
  __shared__ float ps[16*272];
  int tid = threadIdx.x;
  int wq = blockIdx.x, b = blockIdx.y;
  int wb = wq * 256;
  for (int ch = 0; ch < 16; ++ch) {
    for (int s = tid; s < 272; s += 256) {
      int t = wb - 8 + s;
      ps[ch*272 + s] = (t >= 0 && t < TP_) ? p1[(b*16 + ch)*TP_ + t] : 0.0f;
    }
  }
  __syncthreads();
  int w0 = wb + tid;
  if (w0 >= W2_) return;
  float dws[16];
  for (int ch = 0; ch < 16; ++ch) {
    float a = 0.0f;
    #pragma unroll
    for (int k = 0; k < 16; ++k)
      a = fmaf(sdwc[ch*16 + k], ps[ch*272 + tid + k], a);
    dws[ch] = a;
  }
  for (int f = 0; f < 16; ++f) {
    float a = 0.0f;
    #pragma unroll
    for (int ch = 0; ch < 16; ++ch) a = fmaf(pwc[f*16 + ch], dws[ch], a);
    float sc = bnseps[f], sh = bnseps[16 + f];
    p2[(b*16 + f)*W2_ + w0] = eluf(a*sc + sh);
  }
}

// ---------------- K6: avgpool8 (first 1000) + fc ---------------------------
__global__ __launch_bounds__(256) void k6_fc(
    const float* __restrict__ p2,             // B,16,1001
    const float* __restrict__ fcwc,           // 4x2000
    const float* __restrict__ fcbc,           // 4
    const int* __restrict__ flag,
    void* __restrict__ outp)                  // B,4
{
  __shared__ float red[4*256];
  int tid = threadIdx.x;
  int b = blockIdx.x;
  float part[4] = {0.0f, 0.0f, 0.0f, 0.0f};
  for (int idx = tid; idx < 2000; idx += 256) {
    int f = idx / 125, q = idx - f*125;
    const float* src = p2 + (b*16 + f)*W2_ + q*8;
    float s = src[0]+src[1]+src[2]+src[3]+src[4]+src[5]+src[6]+src[7];
    float mval = 0.125f * s;
    #pragma unroll
    for (int n = 0; n < 4; ++n) part[n] = fmaf(fcwc[n*2000 + idx], mval, part[n]);
  }
  #pragma unroll
  for (int n = 0; n < 4; ++n) red[n*256 + tid] = part[n];
  __syncthreads();
  for (int s = 128; s > 0; s >>= 1) {
    if (tid < s) {
      #pragma unroll
      for (int n = 0; n < 4; ++n) red[n*256 + tid] += red[n*256 + tid + s];
    }
    __syncthreads();
  }
  if (tid < 4) {
    float val = red[tid*256] + fcbc[tid];
    if (*flag) ((float*)outp)[b*4 + tid] = val;
    else       ((unsigned short*)outp)[b*4 + tid] = f2bf(val);
  }
}

// ---------------------------------------------------------------------------
extern "C" void kernel_launch(void* const* d_in, const int* in_sizes, int n_in,
                              void* d_out, int out_size, void* d_ws, size_t ws_size,
                              hipStream_t stream) {
  const void* x     = d_in[0];
  const void* adj   = d_in[1];
  const void* w1    = d_in[2];
  const void* bnF   = d_in[3];
  const void* imp   = d_in[4];
  const void* gw    = d_in[5];
  const void* dww   = d_in[6];
  const void* bnsp  = d_in[7];
  const void* sdw   = d_in[8];
  const void* pw    = d_in[9];
  const void* bnsep = d_in[10];
  const void* fcw   = d_in[11];
  const void* fcb   = d_in[12];

  char* w = (char*)d_ws;
  const size_t OFF = 262144000;  // after two 131,072,000-byte f16 buffers
  unsigned short* bufA = (unsigned short*)(w);
  unsigned short* bufB = (unsigned short*)(w + 131072000);
  int*   flag   = (int*)  (w + OFF + 0);
  int*   deg    = (int*)  (w + OFF + 256);
  int*   col    = (int*)  (w + OFF + 512);
  float* avals  = (float*)(w + OFF + 4608);
  float* w1c    = (float*)(w + OFF + 102912);
  float* dwn    = (float*)(w + OFF + 108032);
  float* sdwc   = (float*)(w + OFF + 112128);
  float* pwc    = (float*)(w + OFF + 113152);
  float* fcwc   = (float*)(w + OFF + 114176);
  float* fcbc   = (float*)(w + OFF + 146176);
  float* bnFs   = (float*)(w + OFF + 146432);
  float* bnsps  = (float*)(w + OFF + 146688);
  float* bnseps = (float*)(w + OFF + 146944);
  float* p1     = (float*)(w + OFF + 147200);
  float* p2     = (float*)(w + OFF + 2195200);
  uint4* wmf    = (uint4*)(w + OFF + 4245248);           // 384 uint4
  unsigned int* avph = (unsigned int*)(w + OFF + 4251392);  // 12288 uints
  unsigned int* dwph = (unsigned int*)(w + OFF + 4300544);  // 512 uints

  k0_setup<<<1, 256, 0, stream>>>(adj, imp, dww, w1, bnF, gw, bnsp, sdw, pw,
                                  bnsep, fcw, fcb, flag, deg, col, avals,
                                  w1c, wmf, dwn, sdwc, pwc, fcwc, fcbc,
                                  bnFs, bnsps, bnseps, avph, dwph);
  k1_conv1_bn<<<dim3(4, B_*C_), 256, 0, stream>>>(x, w1c, bnFs, flag, bufA);
  for (int l = 0; l < 3; ++l) {
    const unsigned short* src = (l & 1) ? bufB : bufA;
    unsigned short*       dst = (l & 1) ? bufA : bufB;
    k23_gcn_gconv<<<dim3(4, B_*C_), 256, 0, stream>>>(src, dst, deg, col,
                                                      avals, avph, wmf, bnFs, l);
  }
  k4_dw<<<dim3(2, B_*F1_), 256, 0, stream>>>(bufB, dwph, bnsps, p1);
  k5_sep<<<dim3(4, B_), 256, 0, stream>>>(p1, sdwc, pwc, bnseps, p2);
  k6_fc<<<32, 256, 0, stream>>>(p2, fcwc, fcbc, flag, d_out);
}

// Round 5
// 545.414 us; speedup vs baseline: 1.6366x; 1.0377x over previous
//
#include <hip/hip_runtime.h>

// GCN-EEGNet forward, MI355X. Dtype-adaptive (fp32/bf16 detected in K0 via
// adjacency sentinel). Weights in ws, wave-uniform -> SGPR. Intermediates
// f16. Round-18: two VALU-count cuts (k23 is issue-bound: 77% VALUBusy,
// 23% HBM, MfmaUtil 6.5%):
// (a) k23 phase-2 gather: read A-frag dwords from a 4B-aligned LDS base
//     ((2*Sm)&~3) — equivalent to the old 8B base + bhi cndmask select —
//     removing 16 v_cndmask/tile; 16-tile loop fully unrolled so all
//     ds_read2_b32/ds_read_b32 use immediate offsets (no per-tile addr
//     VALU). Same 6 LDS issues/tile.
// (b) K1 conv1 -> f16 dot2: stage x as f16 pairs in LDS, slide 4-dword
//     window, 3 alignbit/cc odd-pair build, packed f16 weight pairs w1h
//     (SGPR). 2048 fp32 fma -> 1024 dot2 + 48 align. x rounds to f16
//     (same error class as existing f16 intermediates).
// LESSON (r12): no empty blocks resonant with id%8 XCD rr.
// LESSON (r15): XCD swizzle (c fastest, then t, then b) -> FETCH 66 MB.
// Pipeline: K0 -> K1 conv1+bn -> 3x K23 -> K4 dw+bn+elu+pool4 -> K5 sep ->
// K6 pool8+fc.

#define B_   32
#define C_   64
#define T_   4000
#define F1_  8
#define TP_  1000
#define W2_  1001
#define MAXDEG 16
#define ROW4 130      // uint4 chunks per i-row staged in LDS (1040 halfs)
#define ROWB 2080     // bytes per i-row

typedef _Float16 h16x2 __attribute__((ext_vector_type(2)));
typedef _Float16 f16x8 __attribute__((ext_vector_type(8)));
typedef float    f32x4 __attribute__((ext_vector_type(4)));

static __device__ __forceinline__ float bf2f(unsigned short h) {
  union { unsigned int u; float f; } v; v.u = ((unsigned int)h) << 16; return v.f;
}
static __device__ __forceinline__ unsigned short f2bf(float f) {
  union { float f; unsigned int u; } v; v.f = f;
  unsigned int r = v.u + 0x7FFFu + ((v.u >> 16) & 1u);
  return (unsigned short)(r >> 16);
}
static __device__ __forceinline__ float lo_h(unsigned int u) {
  union { unsigned int u; _Float16 h[2]; } v; v.u = u; return (float)v.h[0];
}
static __device__ __forceinline__ float hi_h(unsigned int u) {
  union { unsigned int u; _Float16 h[2]; } v; v.u = u; return (float)v.h[1];
}
static __device__ __forceinline__ unsigned int pack2h(float a, float b) {
  union { _Float16 h[2]; unsigned int u; } v;
  v.h[0] = (_Float16)a; v.h[1] = (_Float16)b; return v.u;
}
static __device__ __forceinline__ h16x2 as_h2(unsigned int u) {
  union { unsigned int u; h16x2 h; } v; v.u = u; return v.h;
}
static __device__ __forceinline__ unsigned int alignb(unsigned int hi,
                                                      unsigned int lo,
                                                      unsigned int s) {
  // s in {0,16}; folds to v_alignbit_b32
  return (unsigned int)(((((unsigned long long)hi) << 32) | lo) >> s);
}
// (x.lo16, y.lo16) -> dword:  b0=x.b0 b1=x.b1 b2=y.b0 b3=y.b1
#define PERM_LO(y, x) __builtin_amdgcn_perm((y), (x), 0x05040100u)
// (x.hi16, y.hi16) -> dword
#define PERM_HI(y, x) __builtin_amdgcn_perm((y), (x), 0x07060302u)
#if defined(__has_builtin) && __has_builtin(__builtin_amdgcn_fdot2)
#define DOT2(a, b, c) __builtin_amdgcn_fdot2((a), (b), (c), false)
#else
static __device__ __forceinline__ float dot2_fb(h16x2 a, h16x2 b, float c) {
  return fmaf((float)a[0], (float)b[0], fmaf((float)a[1], (float)b[1], c));
}
#define DOT2(a, b, c) dot2_fb((a), (b), (c))
#endif
static __device__ __forceinline__ float eluf(float z) {
  return z > 0.0f ? z : __expf(z) - 1.0f;
}
static __device__ __forceinline__ float ldin(const void* p, int i, int isf32) {
  return isf32 ? ((const float*)p)[i] : bf2f(((const unsigned short*)p)[i]);
}

// ---------------- K0: dtype detect + canonicalize + CSR + bn fold ----------
__global__ __launch_bounds__(256) void k0_setup(
    const void* __restrict__ adj, const void* __restrict__ imp,
    const void* __restrict__ dww, const void* __restrict__ w1,
    const void* __restrict__ bnF, const void* __restrict__ gw,
    const void* __restrict__ bnsp, const void* __restrict__ sdw,
    const void* __restrict__ pw, const void* __restrict__ bnsep,
    const void* __restrict__ fcw, const void* __restrict__ fcb,
    int* __restrict__ flag, int* __restrict__ deg, int* __restrict__ col,
    float* __restrict__ avals, unsigned int* __restrict__ w1h,
    uint4* __restrict__ wmf, float* __restrict__ dwn,
    float* __restrict__ sdwc, float* __restrict__ pwc,
    float* __restrict__ fcwc, float* __restrict__ fcbc,
    float* __restrict__ bnFs, float* __restrict__ bnsps,
    float* __restrict__ bnseps,
    unsigned int* __restrict__ avph,   // 3*8*64*8 packed f16 weight pairs
    unsigned int* __restrict__ dwph)   // 16*32 packed f16 weight pairs
{
  __shared__ float dwr[1024];
  __shared__ float dsc[16];
  int tid = threadIdx.x;
  int isf32 = (((const float*)adj)[0] == 1.0f) ? 1 : 0;
  if (tid == 0) *flag = isf32;

  // conv1 weights as packed f16 pairs: w1h[f*32+p] = (w1[f][2p], w1[f][2p+1])
  for (int idx = tid; idx < 256; idx += 256) {
    int f = idx >> 5, p = idx & 31;
    w1h[idx] = pack2h(ldin(w1, f*64 + 2*p, isf32), ldin(w1, f*64 + 2*p + 1, isf32));
  }
  // MFMA B-fragments: wmf[(layer*2+frag)*64 + lane] = uint4 of 8 f16:
  // W[o=lane&15][i=(lane>>4)+4*frag][k=0..7], zero for o>=8.
  for (int idx = tid; idx < 384; idx += 256) {
    int lf = idx >> 6;            // layer*2+frag
    int layer = lf >> 1, frag = lf & 1;
    int lane2 = idx & 63;
    int o = lane2 & 15, ii = (lane2 >> 4) + 4*frag;
    uint4 v; v.x = 0u; v.y = 0u; v.z = 0u; v.w = 0u;
    if (o < 8) {
      int bi = layer*512 + (o*8 + ii)*8;
      v.x = pack2h(ldin(gw, bi+0, isf32), ldin(gw, bi+1, isf32));
      v.y = pack2h(ldin(gw, bi+2, isf32), ldin(gw, bi+3, isf32));
      v.z = pack2h(ldin(gw, bi+4, isf32), ldin(gw, bi+5, isf32));
      v.w = pack2h(ldin(gw, bi+6, isf32), ldin(gw, bi+7, isf32));
    }
    wmf[idx] = v;
  }
  for (int i = tid; i < 256;  i += 256) sdwc[i] = ldin(sdw, i, isf32);
  for (int i = tid; i < 256;  i += 256) pwc[i]  = ldin(pw, i, isf32);
  for (int i = tid; i < 8000; i += 256) fcwc[i] = ldin(fcw, i, isf32);
  if (tid < 4) fcbc[tid] = ldin(fcb, tid, isf32);
  for (int i = tid; i < 1024; i += 256) dwr[i] = ldin(dww, i, isf32);

  if (tid < 64) {            // CSR of adjacency (data-driven), self-padded
    int c = tid, n = 0;
    for (int e = 0; e < MAXDEG; ++e) col[c*MAXDEG + e] = c;
    for (int d = 0; d < 64; ++d) {
      if (ldin(adj, c*64 + d, isf32) != 0.0f) {
        if (n < MAXDEG) col[c*MAXDEG + n] = d;
        ++n;
      }
    }
    deg[c] = n < MAXDEG ? n : MAXDEG;
  }
  __syncthreads();
  if (tid < 16) {            // dw norm clamp scale
    float s2 = 0.0f;
    for (int c2 = 0; c2 < 64; ++c2) { float wv = dwr[tid*64 + c2]; s2 += wv*wv; }
    dsc[tid] = fminf(1.0f, 1.0f / fmaxf(sqrtf(s2), 1e-7f));
  }
  if (tid >= 64 && tid < 96) {   // bnF folded scale/shift: 4 stages x 8 ch
    int i = tid - 64, s = i >> 3, f = i & 7;
    float g = ldin(bnF, s*32 + f,      isf32);
    float b = ldin(bnF, s*32 + 8 + f,  isf32);
    float m = ldin(bnF, s*32 + 16 + f, isf32);
    float v = ldin(bnF, s*32 + 24 + f, isf32);
    float sc = g * rsqrtf(v + 1e-3f);
    bnFs[s*16 + f] = sc; bnFs[s*16 + 8 + f] = b - m*sc;
  }
  if (tid >= 96 && tid < 112) {  // bn_sp
    int ch = tid - 96;
    float g = ldin(bnsp, ch, isf32), b = ldin(bnsp, 16 + ch, isf32);
    float m = ldin(bnsp, 32 + ch, isf32), v = ldin(bnsp, 48 + ch, isf32);
    float sc = g * rsqrtf(v + 1e-3f);
    bnsps[ch] = sc; bnsps[16 + ch] = b - m*sc;
  }
  if (tid >= 112 && tid < 128) { // bn_sep
    int ch = tid - 112;
    float g = ldin(bnsep, ch, isf32), b = ldin(bnsep, 16 + ch, isf32);
    float m = ldin(bnsep, 32 + ch, isf32), v = ldin(bnsep, 48 + ch, isf32);
    float sc = g * rsqrtf(v + 1e-3f);
    bnseps[ch] = sc; bnseps[16 + ch] = b - m*sc;
  }
  for (int combo = tid; combo < 3*8*64; combo += 256) {
    int l = combo >> 9, f = (combo >> 6) & 7, c = combo & 63;
    int dg = deg[c];
    for (int e = 0; e < MAXDEG; ++e) {
      float v = 0.0f;
      if (e < dg) {
        int d = col[c*MAXDEG + e];
        v = ldin(adj, c*64 + d, isf32) * ldin(imp, ((l*8 + f)*64 + c)*64 + d, isf32);
      }
      avals[((l*8 + f)*64 + c)*MAXDEG + e] = v;
    }
  }
  __syncthreads();
  for (int i = tid; i < 1024; i += 256) dwn[i] = dwr[i] * dsc[i >> 6];
  // packed f16 edge-weight pairs from avals (global, visible after sync)
  for (int idx = tid; idx < 3*8*64*8; idx += 256) {
    int base16 = (idx >> 3) * MAXDEG, p = idx & 7;
    avph[idx] = pack2h(avals[base16 + 2*p], avals[base16 + 2*p + 1]);
  }
  __syncthreads();
  // packed f16 dw-weight pairs from dwn (global, visible after sync)
  for (int idx = tid; idx < 512; idx += 256) {
    int ch = idx >> 5, p = idx & 31;
    dwph[idx] = pack2h(dwn[ch*64 + 2*p], dwn[ch*64 + 2*p + 1]);
  }
}

// ---------------- K1: conv1 (64-tap) via f16 dot2 + bn0. 4 t/thread -------
// grid (4 t-tiles of 1024, B*C). Stage xs_h[s] = f16(x[tb-36+s]), s in
// [0,1096) packed 2/dword. Output t0+j needs halfs h = 4tid+5+j+k, k=0..63.
// Window u[n] dwords; odd-start pairs via alignbit (od). Per cc (4 taps):
// u0..u3 = dwords 2tid+2+2cc .. +3; od0..2 = align pairs; 64 dot2 vs
// packed weight pairs w1h (uniform -> SGPR). Slide 2 dwords/cc.
__global__ __launch_bounds__(256, 4) void k1_conv1_bn(
    const void* __restrict__ x,               // B,C,T raw dtype
    const unsigned int* __restrict__ w1h,     // 8x32 packed f16 pairs
    const float* __restrict__ bnFs,
    const int* __restrict__ flag,
    unsigned short* __restrict__ outp)        // B,F1,C,T f16
{
  __shared__ __align__(16) unsigned int xs[548];   // 1096 halfs
  int tid = threadIdx.x;
  int bc = blockIdx.y;                 // b*64+c
  int b = bc >> 6, c = bc & 63;
  int tb = blockIdx.x * 1024;
  int isf32 = *flag;
  int row = bc * T_;
  if (isf32) {
    const float* xr = (const float*)x + row;
    for (int m = tid; m < 274; m += 256) {
      int tg = tb - 36 + 4*m;
      uint2 st;
      if (tg >= 0 && tg + 3 < T_) {
        float4 v = *(const float4*)(xr + tg);               // 16B aligned
        st.x = pack2h(v.x, v.y); st.y = pack2h(v.z, v.w);
      } else {
        float q0 = (tg   >= 0 && tg   < T_) ? xr[tg]   : 0.0f;
        float q1 = (tg+1 >= 0 && tg+1 < T_) ? xr[tg+1] : 0.0f;
        float q2 = (tg+2 >= 0 && tg+2 < T_) ? xr[tg+2] : 0.0f;
        float q3 = (tg+3 >= 0 && tg+3 < T_) ? xr[tg+3] : 0.0f;
        st.x = pack2h(q0, q1); st.y = pack2h(q2, q3);
      }
      *(uint2*)(xs + 2*m) = st;
    }
  } else {
    const unsigned short* xr = (const unsigned short*)x + row;
    for (int m = tid; m < 274; m += 256) {
      int tg = tb - 36 + 4*m;
      uint2 st;
      if (tg >= 0 && tg + 3 < T_) {
        uint2 v = *(const uint2*)(xr + tg);                 // 8B aligned
        st.x = pack2h(bf2f((unsigned short)(v.x & 0xFFFFu)),
                      bf2f((unsigned short)(v.x >> 16)));
        st.y = pack2h(bf2f((unsigned short)(v.y & 0xFFFFu)),
                      bf2f((unsigned short)(v.y >> 16)));
      } else {
        float q0 = (tg   >= 0 && tg   < T_) ? bf2f(xr[tg])   : 0.0f;
        float q1 = (tg+1 >= 0 && tg+1 < T_) ? bf2f(xr[tg+1]) : 0.0f;
        float q2 = (tg+2 >= 0 && tg+2 < T_) ? bf2f(xr[tg+2]) : 0.0f;
        float q3 = (tg+3 >= 0 && tg+3 < T_) ? bf2f(xr[tg+3]) : 0.0f;
        st.x = pack2h(q0, q1); st.y = pack2h(q2, q3);
      }
      *(uint2*)(xs + 2*m) = st;
    }
  }
  __syncthreads();
  int t0 = tb + 4*tid;
  if (t0 >= T_) return;
  float acc[8][4];
  #pragma unroll
  for (int f = 0; f < 8; ++f)
    #pragma unroll
    for (int j = 0; j < 4; ++j) acc[f][j] = 0.0f;
  uint2 a0 = *(const uint2*)(xs + 2*tid + 2);
  uint2 a1 = *(const uint2*)(xs + 2*tid + 4);
  unsigned u0 = a0.x, u1 = a0.y, u2 = a1.x, u3 = a1.y;
  for (int cc = 0; cc < 16; ++cc) {
    unsigned od0 = alignb(u1, u0, 16);
    unsigned od1 = alignb(u2, u1, 16);
    unsigned od2 = alignb(u3, u2, 16);
    #pragma unroll
    for (int f = 0; f < 8; ++f) {
      h16x2 wa = as_h2(w1h[f*32 + 2*cc]);      // uniform -> SGPR
      h16x2 wb = as_h2(w1h[f*32 + 2*cc + 1]);
      acc[f][0] = DOT2(as_h2(od0), wa, acc[f][0]);
      acc[f][0] = DOT2(as_h2(od1), wb, acc[f][0]);
      acc[f][1] = DOT2(as_h2(u1),  wa, acc[f][1]);
      acc[f][1] = DOT2(as_h2(u2),  wb, acc[f][1]);
      acc[f][2] = DOT2(as_h2(od1), wa, acc[f][2]);
      acc[f][2] = DOT2(as_h2(od2), wb, acc[f][2]);
      acc[f][3] = DOT2(as_h2(u2),  wa, acc[f][3]);
      acc[f][3] = DOT2(as_h2(u3),  wb, acc[f][3]);
    }
    u0 = u2; u1 = u3;
    if (cc < 15) {
      uint2 nx = *(const uint2*)(xs + 2*tid + 6 + 2*cc);
      u2 = nx.x; u3 = nx.y;
    }
  }
  #pragma unroll
  for (int f = 0; f < 8; ++f) {
    float sc = bnFs[f], sh = bnFs[8 + f];
    uint2 st;
    st.x = pack2h(acc[f][0]*sc + sh, acc[f][1]*sc + sh);
    st.y = pack2h(acc[f][2]*sc + sh, acc[f][3]*sc + sh);
    *(uint2*)(outp + ((b*8 + f)*64 + c)*T_ + t0) = st;
  }
}

// ---------------- K23: fused graph einsum + MFMA gconv + bn + elu ----------
// grid (4, B*C), 256 thr. XCD swizzle: work = (c fastest, t-tile, b).
// Phase 1: 32 threads per i-row stage Ah (graph sum) into 16.6 KB LDS.
//   Edge-pair dot2 (avph pairs, padded w=0/self). f32 accum.
// Phase 2: MFMA gconv. A-frag dwords read from 4B-aligned base
//   (2*Sm)&~3 (== old 8B base + bhi select, cndmask-free); residual
//   shift {0,16} via alignbit. 16-tile loop fully unrolled: all LDS
//   reads are immediate-offset ds_read2_b32/ds_read_b32 off two bases.
//   D: col=o=lane&15 (<8 valid), rows t'=4q+reg -> 8B store per lane.
__global__ __launch_bounds__(256, 6) void k23_gcn_gconv(
    const unsigned short* __restrict__ in,    // B,F1,C,T f16
    unsigned short* __restrict__ outp,        // B,F1,C,T f16
    const int* __restrict__ deg, const int* __restrict__ col,
    const float* __restrict__ avals,          // 3*8*64*MAXDEG (boundary path)
    const unsigned int* __restrict__ avph,    // 3*8*64*8 packed pairs
    const uint4* __restrict__ wmf,            // 6*64 B-fragments
    const float* __restrict__ bnFs, int l)
{
  __shared__ __align__(16) uint4 ash[8 * ROW4];   // 16,640 B
  int tid = threadIdx.x;
  // bijective XCD swizzle (8192 blocks, 8 XCDs)
  int wgid = blockIdx.y * 4 + blockIdx.x;
  int swz  = (wgid & 7) * 1024 + (wgid >> 3);
  int c = swz & 63;
  int xt = (swz >> 6) & 3;
  int b = swz >> 8;
  int tb = xt * 1024;
  int wb = tb - 8;                     // staged range [wb, wb+1040)
  int dg = deg[c];                     // uniform -> s_load
  const int* cp = col + c*MAXDEG;

  // ---- phase 1: stage Ah into LDS, 32 threads per i-row ----
  {
    int i = tid >> 5;                  // 0..7
    int mlane = tid & 31;
    int dgp = (dg + 1) >> 1;
    const unsigned int* wpp = avph + ((l*8 + i)*64 + c) * 8;   // uniform
    const float* av = avals + ((l*8 + i)*64 + c) * MAXDEG;     // uniform
    const unsigned short* rbp = in + (size_t)((b*8 + i) * 64) * T_;
    for (int m = mlane; m < ROW4; m += 32) {
      int t = wb + 8*m;
      float a[8] = {0,0,0,0,0,0,0,0};
      if (t >= 0 && t + 7 < T_) {
        for (int p = 0; p < dgp; ++p) {
          int d0 = cp[2*p];            // uniform -> s_load
          int d1 = cp[2*p + 1];
          h16x2 w2 = as_h2(wpp[p]);    // uniform
          uint4 v0 = *(const uint4*)(rbp + d0*T_ + t);   // 16B aligned
          uint4 v1 = *(const uint4*)(rbp + d1*T_ + t);
          a[0] = DOT2(as_h2(PERM_LO(v1.x, v0.x)), w2, a[0]);
          a[1] = DOT2(as_h2(PERM_HI(v1.x, v0.x)), w2, a[1]);
          a[2] = DOT2(as_h2(PERM_LO(v1.y, v0.y)), w2, a[2]);
          a[3] = DOT2(as_h2(PERM_HI(v1.y, v0.y)), w2, a[3]);
          a[4] = DOT2(as_h2(PERM_LO(v1.z, v0.z)), w2, a[4]);
          a[5] = DOT2(as_h2(PERM_HI(v1.z, v0.z)), w2, a[5]);
          a[6] = DOT2(as_h2(PERM_LO(v1.w, v0.w)), w2, a[6]);
          a[7] = DOT2(as_h2(PERM_HI(v1.w, v0.w)), w2, a[7]);
        }
      } else if (t + 7 >= 0 && t < T_) {
        for (int e = 0; e < dg; ++e) {
          int d = cp[e];
          float wv = av[e];
          const unsigned short* rp = rbp + d*T_;
          #pragma unroll
          for (int q = 0; q < 8; ++q) {
            int tq = t + q;
            if (tq >= 0 && tq < T_)
              a[q] = fmaf(wv, lo_h((unsigned int)rp[tq]), a[q]);
          }
        }
      }
      uint4 o;
      o.x = pack2h(a[0], a[1]); o.y = pack2h(a[2], a[3]);
      o.z = pack2h(a[4], a[5]); o.w = pack2h(a[6], a[7]);
      ash[i*ROW4 + m] = o;
    }
  }
  __syncthreads();

  // ---- phase 2: MFMA gconv ----
  int lane = tid & 63;
  int wv4 = tid >> 6;                  // wave 0..3
  int m = lane & 15, q = lane >> 4;
  union { uint4 u; f16x8 h; } w0u, w1u;
  w0u.u = wmf[(l*2 + 0)*64 + lane];
  w1u.u = wmf[(l*2 + 1)*64 + lane];
  int o8 = (m < 8) ? m : 0;
  float sc  = bnFs[(l+1)*16 + o8];
  float shb = bnFs[(l+1)*16 + 8 + o8];
  int Sm = m + 5;                      // S = t_base + Sm (t_base % 16 == 0)
  unsigned shv = ((unsigned)Sm & 1u) * 16u;
  int base4 = q*ROWB + ((2*Sm) & ~3);  // 4B-aligned (folds old bhi select)
  const char* ashc = (const char*)ash;
  const unsigned int* p0 =
      (const unsigned int*)(ashc + base4 + wv4*512);
  const unsigned int* p1 =
      (const unsigned int*)(ashc + base4 + wv4*512 + 4*ROWB);
  unsigned short* orow = outp + (size_t)((b*8 + o8)*64 + c) * T_;
  #pragma unroll
  for (int tile = 0; tile < 16; ++tile) {
    int nb = tile * 8;                 // dword offset (32B per tile)
    unsigned dwa[5], dwb[5];
    #pragma unroll
    for (int j2 = 0; j2 < 5; ++j2) {   // immediate-offset ds_read2_b32/b32
      dwa[j2] = p0[nb + j2];
      dwb[j2] = p1[nb + j2];
    }
    union { unsigned d[4]; f16x8 h; } A0, A1;
    #pragma unroll
    for (int j = 0; j < 4; ++j) {
      A0.d[j] = alignb(dwa[j+1], dwa[j], shv);
      A1.d[j] = alignb(dwb[j+1], dwb[j], shv);
    }
    f32x4 acc = {0.0f, 0.0f, 0.0f, 0.0f};
    acc = __builtin_amdgcn_mfma_f32_16x16x32_f16(A0.h, w0u.h, acc, 0, 0, 0);
    acc = __builtin_amdgcn_mfma_f32_16x16x32_f16(A1.h, w1u.h, acc, 0, 0, 0);
    int t0g = tb + wv4*256 + tile*16 + 4*q;
    if (m < 8 && t0g < T_) {
      float e0 = eluf(acc[0]*sc + shb);
      float e1 = eluf(acc[1]*sc + shb);
      float e2 = eluf(acc[2]*sc + shb);
      float e3 = eluf(acc[3]*sc + shb);
      uint2 st; st.x = pack2h(e0, e1); st.y = pack2h(e2, e3);
      *(uint2*)(orow + t0g) = st;
    }
  }
}

// ---------------- K4: depthwise-over-C + bn + elu + avgpool4. 8 t/thread ---
// cc-pair dot2: (h_cc0[t],h_cc1[t]) via v_perm, weight pairs dwph (SGPR).
__global__ __launch_bounds__(256) void k4_dw(
    const unsigned short* __restrict__ in,    // B,F1,C,T f16
    const unsigned int* __restrict__ dwph,    // 16x32 packed f16 pairs
    const float* __restrict__ bnsps,
    float* __restrict__ p1)                   // B,16,1000 fp32
{
  int tid = threadIdx.x;
  int bg = blockIdx.y;                 // b*8+g
  int b = bg >> 3, g = bg & 7;
  int tile = blockIdx.x * 256 + tid;
  if (tile >= 500) return;
  int t0 = tile * 8;
  int base = bg * (64 * T_);
  const unsigned int* w0pp = dwph + (2*g)*32;      // uniform -> s_load
  const unsigned int* w1pp = dwph + (2*g + 1)*32;
  float a0[8] = {0,0,0,0,0,0,0,0}, a1[8] = {0,0,0,0,0,0,0,0};
  for (int p = 0; p < 32; ++p) {
    h16x2 w02 = as_h2(w0pp[p]);        // uniform
    h16x2 w12 = as_h2(w1pp[p]);        // uniform
    uint4 v0 = *(const uint4*)(in + base + (2*p)*T_ + t0);
    uint4 v1 = *(const uint4*)(in + base + (2*p + 1)*T_ + t0);
    unsigned pr;
    pr = PERM_LO(v1.x, v0.x);
    a0[0] = DOT2(as_h2(pr), w02, a0[0]); a1[0] = DOT2(as_h2(pr), w12, a1[0]);
    pr = PERM_HI(v1.x, v0.x);
    a0[1] = DOT2(as_h2(pr), w02, a0[1]); a1[1] = DOT2(as_h2(pr), w12, a1[1]);
    pr = PERM_LO(v1.y, v0.y);
    a0[2] = DOT2(as_h2(pr), w02, a0[2]); a1[2] = DOT2(as_h2(pr), w12, a1[2]);
    pr = PERM_HI(v1.y, v0.y);
    a0[3] = DOT2(as_h2(pr), w02, a0[3]); a1[3] = DOT2(as_h2(pr), w12, a1[3]);
    pr = PERM_LO(v1.z, v0.z);
    a0[4] = DOT2(as_h2(pr), w02, a0[4]); a1[4] = DOT2(as_h2(pr), w12, a1[4]);
    pr = PERM_HI(v1.z, v0.z);
    a0[5] = DOT2(as_h2(pr), w02, a0[5]); a1[5] = DOT2(as_h2(pr), w12, a1[5]);
    pr = PERM_LO(v1.w, v0.w);
    a0[6] = DOT2(as_h2(pr), w02, a0[6]); a1[6] = DOT2(as_h2(pr), w12, a1[6]);
    pr = PERM_HI(v1.w, v0.w);
    a0[7] = DOT2(as_h2(pr), w02, a0[7]); a1[7] = DOT2(as_h2(pr), w12, a1[7]);
  }
  float sc0 = bnsps[2*g],     sh0 = bnsps[16 + 2*g];
  float sc1 = bnsps[2*g + 1], sh1 = bnsps[16 + 2*g + 1];
  int oi = t0 >> 2;
  float2 r0, r1;
  r0.x = 0.25f * (eluf(a0[0]*sc0+sh0) + eluf(a0[1]*sc0+sh0)
                + eluf(a0[2]*sc0+sh0) + eluf(a0[3]*sc0+sh0));
  r0.y = 0.25f * (eluf(a0[4]*sc0+sh0) + eluf(a0[5]*sc0+sh0)
                + eluf(a0[6]*sc0+sh0) + eluf(a0[7]*sc0+sh0));
  r1.x = 0.25f * (eluf(a1[0]*sc1+sh1) + eluf(a1[1]*sc1+sh1)
                + eluf(a1[2]*sc1+sh1) + eluf(a1[3]*sc1+sh1));
  r1.y = 0.25f * (eluf(a1[4]*sc1+sh1) + eluf(a1[5]*sc1+sh1)
                + eluf(a1[6]*sc1+sh1) + eluf(a1[7]*sc1+sh1));
  *(float2*)(p1 + (b*16 + 2*g)*TP_ + oi)     = r0;
  *(float2*)(p1 + (b*16 + 2*g + 1)*TP_ + oi) = r1;
}

// ---------------- K5: sep depthwise(16) + pointwise(16x16) + bn + elu ------
__global__ __launch_bounds__(256) void k5_sep(
    const float* __restrict__ p1,             // B,16,1000
    const float* __restrict__ sdwc,           // 16x16 (uniform)
    const float* __restrict__ pwc,            // 16x16 (uniform)
    const float* __restrict__ bnseps,
    float* __restrict__ p2)                   // B,16,1001
{
  __shared__ float ps[16*272];
  int tid = threadIdx.x;
  int wq = blockIdx.x, b = blockIdx.y;
  int wb = wq * 256;
  for (int ch = 0; ch < 16; ++ch) {
    for (int s = tid; s < 272; s += 256) {
      int t = wb - 8 + s;
      ps[ch*272 + s] = (t >= 0 && t < TP_) ? p1[(b*16 + ch)*TP_ + t] : 0.0f;
    }
  }
  __syncthreads();
  int w0 = wb + tid;
  if (w0 >= W2_) return;
  float dws[16];
  for (int ch = 0; ch < 16; ++ch) {
    float a = 0.0f;
    #pragma unroll
    for (int k = 0; k < 16; ++k)
      a = fmaf(sdwc[ch*16 + k], ps[ch*272 + tid + k], a);
    dws[ch] = a;
  }
  for (int f = 0; f < 16; ++f) {
    float a = 0.0f;
    #pragma unroll
    for (int ch = 0; ch < 16; ++ch) a = fmaf(pwc[f*16 + ch], dws[ch], a);
    float sc = bnseps[f], sh = bnseps[16 + f];
    p2[(b*16 + f)*W2_ + w0] = eluf(a*sc + sh);
  }
}

// ---------------- K6: avgpool8 (first 1000) + fc ---------------------------
__global__ __launch_bounds__(256) void k6_fc(
    const float* __restrict__ p2,             // B,16,1001
    const float* __restrict__ fcwc,           // 4x2000
    const float* __restrict__ fcbc,           // 4
    const int* __restrict__ flag,
    void* __restrict__ outp)                  // B,4
{
  __shared__ float red[4*256];
  int tid = threadIdx.x;
  int b = blockIdx.x;
  float part[4] = {0.0f, 0.0f, 0.0f, 0.0f};
  for (int idx = tid; idx < 2000; idx += 256) {
    int f = idx / 125, q = idx - f*125;
    const float* src = p2 + (b*16 + f)*W2_ + q*8;
    float s = src[0]+src[1]+src[2]+src[3]+src[4]+src[5]+src[6]+src[7];
    float mval = 0.125f * s;
    #pragma unroll
    for (int n = 0; n < 4; ++n) part[n] = fmaf(fcwc[n*2000 + idx], mval, part[n]);
  }
  #pragma unroll
  for (int n = 0; n < 4; ++n) red[n*256 + tid] = part[n];
  __syncthreads();
  for (int s = 128; s > 0; s >>= 1) {
    if (tid < s) {
      #pragma unroll
      for (int n = 0; n < 4; ++n) red[n*256 + tid] += red[n*256 + tid + s];
    }
    __syncthreads();
  }
  if (tid < 4) {
    float val = red[tid*256] + fcbc[tid];
    if (*flag) ((float*)outp)[b*4 + tid] = val;
    else       ((unsigned short*)outp)[b*4 + tid] = f2bf(val);
  }
}

// ---------------------------------------------------------------------------
extern "C" void kernel_launch(void* const* d_in, const int* in_sizes, int n_in,
                              void* d_out, int out_size, void* d_ws, size_t ws_size,
                              hipStream_t stream) {
  const void* x     = d_in[0];
  const void* adj   = d_in[1];
  const void* w1    = d_in[2];
  const void* bnF   = d_in[3];
  const void* imp   = d_in[4];
  const void* gw    = d_in[5];
  const void* dww   = d_in[6];
  const void* bnsp  = d_in[7];
  const void* sdw   = d_in[8];
  const void* pw    = d_in[9];
  const void* bnsep = d_in[10];
  const void* fcw   = d_in[11];
  const void* fcb   = d_in[12];

  char* w = (char*)d_ws;
  const size_t OFF = 262144000;  // after two 131,072,000-byte f16 buffers
  unsigned short* bufA = (unsigned short*)(w);
  unsigned short* bufB = (unsigned short*)(w + 131072000);
  int*   flag   = (int*)  (w + OFF + 0);
  int*   deg    = (int*)  (w + OFF + 256);
  int*   col    = (int*)  (w + OFF + 512);
  float* avals  = (float*)(w + OFF + 4608);
  float* dwn    = (float*)(w + OFF + 108032);
  float* sdwc   = (float*)(w + OFF + 112128);
  float* pwc    = (float*)(w + OFF + 113152);
  float* fcwc   = (float*)(w + OFF + 114176);
  float* fcbc   = (float*)(w + OFF + 146176);
  float* bnFs   = (float*)(w + OFF + 146432);
  float* bnsps  = (float*)(w + OFF + 146688);
  float* bnseps = (float*)(w + OFF + 146944);
  float* p1     = (float*)(w + OFF + 147200);
  float* p2     = (float*)(w + OFF + 2195200);
  uint4* wmf    = (uint4*)(w + OFF + 4245248);              // 384 uint4
  unsigned int* avph = (unsigned int*)(w + OFF + 4251392);  // 12288 uints
  unsigned int* dwph = (unsigned int*)(w + OFF + 4300544);  // 512 uints
  unsigned int* w1h  = (unsigned int*)(w + OFF + 4302592);  // 256 uints

  k0_setup<<<1, 256, 0, stream>>>(adj, imp, dww, w1, bnF, gw, bnsp, sdw, pw,
                                  bnsep, fcw, fcb, flag, deg, col, avals,
                                  w1h, wmf, dwn, sdwc, pwc, fcwc, fcbc,
                                  bnFs, bnsps, bnseps, avph, dwph);
  k1_conv1_bn<<<dim3(4, B_*C_), 256, 0, stream>>>(x, w1h, bnFs, flag, bufA);
  for (int l = 0; l < 3; ++l) {
    const unsigned short* src = (l & 1) ? bufB : bufA;
    unsigned short*       dst = (l & 1) ? bufA : bufB;
    k23_gcn_gconv<<<dim3(4, B_*C_), 256, 0, stream>>>(src, dst, deg, col,
                                                      avals, avph, wmf, bnFs, l);
  }
  k4_dw<<<dim3(2, B_*F1_), 256, 0, stream>>>(bufB, dwph, bnsps, p1);
  k5_sep<<<dim3(4, B_), 256, 0, stream>>>(p1, sdwc, pwc, bnseps, p2);
  k6_fc<<<32, 256, 0, stream>>>(p2, fcwc, fcbc, flag, d_out);
}

// Round 7
// 514.117 us; speedup vs baseline: 1.7362x; 1.0609x over previous
//
#include <hip/hip_runtime.h>

// GCN-EEGNet forward, MI355X. Dtype-adaptive (fp32/bf16 detected in K0 via
// adjacency sentinel). Weights in ws, wave-uniform -> SGPR. Intermediates
// f16. Round-19b: r19 + compile fix (cvt_pkrtz returns __fp16x2, union
// member must match). Structural phase-2 rewrite in k23. r18 lesson:
// per-lane 4B LDS bases = 12.6M bank conflicts. Now: stride-2 row mapping
// — a 32-t supertile computes even-t rows (t'=2m) and odd-t rows (2m+1)
// as two MFMA pairs sharing ONE 5-dword read per i-half: start parity is
// lane-UNIFORM, so A_odd = register copy (0 VALU) and A_even = 4 alignbit
// (const shift 16). Reads consecutive-dword per lane (conflict-free),
// immediate read2 offsets. Epilogue: B cols 8-15 zero -> lanes m>=8 idle;
// ds_swizzle xor-8 (DS pipe) ships acc[2..3] there -> all 64 lanes do 4
// outputs each. v_cvt_pkrtz for all hot-path f16 packs.
// LESSON (r12): no empty blocks resonant with id%8 XCD rr.
// LESSON (r15): XCD swizzle (c fastest, then t, then b) -> FETCH 66 MB.
// LESSON (r18): per-lane-varying 4B LDS bases conflict; keep lane-uniform
// alignment and consecutive-dword patterns.
// Pipeline: K0 -> K1 conv1+bn -> 3x K23 -> K4 dw+bn+elu+pool4 -> K5 sep ->
// K6 pool8+fc.

#define B_   32
#define C_   64
#define T_   4000
#define F1_  8
#define TP_  1000
#define W2_  1001
#define MAXDEG 16
#define ROW4 130      // uint4 chunks per i-row staged in LDS (1040 halfs)
#define ROWD 520      // dwords per i-row

typedef _Float16 h16x2 __attribute__((ext_vector_type(2)));
typedef _Float16 f16x8 __attribute__((ext_vector_type(8)));
typedef float    f32x4 __attribute__((ext_vector_type(4)));
typedef __fp16   cvt16x2 __attribute__((ext_vector_type(2)));

static __device__ __forceinline__ float bf2f(unsigned short h) {
  union { unsigned int u; float f; } v; v.u = ((unsigned int)h) << 16; return v.f;
}
static __device__ __forceinline__ unsigned short f2bf(float f) {
  union { float f; unsigned int u; } v; v.f = f;
  unsigned int r = v.u + 0x7FFFu + ((v.u >> 16) & 1u);
  return (unsigned short)(r >> 16);
}
static __device__ __forceinline__ float lo_h(unsigned int u) {
  union { unsigned int u; _Float16 h[2]; } v; v.u = u; return (float)v.h[0];
}
static __device__ __forceinline__ unsigned int pack2h(float a, float b) {
  union { _Float16 h[2]; unsigned int u; } v;
  v.h[0] = (_Float16)a; v.h[1] = (_Float16)b; return v.u;
}
#if defined(__has_builtin) && __has_builtin(__builtin_amdgcn_cvt_pkrtz)
static __device__ __forceinline__ unsigned int pkh(float a, float b) {
  union { cvt16x2 h; unsigned int u; } v;
  v.h = __builtin_amdgcn_cvt_pkrtz(a, b);   // v_cvt_pkrtz_f16_f32, 1 instr
  return v.u;
}
#else
static __device__ __forceinline__ unsigned int pkh(float a, float b) {
  return pack2h(a, b);
}
#endif
static __device__ __forceinline__ h16x2 as_h2(unsigned int u) {
  union { unsigned int u; h16x2 h; } v; v.u = u; return v.h;
}
static __device__ __forceinline__ unsigned int alignb(unsigned int hi,
                                                      unsigned int lo,
                                                      unsigned int s) {
  // s in {0,16}; folds to v_alignbit_b32
  return (unsigned int)(((((unsigned long long)hi) << 32) | lo) >> s);
}
static __device__ __forceinline__ float swz8(float v) {
  // lane l receives lane (l^8)'s value; BitMode offset = (8<<10)|0x1F
  union { float f; int i; } a; a.f = v;
  a.i = __builtin_amdgcn_ds_swizzle(a.i, 0x201F);
  return a.f;
}
// (x.lo16, y.lo16) -> dword:  b0=x.b0 b1=x.b1 b2=y.b0 b3=y.b1
#define PERM_LO(y, x) __builtin_amdgcn_perm((y), (x), 0x05040100u)
// (x.hi16, y.hi16) -> dword
#define PERM_HI(y, x) __builtin_amdgcn_perm((y), (x), 0x07060302u)
#if defined(__has_builtin) && __has_builtin(__builtin_amdgcn_fdot2)
#define DOT2(a, b, c) __builtin_amdgcn_fdot2((a), (b), (c), false)
#else
static __device__ __forceinline__ float dot2_fb(h16x2 a, h16x2 b, float c) {
  return fmaf((float)a[0], (float)b[0], fmaf((float)a[1], (float)b[1], c));
}
#define DOT2(a, b, c) dot2_fb((a), (b), (c))
#endif
static __device__ __forceinline__ float eluf(float z) {
  return z > 0.0f ? z : __expf(z) - 1.0f;
}
static __device__ __forceinline__ float ldin(const void* p, int i, int isf32) {
  return isf32 ? ((const float*)p)[i] : bf2f(((const unsigned short*)p)[i]);
}

// ---------------- K0: dtype detect + canonicalize + CSR + bn fold ----------
__global__ __launch_bounds__(256) void k0_setup(
    const void* __restrict__ adj, const void* __restrict__ imp,
    const void* __restrict__ dww, const void* __restrict__ w1,
    const void* __restrict__ bnF, const void* __restrict__ gw,
    const void* __restrict__ bnsp, const void* __restrict__ sdw,
    const void* __restrict__ pw, const void* __restrict__ bnsep,
    const void* __restrict__ fcw, const void* __restrict__ fcb,
    int* __restrict__ flag, int* __restrict__ deg, int* __restrict__ col,
    float* __restrict__ avals, unsigned int* __restrict__ w1h,
    uint4* __restrict__ wmf, float* __restrict__ dwn,
    float* __restrict__ sdwc, float* __restrict__ pwc,
    float* __restrict__ fcwc, float* __restrict__ fcbc,
    float* __restrict__ bnFs, float* __restrict__ bnsps,
    float* __restrict__ bnseps,
    unsigned int* __restrict__ avph,   // 3*8*64*8 packed f16 weight pairs
    unsigned int* __restrict__ dwph)   // 16*32 packed f16 weight pairs
{
  __shared__ float dwr[1024];
  __shared__ float dsc[16];
  int tid = threadIdx.x;
  int isf32 = (((const float*)adj)[0] == 1.0f) ? 1 : 0;
  if (tid == 0) *flag = isf32;

  // conv1 weights as packed f16 pairs: w1h[f*32+p] = (w1[f][2p], w1[f][2p+1])
  for (int idx = tid; idx < 256; idx += 256) {
    int f = idx >> 5, p = idx & 31;
    w1h[idx] = pack2h(ldin(w1, f*64 + 2*p, isf32), ldin(w1, f*64 + 2*p + 1, isf32));
  }
  // MFMA B-fragments: wmf[(layer*2+frag)*64 + lane] = uint4 of 8 f16:
  // W[o=lane&15][i=(lane>>4)+4*frag][k=0..7], zero for o>=8.
  for (int idx = tid; idx < 384; idx += 256) {
    int lf = idx >> 6;            // layer*2+frag
    int layer = lf >> 1, frag = lf & 1;
    int lane2 = idx & 63;
    int o = lane2 & 15, ii = (lane2 >> 4) + 4*frag;
    uint4 v; v.x = 0u; v.y = 0u; v.z = 0u; v.w = 0u;
    if (o < 8) {
      int bi = layer*512 + (o*8 + ii)*8;
      v.x = pack2h(ldin(gw, bi+0, isf32), ldin(gw, bi+1, isf32));
      v.y = pack2h(ldin(gw, bi+2, isf32), ldin(gw, bi+3, isf32));
      v.z = pack2h(ldin(gw, bi+4, isf32), ldin(gw, bi+5, isf32));
      v.w = pack2h(ldin(gw, bi+6, isf32), ldin(gw, bi+7, isf32));
    }
    wmf[idx] = v;
  }
  for (int i = tid; i < 256;  i += 256) sdwc[i] = ldin(sdw, i, isf32);
  for (int i = tid; i < 256;  i += 256) pwc[i]  = ldin(pw, i, isf32);
  for (int i = tid; i < 8000; i += 256) fcwc[i] = ldin(fcw, i, isf32);
  if (tid < 4) fcbc[tid] = ldin(fcb, tid, isf32);
  for (int i = tid; i < 1024; i += 256) dwr[i] = ldin(dww, i, isf32);

  if (tid < 64) {            // CSR of adjacency (data-driven), self-padded
    int c = tid, n = 0;
    for (int e = 0; e < MAXDEG; ++e) col[c*MAXDEG + e] = c;
    for (int d = 0; d < 64; ++d) {
      if (ldin(adj, c*64 + d, isf32) != 0.0f) {
        if (n < MAXDEG) col[c*MAXDEG + n] = d;
        ++n;
      }
    }
    deg[c] = n < MAXDEG ? n : MAXDEG;
  }
  __syncthreads();
  if (tid < 16) {            // dw norm clamp scale
    float s2 = 0.0f;
    for (int c2 = 0; c2 < 64; ++c2) { float wv = dwr[tid*64 + c2]; s2 += wv*wv; }
    dsc[tid] = fminf(1.0f, 1.0f / fmaxf(sqrtf(s2), 1e-7f));
  }
  if (tid >= 64 && tid < 96) {   // bnF folded scale/shift: 4 stages x 8 ch
    int i = tid - 64, s = i >> 3, f = i & 7;
    float g = ldin(bnF, s*32 + f,      isf32);
    float b = ldin(bnF, s*32 + 8 + f,  isf32);
    float m = ldin(bnF, s*32 + 16 + f, isf32);
    float v = ldin(bnF, s*32 + 24 + f, isf32);
    float sc = g * rsqrtf(v + 1e-3f);
    bnFs[s*16 + f] = sc; bnFs[s*16 + 8 + f] = b - m*sc;
  }
  if (tid >= 96 && tid < 112) {  // bn_sp
    int ch = tid - 96;
    float g = ldin(bnsp, ch, isf32), b = ldin(bnsp, 16 + ch, isf32);
    float m = ldin(bnsp, 32 + ch, isf32), v = ldin(bnsp, 48 + ch, isf32);
    float sc = g * rsqrtf(v + 1e-3f);
    bnsps[ch] = sc; bnsps[16 + ch] = b - m*sc;
  }
  if (tid >= 112 && tid < 128) { // bn_sep
    int ch = tid - 112;
    float g = ldin(bnsep, ch, isf32), b = ldin(bnsep, 16 + ch, isf32);
    float m = ldin(bnsep, 32 + ch, isf32), v = ldin(bnsep, 48 + ch, isf32);
    float sc = g * rsqrtf(v + 1e-3f);
    bnseps[ch] = sc; bnseps[16 + ch] = b - m*sc;
  }
  for (int combo = tid; combo < 3*8*64; combo += 256) {
    int l = combo >> 9, f = (combo >> 6) & 7, c = combo & 63;
    int dg = deg[c];
    for (int e = 0; e < MAXDEG; ++e) {
      float v = 0.0f;
      if (e < dg) {
        int d = col[c*MAXDEG + e];
        v = ldin(adj, c*64 + d, isf32) * ldin(imp, ((l*8 + f)*64 + c)*64 + d, isf32);
      }
      avals[((l*8 + f)*64 + c)*MAXDEG + e] = v;
    }
  }
  __syncthreads();
  for (int i = tid; i < 1024; i += 256) dwn[i] = dwr[i] * dsc[i >> 6];
  // packed f16 edge-weight pairs from avals (global, visible after sync)
  for (int idx = tid; idx < 3*8*64*8; idx += 256) {
    int base16 = (idx >> 3) * MAXDEG, p = idx & 7;
    avph[idx] = pack2h(avals[base16 + 2*p], avals[base16 + 2*p + 1]);
  }
  __syncthreads();
  // packed f16 dw-weight pairs from dwn (global, visible after sync)
  for (int idx = tid; idx < 512; idx += 256) {
    int ch = idx >> 5, p = idx & 31;
    dwph[idx] = pack2h(dwn[ch*64 + 2*p], dwn[ch*64 + 2*p + 1]);
  }
}

// ---------------- K1: conv1 (64-tap) via f16 dot2 + bn0. 4 t/thread -------
__global__ __launch_bounds__(256, 4) void k1_conv1_bn(
    const void* __restrict__ x,               // B,C,T raw dtype
    const unsigned int* __restrict__ w1h,     // 8x32 packed f16 pairs
    const float* __restrict__ bnFs,
    const int* __restrict__ flag,
    unsigned short* __restrict__ outp)        // B,F1,C,T f16
{
  __shared__ __align__(16) unsigned int xs[548];   // 1096 halfs
  int tid = threadIdx.x;
  int bc = blockIdx.y;                 // b*64+c
  int b = bc >> 6, c = bc & 63;
  int tb = blockIdx.x * 1024;
  int isf32 = *flag;
  int row = bc * T_;
  if (isf32) {
    const float* xr = (const float*)x + row;
    for (int m = tid; m < 274; m += 256) {
      int tg = tb - 36 + 4*m;
      uint2 st;
      if (tg >= 0 && tg + 3 < T_) {
        float4 v = *(const float4*)(xr + tg);               // 16B aligned
        st.x = pkh(v.x, v.y); st.y = pkh(v.z, v.w);
      } else {
        float q0 = (tg   >= 0 && tg   < T_) ? xr[tg]   : 0.0f;
        float q1 = (tg+1 >= 0 && tg+1 < T_) ? xr[tg+1] : 0.0f;
        float q2 = (tg+2 >= 0 && tg+2 < T_) ? xr[tg+2] : 0.0f;
        float q3 = (tg+3 >= 0 && tg+3 < T_) ? xr[tg+3] : 0.0f;
        st.x = pkh(q0, q1); st.y = pkh(q2, q3);
      }
      *(uint2*)(xs + 2*m) = st;
    }
  } else {
    const unsigned short* xr = (const unsigned short*)x + row;
    for (int m = tid; m < 274; m += 256) {
      int tg = tb - 36 + 4*m;
      uint2 st;
      if (tg >= 0 && tg + 3 < T_) {
        uint2 v = *(const uint2*)(xr + tg);                 // 8B aligned
        st.x = pkh(bf2f((unsigned short)(v.x & 0xFFFFu)),
                   bf2f((unsigned short)(v.x >> 16)));
        st.y = pkh(bf2f((unsigned short)(v.y & 0xFFFFu)),
                   bf2f((unsigned short)(v.y >> 16)));
      } else {
        float q0 = (tg   >= 0 && tg   < T_) ? bf2f(xr[tg])   : 0.0f;
        float q1 = (tg+1 >= 0 && tg+1 < T_) ? bf2f(xr[tg+1]) : 0.0f;
        float q2 = (tg+2 >= 0 && tg+2 < T_) ? bf2f(xr[tg+2]) : 0.0f;
        float q3 = (tg+3 >= 0 && tg+3 < T_) ? bf2f(xr[tg+3]) : 0.0f;
        st.x = pkh(q0, q1); st.y = pkh(q2, q3);
      }
      *(uint2*)(xs + 2*m) = st;
    }
  }
  __syncthreads();
  int t0 = tb + 4*tid;
  if (t0 >= T_) return;
  float acc[8][4];
  #pragma unroll
  for (int f = 0; f < 8; ++f)
    #pragma unroll
    for (int j = 0; j < 4; ++j) acc[f][j] = 0.0f;
  uint2 a0 = *(const uint2*)(xs + 2*tid + 2);
  uint2 a1 = *(const uint2*)(xs + 2*tid + 4);
  unsigned u0 = a0.x, u1 = a0.y, u2 = a1.x, u3 = a1.y;
  for (int cc = 0; cc < 16; ++cc) {
    unsigned od0 = alignb(u1, u0, 16);
    unsigned od1 = alignb(u2, u1, 16);
    unsigned od2 = alignb(u3, u2, 16);
    #pragma unroll
    for (int f = 0; f < 8; ++f) {
      h16x2 wa = as_h2(w1h[f*32 + 2*cc]);      // uniform -> SGPR
      h16x2 wb = as_h2(w1h[f*32 + 2*cc + 1]);
      acc[f][0] = DOT2(as_h2(od0), wa, acc[f][0]);
      acc[f][0] = DOT2(as_h2(od1), wb, acc[f][0]);
      acc[f][1] = DOT2(as_h2(u1),  wa, acc[f][1]);
      acc[f][1] = DOT2(as_h2(u2),  wb, acc[f][1]);
      acc[f][2] = DOT2(as_h2(od1), wa, acc[f][2]);
      acc[f][2] = DOT2(as_h2(od2), wb, acc[f][2]);
      acc[f][3] = DOT2(as_h2(u2),  wa, acc[f][3]);
      acc[f][3] = DOT2(as_h2(u3),  wb, acc[f][3]);
    }
    u0 = u2; u1 = u3;
    if (cc < 15) {
      uint2 nx = *(const uint2*)(xs + 2*tid + 6 + 2*cc);
      u2 = nx.x; u3 = nx.y;
    }
  }
  #pragma unroll
  for (int f = 0; f < 8; ++f) {
    float sc = bnFs[f], sh = bnFs[8 + f];
    uint2 st;
    st.x = pkh(acc[f][0]*sc + sh, acc[f][1]*sc + sh);
    st.y = pkh(acc[f][2]*sc + sh, acc[f][3]*sc + sh);
    *(uint2*)(outp + ((b*8 + f)*64 + c)*T_ + t0) = st;
  }
}

// ---------------- K23: fused graph einsum + MFMA gconv + bn + elu ----------
// grid (4, B*C), 256 thr. XCD swizzle: work = (c fastest, t-tile, b).
// Phase 1: 32 threads per i-row stage Ah (graph sum) into 16.6 KB LDS.
//   Edge-pair dot2 (avph pairs, padded w=0/self). f32 accum.
// Phase 2: stride-2 supertiles. Per 32-t supertile s (8/wave):
//   even rows t'=2m (A_even, align shift 16) and odd rows 2m+1 (A_odd =
//   dword copy) share one 5-dword read per i-half at dword
//   q*520 + 128*wv4 + 16*s + m + 2 (consecutive per lane: conflict-free,
//   immediate read2 offsets). 4 MFMAs -> acc_e (t=t_base+8q+2r),
//   acc_o (+1). ds_swizzle xor-8 ships acc[2..3] to lanes m>=8 so all
//   64 lanes run bn+elu on 4 outputs and store one b64 (sel = m>=8 ->
//   t+4..7, o = m&7).
__global__ __launch_bounds__(256, 6) void k23_gcn_gconv(
    const unsigned short* __restrict__ in,    // B,F1,C,T f16
    unsigned short* __restrict__ outp,        // B,F1,C,T f16
    const int* __restrict__ deg, const int* __restrict__ col,
    const float* __restrict__ avals,          // 3*8*64*MAXDEG (boundary path)
    const unsigned int* __restrict__ avph,    // 3*8*64*8 packed pairs
    const uint4* __restrict__ wmf,            // 6*64 B-fragments
    const float* __restrict__ bnFs, int l)
{
  __shared__ __align__(16) uint4 ash[8 * ROW4];   // 16,640 B
  int tid = threadIdx.x;
  // bijective XCD swizzle (8192 blocks, 8 XCDs)
  int wgid = blockIdx.y * 4 + blockIdx.x;
  int swz  = (wgid & 7) * 1024 + (wgid >> 3);
  int c = swz & 63;
  int xt = (swz >> 6) & 3;
  int b = swz >> 8;
  int tb = xt * 1024;
  int wb = tb - 8;                     // staged range [wb, wb+1040)
  int dg = deg[c];                     // uniform -> s_load
  const int* cp = col + c*MAXDEG;

  // ---- phase 1: stage Ah into LDS, 32 threads per i-row ----
  {
    int i = tid >> 5;                  // 0..7
    int mlane = tid & 31;
    int dgp = (dg + 1) >> 1;
    const unsigned int* wpp = avph + ((l*8 + i)*64 + c) * 8;   // uniform
    const float* av = avals + ((l*8 + i)*64 + c) * MAXDEG;     // uniform
    const unsigned short* rbp = in + (size_t)((b*8 + i) * 64) * T_;
    for (int m = mlane; m < ROW4; m += 32) {
      int t = wb + 8*m;
      float a[8] = {0,0,0,0,0,0,0,0};
      if (t >= 0 && t + 7 < T_) {
        for (int p = 0; p < dgp; ++p) {
          int d0 = cp[2*p];            // uniform -> s_load
          int d1 = cp[2*p + 1];
          h16x2 w2 = as_h2(wpp[p]);    // uniform
          uint4 v0 = *(const uint4*)(rbp + d0*T_ + t);   // 16B aligned
          uint4 v1 = *(const uint4*)(rbp + d1*T_ + t);
          a[0] = DOT2(as_h2(PERM_LO(v1.x, v0.x)), w2, a[0]);
          a[1] = DOT2(as_h2(PERM_HI(v1.x, v0.x)), w2, a[1]);
          a[2] = DOT2(as_h2(PERM_LO(v1.y, v0.y)), w2, a[2]);
          a[3] = DOT2(as_h2(PERM_HI(v1.y, v0.y)), w2, a[3]);
          a[4] = DOT2(as_h2(PERM_LO(v1.z, v0.z)), w2, a[4]);
          a[5] = DOT2(as_h2(PERM_HI(v1.z, v0.z)), w2, a[5]);
          a[6] = DOT2(as_h2(PERM_LO(v1.w, v0.w)), w2, a[6]);
          a[7] = DOT2(as_h2(PERM_HI(v1.w, v0.w)), w2, a[7]);
        }
      } else if (t + 7 >= 0 && t < T_) {
        for (int e = 0; e < dg; ++e) {
          int d = cp[e];
          float wv = av[e];
          const unsigned short* rp = rbp + d*T_;
          #pragma unroll
          for (int q = 0; q < 8; ++q) {
            int tq = t + q;
            if (tq >= 0 && tq < T_)
              a[q] = fmaf(wv, lo_h((unsigned int)rp[tq]), a[q]);
          }
        }
      }
      uint4 o;
      o.x = pkh(a[0], a[1]); o.y = pkh(a[2], a[3]);
      o.z = pkh(a[4], a[5]); o.w = pkh(a[6], a[7]);
      ash[i*ROW4 + m] = o;
    }
  }
  __syncthreads();

  // ---- phase 2: MFMA gconv, stride-2 supertiles ----
  int lane = tid & 63;
  int wv4 = tid >> 6;                  // wave 0..3
  int m = lane & 15, q = lane >> 4;
  int sel = (m >> 3) & 1;              // 0: t+0..3, 1: t+4..7
  union { uint4 u; f16x8 h; } w0u, w1u;
  w0u.u = wmf[(l*2 + 0)*64 + lane];
  w1u.u = wmf[(l*2 + 1)*64 + lane];
  int o8 = m & 7;
  float sc  = bnFs[(l+1)*16 + o8];
  float shb = bnFs[(l+1)*16 + 8 + o8];
  const unsigned int* ashd = (const unsigned int*)ash;
  const unsigned int* p0 = ashd + q*ROWD + wv4*128 + m + 2;   // dword idx
  const unsigned int* p1 = p0 + 4*ROWD;
  unsigned short* orow = outp + (size_t)((b*8 + o8)*64 + c) * T_;
  #pragma unroll
  for (int s = 0; s < 8; ++s) {
    unsigned dwa[5], dwb[5];
    #pragma unroll
    for (int j = 0; j < 5; ++j) {      // immediate-offset ds_read2_b32
      dwa[j] = p0[16*s + j];
      dwb[j] = p1[16*s + j];
    }
    union { unsigned d[4]; f16x8 h; } Ae0, Ao0, Ae1, Ao1;
    #pragma unroll
    for (int j = 0; j < 4; ++j) {
      Ao0.d[j] = dwa[j+1];                       // odd rows: pure copy
      Ae0.d[j] = alignb(dwa[j+1], dwa[j], 16);   // even rows: const shift
      Ao1.d[j] = dwb[j+1];
      Ae1.d[j] = alignb(dwb[j+1], dwb[j], 16);
    }
    f32x4 ae = {0.0f, 0.0f, 0.0f, 0.0f};
    f32x4 ao = {0.0f, 0.0f, 0.0f, 0.0f};
    ae = __builtin_amdgcn_mfma_f32_16x16x32_f16(Ae0.h, w0u.h, ae, 0, 0, 0);
    ae = __builtin_amdgcn_mfma_f32_16x16x32_f16(Ae1.h, w1u.h, ae, 0, 0, 0);
    ao = __builtin_amdgcn_mfma_f32_16x16x32_f16(Ao0.h, w0u.h, ao, 0, 0, 0);
    ao = __builtin_amdgcn_mfma_f32_16x16x32_f16(Ao1.h, w1u.h, ao, 0, 0, 0);
    // lanes m>=8 receive (m-8)'s acc[2..3] -> all lanes do 4 outputs
    float r0 = swz8(ae[2]);
    float r1 = swz8(ao[2]);
    float r2 = swz8(ae[3]);
    float r3 = swz8(ao[3]);
    float y0 = sel ? r0 : ae[0];
    float y1 = sel ? r1 : ao[0];
    float y2 = sel ? r2 : ae[1];
    float y3 = sel ? r3 : ao[1];
    int t0g = tb + wv4*256 + s*32 + 8*q + 4*sel;
    if (t0g < T_) {
      uint2 st;
      st.x = pkh(eluf(y0*sc + shb), eluf(y1*sc + shb));
      st.y = pkh(eluf(y2*sc + shb), eluf(y3*sc + shb));
      *(uint2*)(orow + t0g) = st;
    }
  }
}

// ---------------- K4: depthwise-over-C + bn + elu + avgpool4. 8 t/thread ---
// cc-pair dot2: (h_cc0[t],h_cc1[t]) via v_perm, weight pairs dwph (SGPR).
__global__ __launch_bounds__(256) void k4_dw(
    const unsigned short* __restrict__ in,    // B,F1,C,T f16
    const unsigned int* __restrict__ dwph,    // 16x32 packed f16 pairs
    const float* __restrict__ bnsps,
    float* __restrict__ p1)                   // B,16,1000 fp32
{
  int tid = threadIdx.x;
  int bg = blockIdx.y;                 // b*8+g
  int b = bg >> 3, g = bg & 7;
  int tile = blockIdx.x * 256 + tid;
  if (tile >= 500) return;
  int t0 = tile * 8;
  int base = bg * (64 * T_);
  const unsigned int* w0pp = dwph + (2*g)*32;      // uniform -> s_load
  const unsigned int* w1pp = dwph + (2*g + 1)*32;
  float a0[8] = {0,0,0,0,0,0,0,0}, a1[8] = {0,0,0,0,0,0,0,0};
  for (int p = 0; p < 32; ++p) {
    h16x2 w02 = as_h2(w0pp[p]);        // uniform
    h16x2 w12 = as_h2(w1pp[p]);        // uniform
    uint4 v0 = *(const uint4*)(in + base + (2*p)*T_ + t0);
    uint4 v1 = *(const uint4*)(in + base + (2*p + 1)*T_ + t0);
    unsigned pr;
    pr = PERM_LO(v1.x, v0.x);
    a0[0] = DOT2(as_h2(pr), w02, a0[0]); a1[0] = DOT2(as_h2(pr), w12, a1[0]);
    pr = PERM_HI(v1.x, v0.x);
    a0[1] = DOT2(as_h2(pr), w02, a0[1]); a1[1] = DOT2(as_h2(pr), w12, a1[1]);
    pr = PERM_LO(v1.y, v0.y);
    a0[2] = DOT2(as_h2(pr), w02, a0[2]); a1[2] = DOT2(as_h2(pr), w12, a1[2]);
    pr = PERM_HI(v1.y, v0.y);
    a0[3] = DOT2(as_h2(pr), w02, a0[3]); a1[3] = DOT2(as_h2(pr), w12, a1[3]);
    pr = PERM_LO(v1.z, v0.z);
    a0[4] = DOT2(as_h2(pr), w02, a0[4]); a1[4] = DOT2(as_h2(pr), w12, a1[4]);
    pr = PERM_HI(v1.z, v0.z);
    a0[5] = DOT2(as_h2(pr), w02, a0[5]); a1[5] = DOT2(as_h2(pr), w12, a1[5]);
    pr = PERM_LO(v1.w, v0.w);
    a0[6] = DOT2(as_h2(pr), w02, a0[6]); a1[6] = DOT2(as_h2(pr), w12, a1[6]);
    pr = PERM_HI(v1.w, v0.w);
    a0[7] = DOT2(as_h2(pr), w02, a0[7]); a1[7] = DOT2(as_h2(pr), w12, a1[7]);
  }
  float sc0 = bnsps[2*g],     sh0 = bnsps[16 + 2*g];
  float sc1 = bnsps[2*g + 1], sh1 = bnsps[16 + 2*g + 1];
  int oi = t0 >> 2;
  float2 r0, r1;
  r0.x = 0.25f * (eluf(a0[0]*sc0+sh0) + eluf(a0[1]*sc0+sh0)
                + eluf(a0[2]*sc0+sh0) + eluf(a0[3]*sc0+sh0));
  r0.y = 0.25f * (eluf(a0[4]*sc0+sh0) + eluf(a0[5]*sc0+sh0)
                + eluf(a0[6]*sc0+sh0) + eluf(a0[7]*sc0+sh0));
  r1.x = 0.25f * (eluf(a1[0]*sc1+sh1) + eluf(a1[1]*sc1+sh1)
                + eluf(a1[2]*sc1+sh1) + eluf(a1[3]*sc1+sh1));
  r1.y = 0.25f * (eluf(a1[4]*sc1+sh1) + eluf(a1[5]*sc1+sh1)
                + eluf(a1[6]*sc1+sh1) + eluf(a1[7]*sc1+sh1));
  *(float2*)(p1 + (b*16 + 2*g)*TP_ + oi)     = r0;
  *(float2*)(p1 + (b*16 + 2*g + 1)*TP_ + oi) = r1;
}

// ---------------- K5: sep depthwise(16) + pointwise(16x16) + bn + elu ------
__global__ __launch_bounds__(256) void k5_sep(
    const float* __restrict__ p1,             // B,16,1000
    const float* __restrict__ sdwc,           // 16x16 (uniform)
    const float* __restrict__ pwc,            // 16x16 (uniform)
    const float* __restrict__ bnseps,
    float* __restrict__ p2)                   // B,16,1001
{
  __shared__ float ps[16*272];
  int tid = threadIdx.x;
  int wq = blockIdx.x, b = blockIdx.y;
  int wb = wq * 256;
  for (int ch = 0; ch < 16; ++ch) {
    for (int s = tid; s < 272; s += 256) {
      int t = wb - 8 + s;
      ps[ch*272 + s] = (t >= 0 && t < TP_) ? p1[(b*16 + ch)*TP_ + t] : 0.0f;
    }
  }
  __syncthreads();
  int w0 = wb + tid;
  if (w0 >= W2_) return;
  float dws[16];
  for (int ch = 0; ch < 16; ++ch) {
    float a = 0.0f;
    #pragma unroll
    for (int k = 0; k < 16; ++k)
      a = fmaf(sdwc[ch*16 + k], ps[ch*272 + tid + k], a);
    dws[ch] = a;
  }
  for (int f = 0; f < 16; ++f) {
    float a = 0.0f;
    #pragma unroll
    for (int ch = 0; ch < 16; ++ch) a = fmaf(pwc[f*16 + ch], dws[ch], a);
    float sc = bnseps[f], sh = bnseps[16 + f];
    p2[(b*16 + f)*W2_ + w0] = eluf(a*sc + sh);
  }
}

// ---------------- K6: avgpool8 (first 1000) + fc ---------------------------
__global__ __launch_bounds__(256) void k6_fc(
    const float* __restrict__ p2,             // B,16,1001
    const float* __restrict__ fcwc,           // 4x2000
    const float* __restrict__ fcbc,           // 4
    const int* __restrict__ flag,
    void* __restrict__ outp)                  // B,4
{
  __shared__ float red[4*256];
  int tid = threadIdx.x;
  int b = blockIdx.x;
  float part[4] = {0.0f, 0.0f, 0.0f, 0.0f};
  for (int idx = tid; idx < 2000; idx += 256) {
    int f = idx / 125, q = idx - f*125;
    const float* src = p2 + (b*16 + f)*W2_ + q*8;
    float s = src[0]+src[1]+src[2]+src[3]+src[4]+src[5]+src[6]+src[7];
    float mval = 0.125f * s;
    #pragma unroll
    for (int n = 0; n < 4; ++n) part[n] = fmaf(fcwc[n*2000 + idx], mval, part[n]);
  }
  #pragma unroll
  for (int n = 0; n < 4; ++n) red[n*256 + tid] = part[n];
  __syncthreads();
  for (int s = 128; s > 0; s >>= 1) {
    if (tid < s) {
      #pragma unroll
      for (int n = 0; n < 4; ++n) red[n*256 + tid] += red[n*256 + tid + s];
    }
    __syncthreads();
  }
  if (tid < 4) {
    float val = red[tid*256] + fcbc[tid];
    if (*flag) ((float*)outp)[b*4 + tid] = val;
    else       ((unsigned short*)outp)[b*4 + tid] = f2bf(val);
  }
}

// ---------------------------------------------------------------------------
extern "C" void kernel_launch(void* const* d_in, const int* in_sizes, int n_in,
                              void* d_out, int out_size, void* d_ws, size_t ws_size,
                              hipStream_t stream) {
  const void* x     = d_in[0];
  const void* adj   = d_in[1];
  const void* w1    = d_in[2];
  const void* bnF   = d_in[3];
  const void* imp   = d_in[4];
  const void* gw    = d_in[5];
  const void* dww   = d_in[6];
  const void* bnsp  = d_in[7];
  const void* sdw   = d_in[8];
  const void* pw    = d_in[9];
  const void* bnsep = d_in[10];
  const void* fcw   = d_in[11];
  const void* fcb   = d_in[12];

  char* w = (char*)d_ws;
  const size_t OFF = 262144000;  // after two 131,072,000-byte f16 buffers
  unsigned short* bufA = (unsigned short*)(w);
  unsigned short* bufB = (unsigned short*)(w + 131072000);
  int*   flag   = (int*)  (w + OFF + 0);
  int*   deg    = (int*)  (w + OFF + 256);
  int*   col    = (int*)  (w + OFF + 512);
  float* avals  = (float*)(w + OFF + 4608);
  float* dwn    = (float*)(w + OFF + 108032);
  float* sdwc   = (float*)(w + OFF + 112128);
  float* pwc    = (float*)(w + OFF + 113152);
  float* fcwc   = (float*)(w + OFF + 114176);
  float* fcbc   = (float*)(w + OFF + 146176);
  float* bnFs   = (float*)(w + OFF + 146432);
  float* bnsps  = (float*)(w + OFF + 146688);
  float* bnseps = (float*)(w + OFF + 146944);
  float* p1     = (float*)(w + OFF + 147200);
  float* p2     = (float*)(w + OFF + 2195200);
  uint4* wmf    = (uint4*)(w + OFF + 4245248);              // 384 uint4
  unsigned int* avph = (unsigned int*)(w + OFF + 4251392);  // 12288 uints
  unsigned int* dwph = (unsigned int*)(w + OFF + 4300544);  // 512 uints
  unsigned int* w1h  = (unsigned int*)(w + OFF + 4302592);  // 256 uints

  k0_setup<<<1, 256, 0, stream>>>(adj, imp, dww, w1, bnF, gw, bnsp, sdw, pw,
                                  bnsep, fcw, fcb, flag, deg, col, avals,
                                  w1h, wmf, dwn, sdwc, pwc, fcwc, fcbc,
                                  bnFs, bnsps, bnseps, avph, dwph);
  k1_conv1_bn<<<dim3(4, B_*C_), 256, 0, stream>>>(x, w1h, bnFs, flag, bufA);
  for (int l = 0; l < 3; ++l) {
    const unsigned short* src = (l & 1) ? bufB : bufA;
    unsigned short*       dst = (l & 1) ? bufA : bufB;
    k23_gcn_gconv<<<dim3(4, B_*C_), 256, 0, stream>>>(src, dst, deg, col,
                                                      avals, avph, wmf, bnFs, l);
  }
  k4_dw<<<dim3(2, B_*F1_), 256, 0, stream>>>(bufB, dwph, bnsps, p1);
  k5_sep<<<dim3(4, B_), 256, 0, stream>>>(p1, sdwc, pwc, bnseps, p2);
  k6_fc<<<32, 256, 0, stream>>>(p2, fcwc, fcbc, flag, d_out);
}

// Round 8
// 454.220 us; speedup vs baseline: 1.9652x; 1.1319x over previous
//
#include <hip/hip_runtime.h>

// GCN-EEGNet forward, MI355X. Dtype-adaptive (fp32/bf16 detected in K0 via
// adjacency sentinel). Weights in ws, wave-uniform -> SGPR. Intermediates
// f16. Round-20: (a) K1 conv1 moved to the verified k23 stride-2 MFMA
// structure (conv1 IS a GEMM: out[t,f]=sum_k x[t+k-31] w1[f][k], K=64 =
// 2 MFMAs/16t). A-frags from the existing f16 LDS window: odd rows =
// dword copy, even rows = alignbit-16 (lane-uniform parity); per-lane
// dword base 2+m+4q (+16/supertile) — cross-lane overlaps are same-
// address broadcasts (free). B-frags w1mf packed in K0. swz8 epilogue
// (B cols 8-15 zero). (b) K0 de-serialized: avals+avph -> k0b kernel
// (grid 6, one (l,f,c) combo/thread, avph from own-register avals).
// LESSON (r12): no empty blocks resonant with id%8 XCD rr.
// LESSON (r15): XCD swizzle (c fastest, then t, then b) -> FETCH 66 MB.
// LESSON (r18): per-lane-varying 4B LDS bases conflict; keep lane-uniform
// alignment and consecutive-dword/broadcast patterns.
// Pipeline: K0 -> K0b -> K1 conv1+bn (MFMA) -> 3x K23 -> K4 dw+pool4 ->
// K5 sep -> K6 pool8+fc.

#define B_   32
#define C_   64
#define T_   4000
#define F1_  8
#define TP_  1000
#define W2_  1001
#define MAXDEG 16
#define ROW4 130      // uint4 chunks per i-row staged in LDS (1040 halfs)
#define ROWD 520      // dwords per i-row

typedef _Float16 h16x2 __attribute__((ext_vector_type(2)));
typedef _Float16 f16x8 __attribute__((ext_vector_type(8)));
typedef float    f32x4 __attribute__((ext_vector_type(4)));
typedef __fp16   cvt16x2 __attribute__((ext_vector_type(2)));

static __device__ __forceinline__ float bf2f(unsigned short h) {
  union { unsigned int u; float f; } v; v.u = ((unsigned int)h) << 16; return v.f;
}
static __device__ __forceinline__ unsigned short f2bf(float f) {
  union { float f; unsigned int u; } v; v.f = f;
  unsigned int r = v.u + 0x7FFFu + ((v.u >> 16) & 1u);
  return (unsigned short)(r >> 16);
}
static __device__ __forceinline__ float lo_h(unsigned int u) {
  union { unsigned int u; _Float16 h[2]; } v; v.u = u; return (float)v.h[0];
}
static __device__ __forceinline__ unsigned int pack2h(float a, float b) {
  union { _Float16 h[2]; unsigned int u; } v;
  v.h[0] = (_Float16)a; v.h[1] = (_Float16)b; return v.u;
}
#if defined(__has_builtin) && __has_builtin(__builtin_amdgcn_cvt_pkrtz)
static __device__ __forceinline__ unsigned int pkh(float a, float b) {
  union { cvt16x2 h; unsigned int u; } v;
  v.h = __builtin_amdgcn_cvt_pkrtz(a, b);   // v_cvt_pkrtz_f16_f32, 1 instr
  return v.u;
}
#else
static __device__ __forceinline__ unsigned int pkh(float a, float b) {
  return pack2h(a, b);
}
#endif
static __device__ __forceinline__ h16x2 as_h2(unsigned int u) {
  union { unsigned int u; h16x2 h; } v; v.u = u; return v.h;
}
static __device__ __forceinline__ unsigned int alignb(unsigned int hi,
                                                      unsigned int lo,
                                                      unsigned int s) {
  // s in {0,16}; folds to v_alignbit_b32
  return (unsigned int)(((((unsigned long long)hi) << 32) | lo) >> s);
}
static __device__ __forceinline__ float swz8(float v) {
  // lane l receives lane (l^8)'s value; BitMode offset = (8<<10)|0x1F
  union { float f; int i; } a; a.f = v;
  a.i = __builtin_amdgcn_ds_swizzle(a.i, 0x201F);
  return a.f;
}
// (x.lo16, y.lo16) -> dword:  b0=x.b0 b1=x.b1 b2=y.b0 b3=y.b1
#define PERM_LO(y, x) __builtin_amdgcn_perm((y), (x), 0x05040100u)
// (x.hi16, y.hi16) -> dword
#define PERM_HI(y, x) __builtin_amdgcn_perm((y), (x), 0x07060302u)
#if defined(__has_builtin) && __has_builtin(__builtin_amdgcn_fdot2)
#define DOT2(a, b, c) __builtin_amdgcn_fdot2((a), (b), (c), false)
#else
static __device__ __forceinline__ float dot2_fb(h16x2 a, h16x2 b, float c) {
  return fmaf((float)a[0], (float)b[0], fmaf((float)a[1], (float)b[1], c));
}
#define DOT2(a, b, c) dot2_fb((a), (b), (c))
#endif
static __device__ __forceinline__ float eluf(float z) {
  return z > 0.0f ? z : __expf(z) - 1.0f;
}
static __device__ __forceinline__ float ldin(const void* p, int i, int isf32) {
  return isf32 ? ((const float*)p)[i] : bf2f(((const unsigned short*)p)[i]);
}

// ---------------- K0: dtype detect + canonicalize + CSR + bn fold ----------
__global__ __launch_bounds__(256) void k0_setup(
    const void* __restrict__ adj, const void* __restrict__ imp,
    const void* __restrict__ dww, const void* __restrict__ w1,
    const void* __restrict__ bnF, const void* __restrict__ gw,
    const void* __restrict__ bnsp, const void* __restrict__ sdw,
    const void* __restrict__ pw, const void* __restrict__ bnsep,
    const void* __restrict__ fcw, const void* __restrict__ fcb,
    int* __restrict__ flag, int* __restrict__ deg, int* __restrict__ col,
    uint4* __restrict__ w1mf,
    uint4* __restrict__ wmf, float* __restrict__ dwn,
    float* __restrict__ sdwc, float* __restrict__ pwc,
    float* __restrict__ fcwc, float* __restrict__ fcbc,
    float* __restrict__ bnFs, float* __restrict__ bnsps,
    float* __restrict__ bnseps,
    unsigned int* __restrict__ dwph)   // 16*32 packed f16 weight pairs
{
  __shared__ float dwr[1024];
  __shared__ float dsc[16];
  int tid = threadIdx.x;
  int isf32 = (((const float*)adj)[0] == 1.0f) ? 1 : 0;
  if (tid == 0) *flag = isf32;

  // K1 MFMA B-fragments: w1mf[kk*64 + lane] = 8 f16 of
  // w1[o=lane&15][32*kk + 8*(lane>>4) + 0..7], zero for o>=8.
  for (int idx = tid; idx < 128; idx += 256) {
    int kk = idx >> 6, l = idx & 63;
    int o = l & 15, q = l >> 4;
    uint4 v; v.x = 0u; v.y = 0u; v.z = 0u; v.w = 0u;
    if (o < 8) {
      int bi = o*64 + 32*kk + 8*q;
      v.x = pack2h(ldin(w1, bi+0, isf32), ldin(w1, bi+1, isf32));
      v.y = pack2h(ldin(w1, bi+2, isf32), ldin(w1, bi+3, isf32));
      v.z = pack2h(ldin(w1, bi+4, isf32), ldin(w1, bi+5, isf32));
      v.w = pack2h(ldin(w1, bi+6, isf32), ldin(w1, bi+7, isf32));
    }
    w1mf[idx] = v;
  }
  // k23 MFMA B-fragments: wmf[(layer*2+frag)*64 + lane] = uint4 of 8 f16:
  // W[o=lane&15][i=(lane>>4)+4*frag][k=0..7], zero for o>=8.
  for (int idx = tid; idx < 384; idx += 256) {
    int lf = idx >> 6;            // layer*2+frag
    int layer = lf >> 1, frag = lf & 1;
    int lane2 = idx & 63;
    int o = lane2 & 15, ii = (lane2 >> 4) + 4*frag;
    uint4 v; v.x = 0u; v.y = 0u; v.z = 0u; v.w = 0u;
    if (o < 8) {
      int bi = layer*512 + (o*8 + ii)*8;
      v.x = pack2h(ldin(gw, bi+0, isf32), ldin(gw, bi+1, isf32));
      v.y = pack2h(ldin(gw, bi+2, isf32), ldin(gw, bi+3, isf32));
      v.z = pack2h(ldin(gw, bi+4, isf32), ldin(gw, bi+5, isf32));
      v.w = pack2h(ldin(gw, bi+6, isf32), ldin(gw, bi+7, isf32));
    }
    wmf[idx] = v;
  }
  for (int i = tid; i < 256;  i += 256) sdwc[i] = ldin(sdw, i, isf32);
  for (int i = tid; i < 256;  i += 256) pwc[i]  = ldin(pw, i, isf32);
  for (int i = tid; i < 8000; i += 256) fcwc[i] = ldin(fcw, i, isf32);
  if (tid < 4) fcbc[tid] = ldin(fcb, tid, isf32);
  for (int i = tid; i < 1024; i += 256) dwr[i] = ldin(dww, i, isf32);

  if (tid < 64) {            // CSR of adjacency (data-driven), self-padded
    int c = tid, n = 0;
    for (int e = 0; e < MAXDEG; ++e) col[c*MAXDEG + e] = c;
    for (int d = 0; d < 64; ++d) {
      if (ldin(adj, c*64 + d, isf32) != 0.0f) {
        if (n < MAXDEG) col[c*MAXDEG + n] = d;
        ++n;
      }
    }
    deg[c] = n < MAXDEG ? n : MAXDEG;
  }
  __syncthreads();
  if (tid < 16) {            // dw norm clamp scale
    float s2 = 0.0f;
    for (int c2 = 0; c2 < 64; ++c2) { float wv = dwr[tid*64 + c2]; s2 += wv*wv; }
    dsc[tid] = fminf(1.0f, 1.0f / fmaxf(sqrtf(s2), 1e-7f));
  }
  if (tid >= 64 && tid < 96) {   // bnF folded scale/shift: 4 stages x 8 ch
    int i = tid - 64, s = i >> 3, f = i & 7;
    float g = ldin(bnF, s*32 + f,      isf32);
    float b = ldin(bnF, s*32 + 8 + f,  isf32);
    float m = ldin(bnF, s*32 + 16 + f, isf32);
    float v = ldin(bnF, s*32 + 24 + f, isf32);
    float sc = g * rsqrtf(v + 1e-3f);
    bnFs[s*16 + f] = sc; bnFs[s*16 + 8 + f] = b - m*sc;
  }
  if (tid >= 96 && tid < 112) {  // bn_sp
    int ch = tid - 96;
    float g = ldin(bnsp, ch, isf32), b = ldin(bnsp, 16 + ch, isf32);
    float m = ldin(bnsp, 32 + ch, isf32), v = ldin(bnsp, 48 + ch, isf32);
    float sc = g * rsqrtf(v + 1e-3f);
    bnsps[ch] = sc; bnsps[16 + ch] = b - m*sc;
  }
  if (tid >= 112 && tid < 128) { // bn_sep
    int ch = tid - 112;
    float g = ldin(bnsep, ch, isf32), b = ldin(bnsep, 16 + ch, isf32);
    float m = ldin(bnsep, 32 + ch, isf32), v = ldin(bnsep, 48 + ch, isf32);
    float sc = g * rsqrtf(v + 1e-3f);
    bnseps[ch] = sc; bnseps[16 + ch] = b - m*sc;
  }
  __syncthreads();
  for (int i = tid; i < 1024; i += 256) dwn[i] = dwr[i] * dsc[i >> 6];
  __syncthreads();
  // packed f16 dw-weight pairs (from shared dwr*dsc, no global dep)
  for (int idx = tid; idx < 512; idx += 256) {
    int ch = idx >> 5, p = idx & 31;
    dwph[idx] = pack2h(dwr[ch*64 + 2*p]   * dsc[ch],
                       dwr[ch*64 + 2*p+1] * dsc[ch]);
  }
}

// ---------------- K0b: avals + avph (parallel over 1536 combos) -----------
// grid (6), 256 thr: combo = (l*8+f)*64+c. avph from own-register avals.
__global__ __launch_bounds__(256) void k0b_avals(
    const void* __restrict__ adj, const void* __restrict__ imp,
    const int* __restrict__ flag,
    const int* __restrict__ deg, const int* __restrict__ col,
    float* __restrict__ avals, unsigned int* __restrict__ avph)
{
  int combo = blockIdx.x * 256 + threadIdx.x;   // < 1536
  int isf32 = *flag;
  int c = combo & 63;
  int lf = combo >> 6;                 // l*8+f
  int dg = deg[c];
  float av[MAXDEG];
  for (int e = 0; e < MAXDEG; ++e) {
    float v = 0.0f;
    if (e < dg) {
      int d = col[c*MAXDEG + e];
      v = ldin(adj, c*64 + d, isf32) * ldin(imp, (lf*64 + c)*64 + d, isf32);
    }
    av[e] = v;
    avals[combo*MAXDEG + e] = v;
  }
  for (int p = 0; p < 8; ++p)
    avph[combo*8 + p] = pack2h(av[2*p], av[2*p + 1]);
}

// ---------------- K1: conv1 (64-tap) via MFMA + bn0 ------------------------
// grid (4 t-tiles of 1024, B*C). Stage xs half s = f16(x[tb-36+s]).
// Phase 2 = k23's stride-2 supertile structure with K = tap index:
// out[t,f] = sum_{k=0..63} x[t+k-31] w1[f][k]; per 32-t supertile s:
// lane (m,q) reads 5 dwords at xs + 2+m+4q + 128*wv4 + 16*s (+16 for
// kk=1; shared with supertile s+1 -> CSE). A_odd = dw[1..4] copy,
// A_even = alignbit-16. 4 MFMAs (kk=0,1 x even,odd) vs w1mf B-frags.
// swz8 xor-8 epilogue: all 64 lanes store 4 outputs (o = m&7).
__global__ __launch_bounds__(256, 4) void k1_conv1_bn(
    const void* __restrict__ x,               // B,C,T raw dtype
    const uint4* __restrict__ w1mf,           // 2*64 B-fragments
    const float* __restrict__ bnFs,
    const int* __restrict__ flag,
    unsigned short* __restrict__ outp)        // B,F1,C,T f16
{
  __shared__ __align__(16) unsigned int xs[548];   // 1096 halfs
  int tid = threadIdx.x;
  int bc = blockIdx.y;                 // b*64+c
  int b = bc >> 6, c = bc & 63;
  int tb = blockIdx.x * 1024;
  int isf32 = *flag;
  int row = bc * T_;
  if (isf32) {
    const float* xr = (const float*)x + row;
    for (int m = tid; m < 274; m += 256) {
      int tg = tb - 36 + 4*m;
      uint2 st;
      if (tg >= 0 && tg + 3 < T_) {
        float4 v = *(const float4*)(xr + tg);               // 16B aligned
        st.x = pkh(v.x, v.y); st.y = pkh(v.z, v.w);
      } else {
        float q0 = (tg   >= 0 && tg   < T_) ? xr[tg]   : 0.0f;
        float q1 = (tg+1 >= 0 && tg+1 < T_) ? xr[tg+1] : 0.0f;
        float q2 = (tg+2 >= 0 && tg+2 < T_) ? xr[tg+2] : 0.0f;
        float q3 = (tg+3 >= 0 && tg+3 < T_) ? xr[tg+3] : 0.0f;
        st.x = pkh(q0, q1); st.y = pkh(q2, q3);
      }
      *(uint2*)(xs + 2*m) = st;
    }
  } else {
    const unsigned short* xr = (const unsigned short*)x + row;
    for (int m = tid; m < 274; m += 256) {
      int tg = tb - 36 + 4*m;
      uint2 st;
      if (tg >= 0 && tg + 3 < T_) {
        uint2 v = *(const uint2*)(xr + tg);                 // 8B aligned
        st.x = pkh(bf2f((unsigned short)(v.x & 0xFFFFu)),
                   bf2f((unsigned short)(v.x >> 16)));
        st.y = pkh(bf2f((unsigned short)(v.y & 0xFFFFu)),
                   bf2f((unsigned short)(v.y >> 16)));
      } else {
        float q0 = (tg   >= 0 && tg   < T_) ? bf2f(xr[tg])   : 0.0f;
        float q1 = (tg+1 >= 0 && tg+1 < T_) ? bf2f(xr[tg+1]) : 0.0f;
        float q2 = (tg+2 >= 0 && tg+2 < T_) ? bf2f(xr[tg+2]) : 0.0f;
        float q3 = (tg+3 >= 0 && tg+3 < T_) ? bf2f(xr[tg+3]) : 0.0f;
        st.x = pkh(q0, q1); st.y = pkh(q2, q3);
      }
      *(uint2*)(xs + 2*m) = st;
    }
  }
  __syncthreads();

  int lane = tid & 63;
  int wv4 = tid >> 6;                  // wave 0..3
  int m = lane & 15, q = lane >> 4;
  int sel = (m >> 3) & 1;              // 0: t+0..3, 1: t+4..7
  union { uint4 u; f16x8 h; } w0u, w1u;
  w0u.u = w1mf[lane];
  w1u.u = w1mf[64 + lane];
  int o8 = m & 7;
  float sc  = bnFs[o8];
  float shb = bnFs[8 + o8];
  const unsigned int* p0 = xs + 2 + m + 4*q + 128*wv4;
  unsigned short* orow = outp + (size_t)((b*8 + o8)*64 + c) * T_;
  #pragma unroll
  for (int s = 0; s < 8; ++s) {
    unsigned dwa[5], dwb[5];
    #pragma unroll
    for (int j = 0; j < 5; ++j) {
      dwa[j] = p0[16*s + j];           // kk=0 window
      dwb[j] = p0[16*s + 16 + j];      // kk=1 window (== s+1 kk=0: CSE)
    }
    union { unsigned d[4]; f16x8 h; } Ae0, Ao0, Ae1, Ao1;
    #pragma unroll
    for (int j = 0; j < 4; ++j) {
      Ao0.d[j] = dwa[j+1];                       // odd rows: pure copy
      Ae0.d[j] = alignb(dwa[j+1], dwa[j], 16);   // even rows: const shift
      Ao1.d[j] = dwb[j+1];
      Ae1.d[j] = alignb(dwb[j+1], dwb[j], 16);
    }
    f32x4 ae = {0.0f, 0.0f, 0.0f, 0.0f};
    f32x4 ao = {0.0f, 0.0f, 0.0f, 0.0f};
    ae = __builtin_amdgcn_mfma_f32_16x16x32_f16(Ae0.h, w0u.h, ae, 0, 0, 0);
    ae = __builtin_amdgcn_mfma_f32_16x16x32_f16(Ae1.h, w1u.h, ae, 0, 0, 0);
    ao = __builtin_amdgcn_mfma_f32_16x16x32_f16(Ao0.h, w0u.h, ao, 0, 0, 0);
    ao = __builtin_amdgcn_mfma_f32_16x16x32_f16(Ao1.h, w1u.h, ao, 0, 0, 0);
    float r0 = swz8(ae[2]);
    float r1 = swz8(ao[2]);
    float r2 = swz8(ae[3]);
    float r3 = swz8(ao[3]);
    float y0 = sel ? r0 : ae[0];
    float y1 = sel ? r1 : ao[0];
    float y2 = sel ? r2 : ae[1];
    float y3 = sel ? r3 : ao[1];
    int t0g = tb + wv4*256 + s*32 + 8*q + 4*sel;
    if (t0g < T_) {
      uint2 st;
      st.x = pkh(y0*sc + shb, y1*sc + shb);
      st.y = pkh(y2*sc + shb, y3*sc + shb);
      *(uint2*)(orow + t0g) = st;
    }
  }
}

// ---------------- K23: fused graph einsum + MFMA gconv + bn + elu ----------
// grid (4, B*C), 256 thr. XCD swizzle: work = (c fastest, t-tile, b).
// Phase 1: 32 threads per i-row stage Ah (graph sum) into 16.6 KB LDS.
//   Edge-pair dot2 (avph pairs, padded w=0/self). f32 accum.
// Phase 2: stride-2 supertiles (see r19 comment).
__global__ __launch_bounds__(256, 6) void k23_gcn_gconv(
    const unsigned short* __restrict__ in,    // B,F1,C,T f16
    unsigned short* __restrict__ outp,        // B,F1,C,T f16
    const int* __restrict__ deg, const int* __restrict__ col,
    const float* __restrict__ avals,          // 3*8*64*MAXDEG (boundary path)
    const unsigned int* __restrict__ avph,    // 3*8*64*8 packed pairs
    const uint4* __restrict__ wmf,            // 6*64 B-fragments
    const float* __restrict__ bnFs, int l)
{
  __shared__ __align__(16) uint4 ash[8 * ROW4];   // 16,640 B
  int tid = threadIdx.x;
  // bijective XCD swizzle (8192 blocks, 8 XCDs)
  int wgid = blockIdx.y * 4 + blockIdx.x;
  int swz  = (wgid & 7) * 1024 + (wgid >> 3);
  int c = swz & 63;
  int xt = (swz >> 6) & 3;
  int b = swz >> 8;
  int tb = xt * 1024;
  int wb = tb - 8;                     // staged range [wb, wb+1040)
  int dg = deg[c];                     // uniform -> s_load
  const int* cp = col + c*MAXDEG;

  // ---- phase 1: stage Ah into LDS, 32 threads per i-row ----
  {
    int i = tid >> 5;                  // 0..7
    int mlane = tid & 31;
    int dgp = (dg + 1) >> 1;
    const unsigned int* wpp = avph + ((l*8 + i)*64 + c) * 8;   // uniform
    const float* av = avals + ((l*8 + i)*64 + c) * MAXDEG;     // uniform
    const unsigned short* rbp = in + (size_t)((b*8 + i) * 64) * T_;
    for (int m = mlane; m < ROW4; m += 32) {
      int t = wb + 8*m;
      float a[8] = {0,0,0,0,0,0,0,0};
      if (t >= 0 && t + 7 < T_) {
        for (int p = 0; p < dgp; ++p) {
          int d0 = cp[2*p];            // uniform -> s_load
          int d1 = cp[2*p + 1];
          h16x2 w2 = as_h2(wpp[p]);    // uniform
          uint4 v0 = *(const uint4*)(rbp + d0*T_ + t);   // 16B aligned
          uint4 v1 = *(const uint4*)(rbp + d1*T_ + t);
          a[0] = DOT2(as_h2(PERM_LO(v1.x, v0.x)), w2, a[0]);
          a[1] = DOT2(as_h2(PERM_HI(v1.x, v0.x)), w2, a[1]);
          a[2] = DOT2(as_h2(PERM_LO(v1.y, v0.y)), w2, a[2]);
          a[3] = DOT2(as_h2(PERM_HI(v1.y, v0.y)), w2, a[3]);
          a[4] = DOT2(as_h2(PERM_LO(v1.z, v0.z)), w2, a[4]);
          a[5] = DOT2(as_h2(PERM_HI(v1.z, v0.z)), w2, a[5]);
          a[6] = DOT2(as_h2(PERM_LO(v1.w, v0.w)), w2, a[6]);
          a[7] = DOT2(as_h2(PERM_HI(v1.w, v0.w)), w2, a[7]);
        }
      } else if (t + 7 >= 0 && t < T_) {
        for (int e = 0; e < dg; ++e) {
          int d = cp[e];
          float wv = av[e];
          const unsigned short* rp = rbp + d*T_;
          #pragma unroll
          for (int q = 0; q < 8; ++q) {
            int tq = t + q;
            if (tq >= 0 && tq < T_)
              a[q] = fmaf(wv, lo_h((unsigned int)rp[tq]), a[q]);
          }
        }
      }
      uint4 o;
      o.x = pkh(a[0], a[1]); o.y = pkh(a[2], a[3]);
      o.z = pkh(a[4], a[5]); o.w = pkh(a[6], a[7]);
      ash[i*ROW4 + m] = o;
    }
  }
  __syncthreads();

  // ---- phase 2: MFMA gconv, stride-2 supertiles ----
  int lane = tid & 63;
  int wv4 = tid >> 6;                  // wave 0..3
  int m = lane & 15, q = lane >> 4;
  int sel = (m >> 3) & 1;              // 0: t+0..3, 1: t+4..7
  union { uint4 u; f16x8 h; } w0u, w1u;
  w0u.u = wmf[(l*2 + 0)*64 + lane];
  w1u.u = wmf[(l*2 + 1)*64 + lane];
  int o8 = m & 7;
  float sc  = bnFs[(l+1)*16 + o8];
  float shb = bnFs[(l+1)*16 + 8 + o8];
  const unsigned int* ashd = (const unsigned int*)ash;
  const unsigned int* p0 = ashd + q*ROWD + wv4*128 + m + 2;   // dword idx
  const unsigned int* p1 = p0 + 4*ROWD;
  unsigned short* orow = outp + (size_t)((b*8 + o8)*64 + c) * T_;
  #pragma unroll
  for (int s = 0; s < 8; ++s) {
    unsigned dwa[5], dwb[5];
    #pragma unroll
    for (int j = 0; j < 5; ++j) {      // immediate-offset ds_read2_b32
      dwa[j] = p0[16*s + j];
      dwb[j] = p1[16*s + j];
    }
    union { unsigned d[4]; f16x8 h; } Ae0, Ao0, Ae1, Ao1;
    #pragma unroll
    for (int j = 0; j < 4; ++j) {
      Ao0.d[j] = dwa[j+1];                       // odd rows: pure copy
      Ae0.d[j] = alignb(dwa[j+1], dwa[j], 16);   // even rows: const shift
      Ao1.d[j] = dwb[j+1];
      Ae1.d[j] = alignb(dwb[j+1], dwb[j], 16);
    }
    f32x4 ae = {0.0f, 0.0f, 0.0f, 0.0f};
    f32x4 ao = {0.0f, 0.0f, 0.0f, 0.0f};
    ae = __builtin_amdgcn_mfma_f32_16x16x32_f16(Ae0.h, w0u.h, ae, 0, 0, 0);
    ae = __builtin_amdgcn_mfma_f32_16x16x32_f16(Ae1.h, w1u.h, ae, 0, 0, 0);
    ao = __builtin_amdgcn_mfma_f32_16x16x32_f16(Ao0.h, w0u.h, ao, 0, 0, 0);
    ao = __builtin_amdgcn_mfma_f32_16x16x32_f16(Ao1.h, w1u.h, ao, 0, 0, 0);
    // lanes m>=8 receive (m-8)'s acc[2..3] -> all lanes do 4 outputs
    float r0 = swz8(ae[2]);
    float r1 = swz8(ao[2]);
    float r2 = swz8(ae[3]);
    float r3 = swz8(ao[3]);
    float y0 = sel ? r0 : ae[0];
    float y1 = sel ? r1 : ao[0];
    float y2 = sel ? r2 : ae[1];
    float y3 = sel ? r3 : ao[1];
    int t0g = tb + wv4*256 + s*32 + 8*q + 4*sel;
    if (t0g < T_) {
      uint2 st;
      st.x = pkh(eluf(y0*sc + shb), eluf(y1*sc + shb));
      st.y = pkh(eluf(y2*sc + shb), eluf(y3*sc + shb));
      *(uint2*)(orow + t0g) = st;
    }
  }
}

// ---------------- K4: depthwise-over-C + bn + elu + avgpool4. 8 t/thread ---
// cc-pair dot2: (h_cc0[t],h_cc1[t]) via v_perm, weight pairs dwph (SGPR).
__global__ __launch_bounds__(256) void k4_dw(
    const unsigned short* __restrict__ in,    // B,F1,C,T f16
    const unsigned int* __restrict__ dwph,    // 16x32 packed f16 pairs
    const float* __restrict__ bnsps,
    float* __restrict__ p1)                   // B,16,1000 fp32
{
  int tid = threadIdx.x;
  int bg = blockIdx.y;                 // b*8+g
  int b = bg >> 3, g = bg & 7;
  int tile = blockIdx.x * 256 + tid;
  if (tile >= 500) return;
  int t0 = tile * 8;
  int base = bg * (64 * T_);
  const unsigned int* w0pp = dwph + (2*g)*32;      // uniform -> s_load
  const unsigned int* w1pp = dwph + (2*g + 1)*32;
  float a0[8] = {0,0,0,0,0,0,0,0}, a1[8] = {0,0,0,0,0,0,0,0};
  for (int p = 0; p < 32; ++p) {
    h16x2 w02 = as_h2(w0pp[p]);        // uniform
    h16x2 w12 = as_h2(w1pp[p]);        // uniform
    uint4 v0 = *(const uint4*)(in + base + (2*p)*T_ + t0);
    uint4 v1 = *(const uint4*)(in + base + (2*p + 1)*T_ + t0);
    unsigned pr;
    pr = PERM_LO(v1.x, v0.x);
    a0[0] = DOT2(as_h2(pr), w02, a0[0]); a1[0] = DOT2(as_h2(pr), w12, a1[0]);
    pr = PERM_HI(v1.x, v0.x);
    a0[1] = DOT2(as_h2(pr), w02, a0[1]); a1[1] = DOT2(as_h2(pr), w12, a1[1]);
    pr = PERM_LO(v1.y, v0.y);
    a0[2] = DOT2(as_h2(pr), w02, a0[2]); a1[2] = DOT2(as_h2(pr), w12, a1[2]);
    pr = PERM_HI(v1.y, v0.y);
    a0[3] = DOT2(as_h2(pr), w02, a0[3]); a1[3] = DOT2(as_h2(pr), w12, a1[3]);
    pr = PERM_LO(v1.z, v0.z);
    a0[4] = DOT2(as_h2(pr), w02, a0[4]); a1[4] = DOT2(as_h2(pr), w12, a1[4]);
    pr = PERM_HI(v1.z, v0.z);
    a0[5] = DOT2(as_h2(pr), w02, a0[5]); a1[5] = DOT2(as_h2(pr), w12, a1[5]);
    pr = PERM_LO(v1.w, v0.w);
    a0[6] = DOT2(as_h2(pr), w02, a0[6]); a1[6] = DOT2(as_h2(pr), w12, a1[6]);
    pr = PERM_HI(v1.w, v0.w);
    a0[7] = DOT2(as_h2(pr), w02, a0[7]); a1[7] = DOT2(as_h2(pr), w12, a1[7]);
  }
  float sc0 = bnsps[2*g],     sh0 = bnsps[16 + 2*g];
  float sc1 = bnsps[2*g + 1], sh1 = bnsps[16 + 2*g + 1];
  int oi = t0 >> 2;
  float2 r0, r1;
  r0.x = 0.25f * (eluf(a0[0]*sc0+sh0) + eluf(a0[1]*sc0+sh0)
                + eluf(a0[2]*sc0+sh0) + eluf(a0[3]*sc0+sh0));
  r0.y = 0.25f * (eluf(a0[4]*sc0+sh0) + eluf(a0[5]*sc0+sh0)
                + eluf(a0[6]*sc0+sh0) + eluf(a0[7]*sc0+sh0));
  r1.x = 0.25f * (eluf(a1[0]*sc1+sh1) + eluf(a1[1]*sc1+sh1)
                + eluf(a1[2]*sc1+sh1) + eluf(a1[3]*sc1+sh1));
  r1.y = 0.25f * (eluf(a1[4]*sc1+sh1) + eluf(a1[5]*sc1+sh1)
                + eluf(a1[6]*sc1+sh1) + eluf(a1[7]*sc1+sh1));
  *(float2*)(p1 + (b*16 + 2*g)*TP_ + oi)     = r0;
  *(float2*)(p1 + (b*16 + 2*g + 1)*TP_ + oi) = r1;
}

// ---------------- K5: sep depthwise(16) + pointwise(16x16) + bn + elu ------
__global__ __launch_bounds__(256) void k5_sep(
    const float* __restrict__ p1,             // B,16,1000
    const float* __restrict__ sdwc,           // 16x16 (uniform)
    const float* __restrict__ pwc,            // 16x16 (uniform)
    const float* __restrict__ bnseps,
    float* __restrict__ p2)                   // B,16,1001
{
  __shared__ float ps[16*272];
  int tid = threadIdx.x;
  int wq = blockIdx.x, b = blockIdx.y;
  int wb = wq * 256;
  for (int ch = 0; ch < 16; ++ch) {
    for (int s = tid; s < 272; s += 256) {
      int t = wb - 8 + s;
      ps[ch*272 + s] = (t >= 0 && t < TP_) ? p1[(b*16 + ch)*TP_ + t] : 0.0f;
    }
  }
  __syncthreads();
  int w0 = wb + tid;
  if (w0 >= W2_) return;
  float dws[16];
  for (int ch = 0; ch < 16; ++ch) {
    float a = 0.0f;
    #pragma unroll
    for (int k = 0; k < 16; ++k)
      a = fmaf(sdwc[ch*16 + k], ps[ch*272 + tid + k], a);
    dws[ch] = a;
  }
  for (int f = 0; f < 16; ++f) {
    float a = 0.0f;
    #pragma unroll
    for (int ch = 0; ch < 16; ++ch) a = fmaf(pwc[f*16 + ch], dws[ch], a);
    float sc = bnseps[f], sh = bnseps[16 + f];
    p2[(b*16 + f)*W2_ + w0] = eluf(a*sc + sh);
  }
}

// ---------------- K6: avgpool8 (first 1000) + fc ---------------------------
__global__ __launch_bounds__(256) void k6_fc(
    const float* __restrict__ p2,             // B,16,1001
    const float* __restrict__ fcwc,           // 4x2000
    const float* __restrict__ fcbc,           // 4
    const int* __restrict__ flag,
    void* __restrict__ outp)                  // B,4
{
  __shared__ float red[4*256];
  int tid = threadIdx.x;
  int b = blockIdx.x;
  float part[4] = {0.0f, 0.0f, 0.0f, 0.0f};
  for (int idx = tid; idx < 2000; idx += 256) {
    int f = idx / 125, q = idx - f*125;
    const float* src = p2 + (b*16 + f)*W2_ + q*8;
    float s = src[0]+src[1]+src[2]+src[3]+src[4]+src[5]+src[6]+src[7];
    float mval = 0.125f * s;
    #pragma unroll
    for (int n = 0; n < 4; ++n) part[n] = fmaf(fcwc[n*2000 + idx], mval, part[n]);
  }
  #pragma unroll
  for (int n = 0; n < 4; ++n) red[n*256 + tid] = part[n];
  __syncthreads();
  for (int s = 128; s > 0; s >>= 1) {
    if (tid < s) {
      #pragma unroll
      for (int n = 0; n < 4; ++n) red[n*256 + tid] += red[n*256 + tid + s];
    }
    __syncthreads();
  }
  if (tid < 4) {
    float val = red[tid*256] + fcbc[tid];
    if (*flag) ((float*)outp)[b*4 + tid] = val;
    else       ((unsigned short*)outp)[b*4 + tid] = f2bf(val);
  }
}

// ---------------------------------------------------------------------------
extern "C" void kernel_launch(void* const* d_in, const int* in_sizes, int n_in,
                              void* d_out, int out_size, void* d_ws, size_t ws_size,
                              hipStream_t stream) {
  const void* x     = d_in[0];
  const void* adj   = d_in[1];
  const void* w1    = d_in[2];
  const void* bnF   = d_in[3];
  const void* imp   = d_in[4];
  const void* gw    = d_in[5];
  const void* dww   = d_in[6];
  const void* bnsp  = d_in[7];
  const void* sdw   = d_in[8];
  const void* pw    = d_in[9];
  const void* bnsep = d_in[10];
  const void* fcw   = d_in[11];
  const void* fcb   = d_in[12];

  char* w = (char*)d_ws;
  const size_t OFF = 262144000;  // after two 131,072,000-byte f16 buffers
  unsigned short* bufA = (unsigned short*)(w);
  unsigned short* bufB = (unsigned short*)(w + 131072000);
  int*   flag   = (int*)  (w + OFF + 0);
  int*   deg    = (int*)  (w + OFF + 256);
  int*   col    = (int*)  (w + OFF + 512);
  float* avals  = (float*)(w + OFF + 4608);
  float* dwn    = (float*)(w + OFF + 108032);
  float* sdwc   = (float*)(w + OFF + 112128);
  float* pwc    = (float*)(w + OFF + 113152);
  float* fcwc   = (float*)(w + OFF + 114176);
  float* fcbc   = (float*)(w + OFF + 146176);
  float* bnFs   = (float*)(w + OFF + 146432);
  float* bnsps  = (float*)(w + OFF + 146688);
  float* bnseps = (float*)(w + OFF + 146944);
  float* p1     = (float*)(w + OFF + 147200);
  float* p2     = (float*)(w + OFF + 2195200);
  uint4* wmf    = (uint4*)(w + OFF + 4245248);              // 384 uint4
  unsigned int* avph = (unsigned int*)(w + OFF + 4251392);  // 12288 uints
  unsigned int* dwph = (unsigned int*)(w + OFF + 4300544);  // 512 uints
  uint4* w1mf   = (uint4*)(w + OFF + 4302592);              // 128 uint4

  k0_setup<<<1, 256, 0, stream>>>(adj, imp, dww, w1, bnF, gw, bnsp, sdw, pw,
                                  bnsep, fcw, fcb, flag, deg, col,
                                  w1mf, wmf, dwn, sdwc, pwc, fcwc, fcbc,
                                  bnFs, bnsps, bnseps, dwph);
  k0b_avals<<<6, 256, 0, stream>>>(adj, imp, flag, deg, col, avals, avph);
  k1_conv1_bn<<<dim3(4, B_*C_), 256, 0, stream>>>(x, w1mf, bnFs, flag, bufA);
  for (int l = 0; l < 3; ++l) {
    const unsigned short* src = (l & 1) ? bufB : bufA;
    unsigned short*       dst = (l & 1) ? bufA : bufB;
    k23_gcn_gconv<<<dim3(4, B_*C_), 256, 0, stream>>>(src, dst, deg, col,
                                                      avals, avph, wmf, bnFs, l);
  }
  k4_dw<<<dim3(2, B_*F1_), 256, 0, stream>>>(bufB, dwph, bnsps, p1);
  k5_sep<<<dim3(4, B_), 256, 0, stream>>>(p1, sdwc, pwc, bnseps, p2);
  k6_fc<<<32, 256, 0, stream>>>(p2, fcwc, fcbc, flag, d_out);
}